// Round 8
// baseline (2657.226 us; speedup 1.0000x reference)
//
#include <hip/hip_runtime.h>
#include <math.h>

// Problem constants
#define BB 2048
#define LL 100
#define FF 64
#define EE 256
#define DD 256
#define NOUT 3

#define COMP(v, i) ((i) == 0 ? (v).x : (i) == 1 ? (v).y : (i) == 2 ? (v).z : (v).w)

typedef unsigned short u16;
typedef unsigned int u32;
typedef __attribute__((ext_vector_type(8))) __bf16 bf16x8;
typedef __attribute__((ext_vector_type(4))) float f32x4;

#define MFMA_(A, B, C) __builtin_amdgcn_mfma_f32_16x16x32_bf16((A), (B), (C), 0, 0, 0)

__device__ __forceinline__ float sigmoidf_(float x) {
    return 1.0f / (1.0f + expf(-x));
}
// tanh via identity 1 - 2/(1+e^{2x}); ~2e-7 abs fp32 error, saturates correctly.
__device__ __forceinline__ float tanhf_(float x) {
    return 1.0f - 2.0f / (1.0f + expf(2.0f * x));
}
// fp32 -> bf16 round-to-nearest-even
__device__ __forceinline__ u16 f2b_(float f) {
    u32 u = __float_as_uint(f);
    u = (u + 0x7FFFu + ((u >> 16) & 1u)) >> 16;
    return (u16)u;
}
__device__ __forceinline__ float b2f_(u16 b) {
    return __uint_as_float(((u32)b) << 16);
}
__device__ __forceinline__ u32 pack2_(float a, float b) {
    return (u32)f2b_(a) | ((u32)f2b_(b) << 16);
}
__device__ __forceinline__ f32x4 splat4(float b) {
    f32x4 v; v[0] = b; v[1] = b; v[2] = b; v[3] = b; return v;
}
// split 8 fp32 into bf16 hi/lo planes packed as uint4 (little-endian pairs)
__device__ __forceinline__ void split8(const float* v, uint4& H, uint4& L) {
    u16 h[8], lo[8];
    #pragma unroll
    for (int e = 0; e < 8; ++e) {
        h[e]  = f2b_(v[e]);
        lo[e] = f2b_(v[e] - b2f_(h[e]));
    }
    H = make_uint4((u32)h[0]  | ((u32)h[1]  << 16), (u32)h[2]  | ((u32)h[3]  << 16),
                   (u32)h[4]  | ((u32)h[5]  << 16), (u32)h[6]  | ((u32)h[7]  << 16));
    L = make_uint4((u32)lo[0] | ((u32)lo[1] << 16), (u32)lo[2] | ((u32)lo[3] << 16),
                   (u32)lo[4] | ((u32)lo[5] << 16), (u32)lo[6] | ((u32)lo[7] << 16));
}

// Encoder A-fragment LDS index: [mt][kt(10)][plane][lane][8] u16.
// AFX bank swizzle (R7-verified): stored lane = ln ^ ((ln>>4)&3). Pure storage
// permutation; readers use the same macro, so reads stay full-tile
// conflict-free while scatter writes spread across banks (conflicts
// 7.2e7 -> 1.6e7 measured).
#define AF(mt, kt, p, ln) (((((mt) * 10 + (kt)) * 2 + (p)) * 64 + (ln)) * 8)
#define AFX(mt, kt, p, ln) AF(mt, kt, p, (ln) ^ (((ln) >> 4) & 3))
// ep-GEMM A-fragment LDS index: [mt][kt(8)][plane][lane][8] u16
#define AF2(mt, kt, p, ln) (((((mt) * 8 + (kt)) * 2 + (p)) * 64 + (ln)) * 8)

// ---------------------------------------------------------------------------
// Weight prep (once per launch, into the dead ctx region):
// bf16 hi/lo split of [Wi;Wh] (tiles 0..639) and Wa (tiles 640..679) in MFMA
// B-fragment order. Tile (nt,kt) = 1024 u16: plane-hi [64 lanes][8 e], then lo.
// Element (lane l, e) = W[k = kt*32 + (l>>4)*8 + e][col = nt*16 + (l&15)].
// ---------------------------------------------------------------------------
__global__ __launch_bounds__(64) void w_prep(
    const float* __restrict__ Wi, const float* __restrict__ Wh,
    const float* __restrict__ Wa, u16* __restrict__ wp)
{
    const int bid = blockIdx.x;      // 0..679
    const int l   = threadIdx.x;     // 0..63
    const int isA = (bid >= 640);
    const int b2  = isA ? bid - 640 : bid;
    const int nt  = b2 / 10, kt = b2 - nt * 10;
    const int col = nt * 16 + (l & 15);

    float v[8];
    #pragma unroll
    for (int e = 0; e < 8; ++e) {
        const int k = kt * 32 + ((l >> 4) << 3) + e;
        v[e] = isA ? Wa[(size_t)k * 64 + col]
                   : (k < 64 ? Wi[(size_t)k * 1024 + col]
                             : Wh[(size_t)(k - 64) * 1024 + col]);
    }
    uint4 H, L;
    split8(v, H, L);
    *(uint4*)&wp[(size_t)bid * 1024 + (size_t)l * 8]       = H;
    *(uint4*)&wp[(size_t)bid * 1024 + 512 + (size_t)l * 8] = L;
}

// ---------------------------------------------------------------------------
// Wd_top (256x256) -> hi/lo MFMA tiles 680..807 (nt 0..15, kt 0..7).
// ---------------------------------------------------------------------------
__global__ __launch_bounds__(64) void w_prep2(
    const float* __restrict__ Wd, u16* __restrict__ wp)
{
    const int bid = blockIdx.x;      // 0..127
    const int l   = threadIdx.x;
    const int nt  = bid >> 3, kt = bid & 7;
    const int col = nt * 16 + (l & 15);
    float v[8];
    #pragma unroll
    for (int e = 0; e < 8; ++e) {
        const int k = kt * 32 + ((l >> 4) << 3) + e;
        v[e] = Wd[(size_t)k * 256 + col];
    }
    uint4 H, L;
    split8(v, H, L);
    u16* tp = wp + (size_t)(680 + bid) * 1024;
    *(uint4*)&tp[(size_t)l * 8]       = H;
    *(uint4*)&tp[512 + (size_t)l * 8] = L;
}

// ---------------------------------------------------------------------------
// Persistent MFMA encoder, R8 = R4's overlap frame + R7's AFX swizzle +
// pre-split h exchange + early flag release.
// Grid 256 x 1024 (1 block/CU, 92 KB LDS). Block (g 0..63, p 0..3): rows
// g*32..+32, hidden units p*64..+64. Wave w owns N-tile
// nt = (w>>2)*16 + p*4 + (w&3); its B-hi plane (40 VGPR) is register-
// resident; B-lo + Wa stream from warm L2. h exchanged between the 4
// partner blocks of a group as PRE-SPLIT bf16 hi/lo planes (bit-identical
// to recomputing split8 on fp32; kills the 768-thread split8 per step)
// via sc0/sc1 LLC stores/loads + per-group monotonic counter. Staging
// waves poll-then-load (per-wave coalesced spin, R4-proven overlap);
// flag is released BEFORE enc_out/own-fragment writes so partners observe
// it while we finish local work. 5 barriers/t. Bounded spin (no hang).
// ---------------------------------------------------------------------------
__global__ __launch_bounds__(1024) void enc_mfma4(
    const float* __restrict__ x,
    const float* __restrict__ ba, const float* __restrict__ be,
    const u16* __restrict__ wp,
    float* __restrict__ enc_out,
    u16* __restrict__ hbh,             // [2][BB][256] bf16-hi (aliases hd)
    u16* __restrict__ hbl,             // [2][BB][256] bf16-lo (aliases c_d)
    u32* __restrict__ flags)           // [64*32] counters, 128B apart (memset 0)
{
    __shared__ u16   aFrag[20480];         // 40 KB A-fragments (bf16 hi/lo)
    __shared__ float x_s[32 * 68];         // 8.5 KB x fp32
    __shared__ float e_s[32 * 68];         // 8.5 KB attention energies
    __shared__ float gate_s[4][32][66];    // 33 KB gates, padded stride 66

    const int bid = blockIdx.x;
    const int g   = (bid & 7) | ((bid >> 5) << 3);   // group 0..63
    const int p   = (bid >> 3) & 3;                  // unit-quarter
    const int row0 = g * 32;
    const int tid = threadIdx.x;
    const int l   = tid & 63;
    const int w   = tid >> 6;                        // wave 0..15

    // zero aFrag (h region must be 0 at t=0)
    for (int v = tid; v < 20480 / 2; v += 1024) ((u32*)aFrag)[v] = 0u;

    // per-wave N-tile; B-hi plane register-resident (40 VGPR)
    const int ntW = (w >> 2) * 16 + p * 4 + (w & 3);
    uint4 BhR[10];
    #pragma unroll
    for (int kt = 0; kt < 10; ++kt)
        BhR[kt] = *(const uint4*)&wp[(size_t)(ntW * 10 + kt) * 1024 + (size_t)l * 8];

    const float be_r = be[(size_t)ntW * 16 + (l & 15)];
    const float ba_r = (w < 8) ? ba[(w & 3) * 16 + (l & 15)] : 0.f;

    float c_state[2] = {0.f, 0.f};

    __syncthreads();

    for (int t = 0; t < LL; ++t) {
        // ---- staging: x (tid<256) || partner-h poll-then-load (tid>=256) ----
        if (tid < 256) {
            const int kt2 = tid >> 7;          // 0..1
            const int mt  = (tid >> 6) & 1;    // 0..1
            const int l2  = tid & 63;
            const int row2 = mt * 16 + (l2 & 15);
            const int f0   = kt2 * 32 + ((l2 >> 4) << 3);
            const float* xp = x + (size_t)(row0 + row2) * (LL * FF) + (size_t)t * FF + f0;
            float4 xa = *(const float4*)xp;
            float4 xb = *(const float4*)(xp + 4);
            float v[8] = {xa.x, xa.y, xa.z, xa.w, xb.x, xb.y, xb.z, xb.w};
            uint4 H, L;
            split8(v, H, L);
            *(uint4*)&aFrag[AFX(mt, kt2, 0, l2)] = H;
            *(uint4*)&aFrag[AFX(mt, kt2, 1, l2)] = L;
            *(float4*)&x_s[row2 * 68 + f0]     = xa;
            *(float4*)&x_s[row2 * 68 + f0 + 4] = xb;
        } else if (t > 0) {
            // per-wave coalesced spin (all lanes load the same flag word ->
            // one request/wave), then immediately load this thread's chunk:
            // poll latency and LLC load latency overlap per-wave (R4-proven).
            const u32 target = 4u * (u32)t;
            int guard = 0;
            while (__hip_atomic_load(&flags[g * 32], __ATOMIC_RELAXED,
                                     __HIP_MEMORY_SCOPE_AGENT) < target) {
                __builtin_amdgcn_s_sleep(1);
                if (++guard > 2000000) break;   // bounded: no GPU hang
            }
            const int v   = tid - 256;         // 0..767
            const int prl = v >> 8;            // 0..2 (relative partner)
            const int vv  = v & 255;
            const int row = vv >> 3;           // 0..31
            const int i8  = vv & 7;            // 8-unit chunk
            const int ugp = (p + 1 + prl) & 3;
            const int u8  = ugp * 64 + i8 * 8;
            const size_t hoff = ((size_t)((t - 1) & 1) * BB + row0 + row) * 256 + u8;
            uint4 H, L;
            asm volatile("global_load_dwordx4 %0, %2, off sc0 sc1\n\t"
                         "global_load_dwordx4 %1, %3, off sc0 sc1\n\t"
                         "s_waitcnt vmcnt(0)"
                         : "=v"(H), "=v"(L)
                         : "v"(hbh + hoff), "v"(hbl + hoff) : "memory");
            // pre-split planes land directly in fragment layout: no split8
            const int mt = row >> 4, rowT = row & 15;
            const int kt_h = 2 + (u8 >> 5);
            const int g2   = (u8 & 31) >> 3;
            const int ln   = rowT + (g2 << 4);
            *(uint4*)&aFrag[AFX(mt, kt_h, 0, ln)] = H;
            *(uint4*)&aFrag[AFX(mt, kt_h, 1, ln)] = L;
        }
        __syncthreads();   // A: x/h fragments visible

        // ---- P1: attention energies (waves 0..7: mt = w>>2, nta = w&3) ----
        if (w < 8) {
            const int mt  = w >> 2;
            const int nta = w & 3;
            f32x4 ea = splat4(ba_r);
            #pragma unroll
            for (int kt = 0; kt < 10; ++kt) {
                bf16x8 Ah = *(const bf16x8*)&aFrag[AFX(mt, kt, 0, l)];
                bf16x8 Al = *(const bf16x8*)&aFrag[AFX(mt, kt, 1, l)];
                const size_t o = (size_t)(640 + nta * 10 + kt) * 1024 + (size_t)l * 8;
                bf16x8 Bh = *(const bf16x8*)&wp[o];
                bf16x8 Bl = *(const bf16x8*)&wp[o + 512];
                ea = MFMA_(Ah, Bh, ea);
                ea = MFMA_(Al, Bh, ea);
                ea = MFMA_(Ah, Bl, ea);
            }
            const int colA = nta * 16 + (l & 15);
            #pragma unroll
            for (int r = 0; r < 4; ++r) {
                const int rowT = ((l >> 4) << 2) + r;
                e_s[(mt * 16 + rowT) * 68 + colA] = tanhf_(ea[r]);
            }
        }
        __syncthreads();   // B: energies staged

        // ---- P2: softmax over 64 cols + ein fragments (tid<512) ----
        if (tid < 512) {
            const int row2 = tid >> 4;           // 0..31
            const int c4   = (tid & 15) * 4;     // 0..60
            float4 ev = *(const float4*)&e_s[row2 * 68 + c4];
            float m = fmaxf(fmaxf(ev.x, ev.y), fmaxf(ev.z, ev.w));
            #pragma unroll
            for (int msk = 8; msk >= 1; msk >>= 1) m = fmaxf(m, __shfl_xor(m, msk, 64));
            float4 ex;
            ex.x = expf(ev.x - m); ex.y = expf(ev.y - m);
            ex.z = expf(ev.z - m); ex.w = expf(ev.w - m);
            float s = ex.x + ex.y + ex.z + ex.w;
            #pragma unroll
            for (int msk = 8; msk >= 1; msk >>= 1) s += __shfl_xor(s, msk, 64);
            const float inv = 1.f / s;
            float4 xv = *(const float4*)&x_s[row2 * 68 + c4];
            float ein[4] = { ex.x * inv * xv.x, ex.y * inv * xv.y,
                             ex.z * inv * xv.z, ex.w * inv * xv.w };
            const int mt   = row2 >> 4;
            const int rowT = row2 & 15;
            const int kt   = c4 >> 5;
            const int g2   = (c4 & 31) >> 3;
            const int e0   = c4 & 7;             // 0 or 4
            const int ln   = rowT + (g2 << 4);
            ushort4 h4, l4;
            #pragma unroll
            for (int e = 0; e < 4; ++e) {
                u16 hh = f2b_(ein[e]);
                u16 ll = f2b_(ein[e] - b2f_(hh));
                if (e == 0) { h4.x = hh; l4.x = ll; } else if (e == 1) { h4.y = hh; l4.y = ll; }
                else if (e == 2) { h4.z = hh; l4.z = ll; } else { h4.w = hh; l4.w = ll; }
            }
            *(ushort4*)&aFrag[AFX(mt, kt, 0, ln) + e0] = h4;
            *(ushort4*)&aFrag[AFX(mt, kt, 1, ln) + e0] = l4;
        }
        __syncthreads();   // C: ein fragments staged

        // ---- P3: gate GEMM, B-hi from registers, B-lo streamed (L2) ----
        f32x4 acc0 = splat4(be_r), acc1 = splat4(be_r);
        #pragma unroll
        for (int kt = 0; kt < 10; ++kt) {
            bf16x8 Ah0 = *(const bf16x8*)&aFrag[AFX(0, kt, 0, l)];
            bf16x8 Al0 = *(const bf16x8*)&aFrag[AFX(0, kt, 1, l)];
            bf16x8 Ah1 = *(const bf16x8*)&aFrag[AFX(1, kt, 0, l)];
            bf16x8 Al1 = *(const bf16x8*)&aFrag[AFX(1, kt, 1, l)];
            bf16x8 Bl  = *(const bf16x8*)&wp[(size_t)(ntW * 10 + kt) * 1024 + 512 + (size_t)l * 8];
            bf16x8 Bh  = __builtin_bit_cast(bf16x8, BhR[kt]);
            acc0 = MFMA_(Ah0, Bh, acc0);
            acc1 = MFMA_(Ah1, Bh, acc1);
            acc0 = MFMA_(Al0, Bh, acc0);
            acc1 = MFMA_(Al1, Bh, acc1);
            acc0 = MFMA_(Ah0, Bl, acc0);
            acc1 = MFMA_(Ah1, Bl, acc1);
        }
        // stage gates: gate = w>>2, unit_local = (w&3)*16 + (l&15)
        {
            const int gate = w >> 2;
            const int ulb  = (w & 3) * 16 + (l & 15);
            #pragma unroll
            for (int r = 0; r < 4; ++r) {
                const int rT = ((l >> 4) << 2) + r;
                gate_s[gate][rT][ulb]      = acc0[r];
                gate_s[gate][16 + rT][ulb] = acc1[r];
            }
        }
        __syncthreads();   // D: gates staged; aFrag reads done

        // ---- epilogue: compute h, ship pre-split planes, release early ----
        const int row = tid >> 5;            // 0..31
        const int q2  = (tid & 31) * 2;      // unit_local 0..62 even
        float hv0, hv1;
        u32 hw, lw;
        {
            float2 gi2 = *(const float2*)&gate_s[0][row][q2];
            float2 gf2 = *(const float2*)&gate_s[1][row][q2];
            float2 gg2 = *(const float2*)&gate_s[2][row][q2];
            float2 go2 = *(const float2*)&gate_s[3][row][q2];
            float cv0 = sigmoidf_(gf2.x) * c_state[0] + sigmoidf_(gi2.x) * tanhf_(gg2.x);
            float cv1 = sigmoidf_(gf2.y) * c_state[1] + sigmoidf_(gi2.y) * tanhf_(gg2.y);
            c_state[0] = cv0; c_state[1] = cv1;
            hv0 = sigmoidf_(go2.x) * tanhf_(cv0);
            hv1 = sigmoidf_(go2.y) * tanhf_(cv1);
            const u16 hi0 = f2b_(hv0), hi1 = f2b_(hv1);
            const u16 lo0 = f2b_(hv0 - b2f_(hi0));
            const u16 lo1 = f2b_(hv1 - b2f_(hi1));
            hw = (u32)hi0 | ((u32)hi1 << 16);
            lw = (u32)lo0 | ((u32)lo1 << 16);
            const size_t hoff = ((size_t)(t & 1) * BB + row0 + row) * 256 + p * 64 + q2;
            asm volatile("global_store_dword %0, %2, off sc0 sc1\n\t"
                         "global_store_dword %1, %3, off sc0 sc1"
                         :: "v"(hbh + hoff), "v"(hbl + hoff), "v"(hw), "v"(lw)
                         : "memory");
        }
        asm volatile("s_waitcnt vmcnt(0)" ::: "memory");   // hbuf visible
        __syncthreads();   // E
        if (tid == 0)
            __hip_atomic_fetch_add(&flags[g * 32], 1u, __ATOMIC_RELEASE,
                                   __HIP_MEMORY_SCOPE_AGENT);

        // post-release local writes (overlap partners' flag observation)
        {
            const int u_g = p * 64 + q2;
            *(float2*)&enc_out[((size_t)t * BB + row0 + row) * 256 + u_g]
                = make_float2(hv0, hv1);
            const int mt = row >> 4, rowT = row & 15;
            const int kt_h = 2 + (u_g >> 5);
            const int g2   = (u_g & 31) >> 3;
            const int ln   = rowT + (g2 << 4);
            const int e    = u_g & 7;            // even
            ((u32*)aFrag)[(AFX(mt, kt_h, 0, ln) + e) >> 1] = hw;
            ((u32*)aFrag)[(AFX(mt, kt_h, 1, ln) + e) >> 1] = lw;
        }
        // next-iter barrier A orders these + staging writes before P1 reads.
    }
}

// ---------------------------------------------------------------------------
// ep = enc_out @ Wd_top via split-bf16 MFMA (tier 1 hoisted GEMM).
// Grid M/32 x 256 threads (4 waves). Wave w owns nt = w*4..w*4+3.
// ---------------------------------------------------------------------------
__global__ __launch_bounds__(256) void gemm_ep_mfma(
    const float* __restrict__ A, const u16* __restrict__ wp,
    float* __restrict__ C)
{
    __shared__ u16   aF[2 * 8 * 2 * 64 * 8];   // 32 KB A-fragments
    __shared__ float c_s[32 * 260];            // 32.5 KB C staging (padded)
    const int m0  = blockIdx.x * 32;
    const int tid = threadIdx.x;
    const int l   = tid & 63;
    const int w   = tid >> 6;                  // 0..3

    for (int s = tid; s < 1024; s += 256) {
        const int mt = s >> 9, kt = (s >> 6) & 7, l2 = s & 63;
        const int row2 = mt * 16 + (l2 & 15);
        const int k0   = kt * 32 + ((l2 >> 4) << 3);
        const float* ap = A + (size_t)(m0 + row2) * 256 + k0;
        float4 xa = *(const float4*)ap;
        float4 xb = *(const float4*)(ap + 4);
        float v[8] = {xa.x, xa.y, xa.z, xa.w, xb.x, xb.y, xb.z, xb.w};
        uint4 H, L;
        split8(v, H, L);
        *(uint4*)&aF[AF2(mt, kt, 0, l2)] = H;
        *(uint4*)&aF[AF2(mt, kt, 1, l2)] = L;
    }
    __syncthreads();

    f32x4 acc[2][4];
    #pragma unroll
    for (int mt = 0; mt < 2; ++mt)
        #pragma unroll
        for (int j = 0; j < 4; ++j) acc[mt][j] = splat4(0.f);

    #pragma unroll
    for (int kt = 0; kt < 8; ++kt) {
        bf16x8 Ah0 = *(const bf16x8*)&aF[AF2(0, kt, 0, l)];
        bf16x8 Al0 = *(const bf16x8*)&aF[AF2(0, kt, 1, l)];
        bf16x8 Ah1 = *(const bf16x8*)&aF[AF2(1, kt, 0, l)];
        bf16x8 Al1 = *(const bf16x8*)&aF[AF2(1, kt, 1, l)];
        #pragma unroll
        for (int j = 0; j < 4; ++j) {
            const int nt = w * 4 + j;
            const u16* bt = wp + (size_t)(680 + nt * 8 + kt) * 1024 + (size_t)l * 8;
            bf16x8 Bh = *(const bf16x8*)bt;
            bf16x8 Bl = *(const bf16x8*)(bt + 512);
            acc[0][j] = MFMA_(Ah0, Bh, acc[0][j]);
            acc[1][j] = MFMA_(Ah1, Bh, acc[1][j]);
            acc[0][j] = MFMA_(Al0, Bh, acc[0][j]);
            acc[1][j] = MFMA_(Al1, Bh, acc[1][j]);
            acc[0][j] = MFMA_(Ah0, Bl, acc[0][j]);
            acc[1][j] = MFMA_(Ah1, Bl, acc[1][j]);
        }
    }

    #pragma unroll
    for (int mt = 0; mt < 2; ++mt)
        #pragma unroll
        for (int j = 0; j < 4; ++j) {
            const int col = (w * 4 + j) * 16 + (l & 15);
            #pragma unroll
            for (int r = 0; r < 4; ++r) {
                const int row = mt * 16 + ((l >> 4) << 2) + r;
                c_s[row * 260 + col] = acc[mt][j][r];
            }
        }
    __syncthreads();
    for (int v = tid; v < 32 * 64; v += 256) {
        const int row = v >> 6, c4 = (v & 63) << 2;
        *(float4*)&C[(size_t)(m0 + row) * 256 + c4] = *(const float4*)&c_s[row * 260 + c4];
    }
}

// ---------------------------------------------------------------------------
// Generic fp32 GEMM C(M,256) = A(M,256) @ W(256,256) [+ bias].
// Block = 32 rows, 256 threads. skip_gemm: C = bias (decoder step 0, hd==0).
// Used for: hp = hd @ Wd_bot + bd.
// ---------------------------------------------------------------------------
__global__ __launch_bounds__(256) void gemm_nk256(
    const float* __restrict__ A, const float* __restrict__ W,
    const float* __restrict__ bias, float* __restrict__ C, int skip_gemm)
{
    __shared__ float a_s[32 * 256];   // 32 KB
    const int m0   = blockIdx.x * 32;
    const int tid  = threadIdx.x;
    const int lane = tid & 63;
    const int rg   = tid >> 6;        // 0..3 -> rows rg*8..rg*8+7
    const int n0   = lane * 4;

    float4 bias4 = make_float4(0.f, 0.f, 0.f, 0.f);
    if (bias) bias4 = *(const float4*)&bias[n0];

    if (skip_gemm) {
        #pragma unroll
        for (int r = 0; r < 8; ++r)
            *(float4*)&C[(size_t)(m0 + rg * 8 + r) * 256 + n0] = bias4;
        return;
    }

    for (int v = tid; v < 32 * 64; v += 256)
        ((float4*)a_s)[v] = ((const float4*)(A + (size_t)m0 * 256))[v];
    __syncthreads();

    float4 acc[8];
    #pragma unroll
    for (int r = 0; r < 8; ++r) acc[r] = bias4;

    #pragma unroll 2
    for (int k = 0; k < 256; k += 4) {
        float4 wv[4];
        #pragma unroll
        for (int kk = 0; kk < 4; ++kk)
            wv[kk] = *(const float4*)&W[(size_t)(k + kk) * 256 + n0];
        float4 av[8];
        #pragma unroll
        for (int r = 0; r < 8; ++r)
            av[r] = *(const float4*)&a_s[(rg * 8 + r) * 256 + k];
        #pragma unroll
        for (int kk = 0; kk < 4; ++kk) {
            #pragma unroll
            for (int r = 0; r < 8; ++r) {
                float e = COMP(av[r], kk);
                acc[r].x += e * wv[kk].x; acc[r].y += e * wv[kk].y;
                acc[r].z += e * wv[kk].z; acc[r].w += e * wv[kk].w;
            }
        }
    }
    #pragma unroll
    for (int r = 0; r < 8; ++r)
        *(float4*)&C[(size_t)(m0 + rg * 8 + r) * 256 + n0] = acc[r];
}

// ---------------------------------------------------------------------------
// ep = enc_out @ Wd_top, emitted as bf16 (tiers 2/3 fallback).
// ---------------------------------------------------------------------------
__global__ __launch_bounds__(256) void pack_ep(
    float* A, const float* __restrict__ W, u16* epOut, int packed)
{
    __shared__ float a_s[32 * 256];   // 32 KB
    const int m0   = blockIdx.x * 32;
    const int tid  = threadIdx.x;
    const int lane = tid & 63;
    const int rg   = tid >> 6;
    const int n0   = lane * 4;

    for (int v = tid; v < 32 * 64; v += 256)
        ((float4*)a_s)[v] = ((const float4*)(A + (size_t)m0 * 256))[v];
    __syncthreads();

    float4 acc[8];
    #pragma unroll
    for (int r = 0; r < 8; ++r) acc[r] = make_float4(0.f, 0.f, 0.f, 0.f);

    #pragma unroll 2
    for (int k = 0; k < 256; k += 4) {
        float4 wv[4];
        #pragma unroll
        for (int kk = 0; kk < 4; ++kk)
            wv[kk] = *(const float4*)&W[(size_t)(k + kk) * 256 + n0];
        float4 av[8];
        #pragma unroll
        for (int r = 0; r < 8; ++r)
            av[r] = *(const float4*)&a_s[(rg * 8 + r) * 256 + k];
        #pragma unroll
        for (int kk = 0; kk < 4; ++kk) {
            #pragma unroll
            for (int r = 0; r < 8; ++r) {
                float e = COMP(av[r], kk);
                acc[r].x += e * wv[kk].x; acc[r].y += e * wv[kk].y;
                acc[r].z += e * wv[kk].z; acc[r].w += e * wv[kk].w;
            }
        }
    }

    u16* epu = packed ? (u16*)A : epOut;
    #pragma unroll
    for (int r = 0; r < 8; ++r) {
        const size_t row = (size_t)(m0 + rg * 8 + r);
        ushort4 o;
        o.x = f2b_(acc[r].x); o.y = f2b_(acc[r].y);
        o.z = f2b_(acc[r].z); o.w = f2b_(acc[r].w);
        u16* dst = packed ? (epu + row * 512 + 256 + n0)
                          : (epu + row * 256 + n0);
        *(ushort4*)dst = o;
    }

    if (packed) {
        u32* ab = (u32*)A;
        for (int v = tid; v < 32 * 128; v += 256) {
            const int row = v >> 7, j = v & 127;
            float2 f = *(const float2*)&a_s[(row << 8) + (j << 1)];
            ab[((size_t)(m0 + row)) * 256 + j] = pack2_(f.x, f.y);
        }
    }
}

// ---------------------------------------------------------------------------
// Per-step decoder scores from precomputed fp32 ep (tier 1):
//   score[l,b] = Wl . tanh(ep[l,b,:] + hp[b,:])   (bl cancels in softmax)
// ---------------------------------------------------------------------------
__global__ __launch_bounds__(256) void scores_ep_f32(
    const float* __restrict__ ep, const float* __restrict__ hp,
    const float* __restrict__ Wl, float* __restrict__ scores)
{
    __shared__ float hp_s[8 * 256];
    const int b0  = blockIdx.x * 8;
    const int l0  = blockIdx.y * 20;
    const int tid = threadIdx.x;
    const int r   = tid >> 5;
    const int g   = tid & 31;

    for (int v = tid; v < 512; v += 256)
        ((float4*)hp_s)[v] = ((const float4*)(hp + (size_t)b0 * 256))[v];
    __syncthreads();

    const float4 wl0 = *(const float4*)&Wl[g * 4];
    const float4 wl1 = *(const float4*)&Wl[128 + g * 4];
    const float4 h0  = *(const float4*)&hp_s[r * 256 + g * 4];
    const float4 h1  = *(const float4*)&hp_s[r * 256 + 128 + g * 4];
    const float* eb  = ep + (size_t)l0 * (BB * 256) + (size_t)(b0 + r) * 256;

    #pragma unroll 2
    for (int li = 0; li < 20; ++li) {
        float4 e0 = *(const float4*)&eb[(size_t)li * (BB * 256) + g * 4];
        float4 e1 = *(const float4*)&eb[(size_t)li * (BB * 256) + 128 + g * 4];
        float p = tanhf_(e0.x + h0.x) * wl0.x + tanhf_(e0.y + h0.y) * wl0.y
                + tanhf_(e0.z + h0.z) * wl0.z + tanhf_(e0.w + h0.w) * wl0.w
                + tanhf_(e1.x + h1.x) * wl1.x + tanhf_(e1.y + h1.y) * wl1.y
                + tanhf_(e1.z + h1.z) * wl1.z + tanhf_(e1.w + h1.w) * wl1.w;
        #pragma unroll
        for (int msk = 16; msk >= 1; msk >>= 1) p += __shfl_xor(p, msk, 64);
        if (g == 0) scores[(size_t)(l0 + li) * BB + b0 + r] = p;
    }
}

// ---------------------------------------------------------------------------
// Same, from bf16 ep rows (tiers 2/3). sstr/soff in u16 units.
// ---------------------------------------------------------------------------
__global__ __launch_bounds__(256) void scores_ep_b16(
    const u16* __restrict__ ep, const float* __restrict__ hp,
    const float* __restrict__ Wl, float* __restrict__ scores,
    int sstr, int soff)
{
    __shared__ float hp_s[8 * 256];
    const int b0  = blockIdx.x * 8;
    const int l0  = blockIdx.y * 20;
    const int tid = threadIdx.x;
    const int r   = tid >> 5;
    const int g   = tid & 31;

    for (int v = tid; v < 512; v += 256)
        ((float4*)hp_s)[v] = ((const float4*)(hp + (size_t)b0 * 256))[v];
    __syncthreads();

    const float4 wl0 = *(const float4*)&Wl[g * 4];
    const float4 wl1 = *(const float4*)&Wl[128 + g * 4];
    const float4 h0  = *(const float4*)&hp_s[r * 256 + g * 4];
    const float4 h1  = *(const float4*)&hp_s[r * 256 + 128 + g * 4];

    #pragma unroll 2
    for (int li = 0; li < 20; ++li) {
        const u16* er = ep + ((size_t)(l0 + li) * BB + b0 + r) * sstr + soff;
        ushort4 u0 = *(const ushort4*)&er[g * 4];
        ushort4 u1 = *(const ushort4*)&er[128 + g * 4];
        float p = tanhf_(b2f_(u0.x) + h0.x) * wl0.x + tanhf_(b2f_(u0.y) + h0.y) * wl0.y
                + tanhf_(b2f_(u0.z) + h0.z) * wl0.z + tanhf_(b2f_(u0.w) + h0.w) * wl0.w
                + tanhf_(b2f_(u1.x) + h1.x) * wl1.x + tanhf_(b2f_(u1.y) + h1.y) * wl1.y
                + tanhf_(b2f_(u1.z) + h1.z) * wl1.z + tanhf_(b2f_(u1.w) + h1.w) * wl1.w;
        #pragma unroll
        for (int msk = 16; msk >= 1; msk >>= 1) p += __shfl_xor(p, msk, 64);
        if (g == 0) scores[(size_t)(l0 + li) * BB + b0 + r] = p;
    }
}

// ---------------------------------------------------------------------------
// softmax over L + ctx. fp32 enc variant (tiers 1/2). Block = 8 rows.
// ---------------------------------------------------------------------------
__global__ __launch_bounds__(256) void softmax_ctx(
    const float* __restrict__ scores, const float* __restrict__ enc_out,
    float* __restrict__ ctx)
{
    __shared__ float al_s[8 * 100];
    const int b0  = blockIdx.x * 8;
    const int tid = threadIdx.x;
    for (int v = tid; v < 800; v += 256) {
        int r = v / 100, l = v - r * 100;
        al_s[r * 100 + l] = scores[(size_t)l * BB + b0 + r];
    }
    __syncthreads();
    if (tid < 8) {
        float m = -1e30f;
        for (int l = 0; l < LL; ++l) m = fmaxf(m, al_s[tid * 100 + l]);
        float s = 0.f;
        for (int l = 0; l < LL; ++l) { float e = expf(al_s[tid * 100 + l] - m); al_s[tid * 100 + l] = e; s += e; }
        float inv = 1.f / s;
        for (int l = 0; l < LL; ++l) al_s[tid * 100 + l] *= inv;
    }
    __syncthreads();
    float acc[8] = {};
    for (int l = 0; l < LL; ++l) {
        const float* er = enc_out + (size_t)l * (BB * 256) + (size_t)b0 * 256 + tid;
        #pragma unroll
        for (int r = 0; r < 8; ++r) acc[r] += al_s[r * 100 + l] * er[r * 256];
    }
    for (int r = 0; r < 8; ++r) ctx[(size_t)(b0 + r) * 256 + tid] = acc[r];
}

// ---------------------------------------------------------------------------
// softmax over L + ctx, bf16 packed enc (tier 3).
// ---------------------------------------------------------------------------
__global__ __launch_bounds__(256) void softmax_ctx_b16(
    const float* __restrict__ scores, const u16* __restrict__ encp,
    float* __restrict__ ctx)
{
    __shared__ float al_s[8 * 100];
    const int b0  = blockIdx.x * 8;
    const int tid = threadIdx.x;
    for (int v = tid; v < 800; v += 256) {
        int r = v / 100, l = v - r * 100;
        al_s[r * 100 + l] = scores[(size_t)l * BB + b0 + r];
    }
    __syncthreads();
    if (tid < 8) {
        float m = -1e30f;
        for (int l = 0; l < LL; ++l) m = fmaxf(m, al_s[tid * 100 + l]);
        float s = 0.f;
        for (int l = 0; l < LL; ++l) { float e = expf(al_s[tid * 100 + l] - m); al_s[tid * 100 + l] = e; s += e; }
        float inv = 1.f / s;
        for (int l = 0; l < LL; ++l) al_s[tid * 100 + l] *= inv;
    }
    __syncthreads();
    float acc[8] = {};
    for (int l = 0; l < LL; ++l) {
        const u16* er = encp + ((size_t)l * BB + b0) * 512 + tid;
        #pragma unroll
        for (int r = 0; r < 8; ++r) acc[r] += al_s[r * 100 + l] * b2f_(er[r * 512]);
    }
    for (int r = 0; r < 8; ++r) ctx[(size_t)(b0 + r) * 256 + tid] = acc[r];
}

// ---------------------------------------------------------------------------
// Decoder LSTM cell: grid 256 x 512, block = 8 rows, half0 = ctx@Wdi,
// half1 = hd@Wdh, coalesced float4 weights. hd updated in place.
// ---------------------------------------------------------------------------
__global__ __launch_bounds__(512) void dec_step(
    const float* __restrict__ ctxp,
    const float* __restrict__ Wdi, const float* __restrict__ Wdh,
    const float* __restrict__ bdec,
    float* __restrict__ hd, float* __restrict__ c_st, int first)
{
    __shared__ float ct_s[8 * 256];        // 8 KB
    __shared__ float hd_s[8 * 256];        // 8 KB
    __shared__ float gate_s[2][8 * 1024];  // 64 KB
    const int row0 = blockIdx.x * 8;
    const int tid  = threadIdx.x;
    const int lane = tid & 63, w = tid >> 6;
    const int half = tid >> 8;
    const int ct   = tid & 255;
    const int c0   = ct * 4;

    ((float4*)ct_s)[tid] = ((const float4*)(ctxp + (size_t)row0 * 256))[tid];
    if (!first)
        ((float4*)hd_s)[tid] = ((const float4*)(hd + (size_t)row0 * 256))[tid];
    __syncthreads();

    float4 acc[8];
    {
        float4 b4 = *(const float4*)&bdec[c0];
        float4 bias4 = (half == 0) ? b4 : make_float4(0.f, 0.f, 0.f, 0.f);
        #pragma unroll
        for (int r = 0; r < 8; ++r) acc[r] = bias4;
    }
    if (half == 0) {
        const float* wP = Wdi + c0;
        #pragma unroll 2
        for (int ch = 0; ch < 64; ++ch) {
            const int k0 = ch * 4;
            float4 w0 = *(const float4*)&wP[(size_t)(k0 + 0) * 1024];
            float4 w1 = *(const float4*)&wP[(size_t)(k0 + 1) * 1024];
            float4 w2 = *(const float4*)&wP[(size_t)(k0 + 2) * 1024];
            float4 w3 = *(const float4*)&wP[(size_t)(k0 + 3) * 1024];
            #pragma unroll
            for (int r = 0; r < 8; ++r) {
                float4 av = *(const float4*)&ct_s[r * 256 + k0];
                acc[r].x += av.x * w0.x; acc[r].y += av.x * w0.y;
                acc[r].z += av.x * w0.z; acc[r].w += av.x * w0.w;
                acc[r].x += av.y * w1.x; acc[r].y += av.y * w1.y;
                acc[r].z += av.y * w1.z; acc[r].w += av.y * w1.w;
                acc[r].x += av.z * w2.x; acc[r].y += av.z * w2.y;
                acc[r].z += av.z * w2.z; acc[r].w += av.z * w2.w;
                acc[r].x += av.w * w3.x; acc[r].y += av.w * w3.y;
                acc[r].z += av.w * w3.z; acc[r].w += av.w * w3.w;
            }
        }
    } else if (!first) {
        const float* wP = Wdh + c0;
        #pragma unroll 2
        for (int ch = 0; ch < 64; ++ch) {
            const int k0 = ch * 4;
            float4 w0 = *(const float4*)&wP[(size_t)(k0 + 0) * 1024];
            float4 w1 = *(const float4*)&wP[(size_t)(k0 + 1) * 1024];
            float4 w2 = *(const float4*)&wP[(size_t)(k0 + 2) * 1024];
            float4 w3 = *(const float4*)&wP[(size_t)(k0 + 3) * 1024];
            #pragma unroll
            for (int r = 0; r < 8; ++r) {
                float4 av = *(const float4*)&hd_s[r * 256 + k0];
                acc[r].x += av.x * w0.x; acc[r].y += av.x * w0.y;
                acc[r].z += av.x * w0.z; acc[r].w += av.x * w0.w;
                acc[r].x += av.y * w1.x; acc[r].y += av.y * w1.y;
                acc[r].z += av.y * w1.z; acc[r].w += av.y * w1.w;
                acc[r].x += av.z * w2.x; acc[r].y += av.z * w2.y;
                acc[r].z += av.z * w2.z; acc[r].w += av.z * w2.w;
                acc[r].x += av.w * w3.x; acc[r].y += av.w * w3.y;
                acc[r].z += av.w * w3.z; acc[r].w += av.w * w3.w;
            }
        }
    }
    #pragma unroll
    for (int r = 0; r < 8; ++r)
        *(float4*)&gate_s[half][r * 1024 + c0] = acc[r];
    __syncthreads();

    {
        const float* g0 = &gate_s[0][w * 1024 + lane * 4];
        const float* g1 = &gate_s[1][w * 1024 + lane * 4];
        float4 giA = *(const float4*)&g0[0],   giB = *(const float4*)&g1[0];
        float4 gfA = *(const float4*)&g0[256], gfB = *(const float4*)&g1[256];
        float4 ggA = *(const float4*)&g0[512], ggB = *(const float4*)&g1[512];
        float4 goA = *(const float4*)&g0[768], goB = *(const float4*)&g1[768];
        size_t ci = (size_t)(row0 + w) * 256 + lane * 4;
        float4 c4 = first ? make_float4(0.f, 0.f, 0.f, 0.f)
                          : *(const float4*)&c_st[ci];
        float cc[4] = { c4.x, c4.y, c4.z, c4.w };
        float gi[4] = { giA.x + giB.x, giA.y + giB.y, giA.z + giB.z, giA.w + giB.w };
        float gf[4] = { gfA.x + gfB.x, gfA.y + gfB.y, gfA.z + gfB.z, gfA.w + gfB.w };
        float gg[4] = { ggA.x + ggB.x, ggA.y + ggB.y, ggA.z + ggB.z, ggA.w + ggB.w };
        float go[4] = { goA.x + goB.x, goA.y + goB.y, goA.z + goB.z, goA.w + goB.w };
        float4 cn, hn;
        #pragma unroll
        for (int uu = 0; uu < 4; ++uu) {
            float cv = sigmoidf_(gf[uu]) * cc[uu] + sigmoidf_(gi[uu]) * tanhf_(gg[uu]);
            float hv = sigmoidf_(go[uu]) * tanhf_(cv);
            if (uu == 0) { cn.x = cv; hn.x = hv; } else if (uu == 1) { cn.y = cv; hn.y = hv; }
            else if (uu == 2) { cn.z = cv; hn.z = hv; } else { cn.w = cv; hn.w = hv; }
        }
        *(float4*)&c_st[ci] = cn;
        *(float4*)&hd[ci]   = hn;
    }
}

// ---------------------------------------------------------------------------
// Head: fc = tanh(h_d@Wf+bf); out[:,step] = tanh(fc@Wo+bo). Block = 16 rows.
// ---------------------------------------------------------------------------
__global__ __launch_bounds__(256) void head_k(
    const float* __restrict__ hd, const float* __restrict__ Wf,
    const float* __restrict__ bf, const float* __restrict__ Wo,
    const float* __restrict__ bo, float* __restrict__ out, int step)
{
    __shared__ float hd_s[16 * 256];
    __shared__ float fc_s[16 * 128];
    const int b0  = blockIdx.x * 16;
    const int tid = threadIdx.x;
    {
        const float4* hg = (const float4*)(hd + (size_t)b0 * 256);
        for (int i = tid; i < 1024; i += 256) ((float4*)hd_s)[i] = hg[i];
    }
    __syncthreads();
    {
        const int f = tid & 127, rg = tid >> 7;
        float acc[8];
        float bfv = bf[f];
        #pragma unroll
        for (int rr = 0; rr < 8; ++rr) acc[rr] = bfv;
        const float* wp = Wf + f;
        #pragma unroll 2
        for (int k = 0; k < 256; ++k) {
            float wv = wp[k * 128];
            #pragma unroll
            for (int rr = 0; rr < 8; ++rr) acc[rr] += hd_s[(rg * 8 + rr) * 256 + k] * wv;
        }
        for (int rr = 0; rr < 8; ++rr) fc_s[(rg * 8 + rr) * 128 + f] = tanhf_(acc[rr]);
    }
    __syncthreads();
    {
        const int lane = tid & 63, w = tid >> 6;
        const float bov = bo[0];
        #pragma unroll
        for (int rr = 0; rr < 4; ++rr) {
            int r = w * 4 + rr;
            float p = fc_s[r * 128 + lane] * Wo[lane] + fc_s[r * 128 + 64 + lane] * Wo[64 + lane];
            #pragma unroll
            for (int msk = 32; msk >= 1; msk >>= 1) p += __shfl_xor(p, msk, 64);
            if (lane == 0) out[(size_t)(b0 + r) * NOUT + step] = tanhf_(p + bov);
        }
    }
}

extern "C" void kernel_launch(void* const* d_in, const int* in_sizes, int n_in,
                              void* d_out, int out_size, void* d_ws, size_t ws_size,
                              hipStream_t stream)
{
    const float* x    = (const float*)d_in[0];
    const float* Wa   = (const float*)d_in[1];
    const float* ba   = (const float*)d_in[2];
    const float* Wi   = (const float*)d_in[3];
    const float* Wh   = (const float*)d_in[4];
    const float* be   = (const float*)d_in[5];
    const float* Wd   = (const float*)d_in[6];
    const float* bd   = (const float*)d_in[7];
    const float* Wl   = (const float*)d_in[8];
    const float* bl   = (const float*)d_in[9];
    const float* Wdi  = (const float*)d_in[10];
    const float* Wdh  = (const float*)d_in[11];
    const float* bdec = (const float*)d_in[12];
    const float* Wf   = (const float*)d_in[13];
    const float* bf   = (const float*)d_in[14];
    const float* Wo   = (const float*)d_in[15];
    const float* bo   = (const float*)d_in[16];
    float* out = (float*)d_out;

    // ws layout (floats): enc_out | hd | c_d | ctx(=hp=wprep alias) | scores | [ep]
    const size_t f_enc    = (size_t)LL * BB * EE;     // 52,428,800
    const size_t f_state  = (size_t)BB * EE;          // 524,288
    const size_t f_scores = (size_t)LL * BB;          // 204,800
    const size_t need3 = (f_enc + 3 * f_state + f_scores) * sizeof(float);
    const size_t need2 = need3 + f_enc * sizeof(u16);
    const size_t need1 = need3 + f_enc * sizeof(float);

    float* ws      = (float*)d_ws;
    float* enc_out = ws;
    float* hd      = enc_out + f_enc;
    float* c_d     = hd + f_state;
    float* ctx     = c_d + f_state;      // also hp AND the weight-prep buffer
    float* scores  = ctx + f_state;      //   (disjoint lifetimes)
    float* ep32    = scores + f_scores;  // tier 1 only
    u16*   ep16    = (u16*)(scores + f_scores);  // tier 2 only
    float* hp      = ctx;
    u16*   wprep   = (u16*)ctx;          // 808 tiles x 2 KB = 1.616 MB <= 2 MB
    // encoder h-exchange planes alias hd (hi) and c_d (lo), each exactly
    // 2 x BB x 256 u16 = 2 MB (dead during encoder); flags alias scores.
    u16*   hbh     = (u16*)hd;
    u16*   hbl     = (u16*)c_d;
    u32*   flags   = (u32*)scores;

    if (ws_size < need3) return;   // diagnostic clean-fail (known satisfied)
    const int tier = (ws_size >= need1) ? 1 : (ws_size >= need2) ? 2 : 3;

    // zero the group sync counters (replayed as a graph node each launch)
    hipMemsetAsync(flags, 0, 64 * 32 * sizeof(u32), stream);
    // weights -> bf16 hi/lo MFMA fragments (ctx region is dead here)
    w_prep<<<680, 64, 0, stream>>>(Wi, Wh, Wa, wprep);
    w_prep2<<<128, 64, 0, stream>>>(Wd, wprep);
    // persistent MFMA encoder: 256 blocks x 1024 threads (1/CU, co-resident)
    enc_mfma4<<<256, 1024, 0, stream>>>(x, ba, be, wprep, enc_out, hbh, hbl, flags);

    // hoist the step-invariant enc_out @ Wd_top out of the decode loop
    if (tier == 1)
        gemm_ep_mfma<<<(LL * BB) / 32, 256, 0, stream>>>(enc_out, wprep, ep32);
    else
        pack_ep<<<(LL * BB) / 32, 256, 0, stream>>>(
            enc_out, Wd, ep16, tier == 3 ? 1 : 0);

    for (int s = 0; s < NOUT; ++s) {
        // hp = hd @ Wd_bot + bd  (step 0: hd == 0 -> hp = bd)
        gemm_nk256<<<BB / 32, 256, 0, stream>>>(
            hd, Wd + 256 * 256, bd, hp, s == 0);
        if (tier == 1)
            scores_ep_f32<<<dim3(BB / 8, 5), 256, 0, stream>>>(ep32, hp, Wl, scores);
        else if (tier == 2)
            scores_ep_b16<<<dim3(BB / 8, 5), 256, 0, stream>>>(ep16, hp, Wl, scores, 256, 0);
        else
            scores_ep_b16<<<dim3(BB / 8, 5), 256, 0, stream>>>(
                (const u16*)enc_out, hp, Wl, scores, 512, 256);
        if (tier == 3)
            softmax_ctx_b16<<<BB / 8, 256, 0, stream>>>(scores, (const u16*)enc_out, ctx);
        else
            softmax_ctx<<<BB / 8, 256, 0, stream>>>(scores, enc_out, ctx);
        dec_step<<<BB / 8, 512, 0, stream>>>(ctx, Wdi, Wdh, bdec, hd, c_d, s == 0);
        head_k<<<BB / 16, 256, 0, stream>>>(hd, Wf, bf, Wo, bo, out, s);
    }
}

// Round 9
// 2601.744 us; speedup vs baseline: 1.0213x; 1.0213x over previous
//
#include <hip/hip_runtime.h>
#include <math.h>

// Problem constants
#define BB 2048
#define LL 100
#define FF 64
#define EE 256
#define DD 256
#define NOUT 3

#define COMP(v, i) ((i) == 0 ? (v).x : (i) == 1 ? (v).y : (i) == 2 ? (v).z : (v).w)

typedef unsigned short u16;
typedef unsigned int u32;
typedef __attribute__((ext_vector_type(8))) __bf16 bf16x8;
typedef __attribute__((ext_vector_type(4))) float f32x4;
typedef __attribute__((ext_vector_type(2))) float f32x2;

#define MFMA_(A, B, C) __builtin_amdgcn_mfma_f32_16x16x32_bf16((A), (B), (C), 0, 0, 0)

__device__ __forceinline__ float sigmoidf_(float x) {
    return 1.0f / (1.0f + expf(-x));
}
// tanh via identity 1 - 2/(1+e^{2x}); ~2e-7 abs fp32 error, saturates correctly.
__device__ __forceinline__ float tanhf_(float x) {
    return 1.0f - 2.0f / (1.0f + expf(2.0f * x));
}
// fp32 -> bf16 round-to-nearest-even
__device__ __forceinline__ u16 f2b_(float f) {
    u32 u = __float_as_uint(f);
    u = (u + 0x7FFFu + ((u >> 16) & 1u)) >> 16;
    return (u16)u;
}
__device__ __forceinline__ float b2f_(u16 b) {
    return __uint_as_float(((u32)b) << 16);
}
__device__ __forceinline__ u32 pack2_(float a, float b) {
    return (u32)f2b_(a) | ((u32)f2b_(b) << 16);
}
__device__ __forceinline__ f32x4 splat4(float b) {
    f32x4 v; v[0] = b; v[1] = b; v[2] = b; v[3] = b; return v;
}
// split 8 fp32 into bf16 hi/lo planes packed as uint4 (little-endian pairs)
__device__ __forceinline__ void split8(const float* v, uint4& H, uint4& L) {
    u16 h[8], lo[8];
    #pragma unroll
    for (int e = 0; e < 8; ++e) {
        h[e]  = f2b_(v[e]);
        lo[e] = f2b_(v[e] - b2f_(h[e]));
    }
    H = make_uint4((u32)h[0]  | ((u32)h[1]  << 16), (u32)h[2]  | ((u32)h[3]  << 16),
                   (u32)h[4]  | ((u32)h[5]  << 16), (u32)h[6]  | ((u32)h[7]  << 16));
    L = make_uint4((u32)lo[0] | ((u32)lo[1] << 16), (u32)lo[2] | ((u32)lo[3] << 16),
                   (u32)lo[4] | ((u32)lo[5] << 16), (u32)lo[6] | ((u32)lo[7] << 16));
}

// Encoder A-fragment LDS index: [mt][kt(10)][plane][lane][8] u16.
// AFX bank swizzle (R7-verified): stored lane = ln ^ ((ln>>4)&3). Pure storage
// permutation; readers use the same macro with ln = hardware lane, so reads
// stay full-tile conflict-free while scatter writes spread across banks
// (SQ_LDS_BANK_CONFLICT 6.5e7 -> 1.6e7 measured).
#define AF(mt, kt, p, ln) (((((mt) * 10 + (kt)) * 2 + (p)) * 64 + (ln)) * 8)
#define AFX(mt, kt, p, ln) AF(mt, kt, p, (ln) ^ (((ln) >> 4) & 3))
// ep-GEMM A-fragment LDS index: [mt][kt(8)][plane][lane][8] u16
#define AF2(mt, kt, p, ln) (((((mt) * 8 + (kt)) * 2 + (p)) * 64 + (ln)) * 8)

// ---------------------------------------------------------------------------
// Weight prep (once per launch, into the dead ctx region):
// bf16 hi/lo split of [Wi;Wh] (tiles 0..639) and Wa (tiles 640..679) in MFMA
// B-fragment order. Tile (nt,kt) = 1024 u16: plane-hi [64 lanes][8 e], then lo.
// Element (lane l, e) = W[k = kt*32 + (l>>4)*8 + e][col = nt*16 + (l&15)].
// ---------------------------------------------------------------------------
__global__ __launch_bounds__(64) void w_prep(
    const float* __restrict__ Wi, const float* __restrict__ Wh,
    const float* __restrict__ Wa, u16* __restrict__ wp)
{
    const int bid = blockIdx.x;      // 0..679
    const int l   = threadIdx.x;     // 0..63
    const int isA = (bid >= 640);
    const int b2  = isA ? bid - 640 : bid;
    const int nt  = b2 / 10, kt = b2 - nt * 10;
    const int col = nt * 16 + (l & 15);

    float v[8];
    #pragma unroll
    for (int e = 0; e < 8; ++e) {
        const int k = kt * 32 + ((l >> 4) << 3) + e;
        v[e] = isA ? Wa[(size_t)k * 64 + col]
                   : (k < 64 ? Wi[(size_t)k * 1024 + col]
                             : Wh[(size_t)(k - 64) * 1024 + col]);
    }
    uint4 H, L;
    split8(v, H, L);
    *(uint4*)&wp[(size_t)bid * 1024 + (size_t)l * 8]       = H;
    *(uint4*)&wp[(size_t)bid * 1024 + 512 + (size_t)l * 8] = L;
}

// ---------------------------------------------------------------------------
// Wd_top (256x256) -> hi/lo MFMA tiles 680..807 (nt 0..15, kt 0..7).
// ---------------------------------------------------------------------------
__global__ __launch_bounds__(64) void w_prep2(
    const float* __restrict__ Wd, u16* __restrict__ wp)
{
    const int bid = blockIdx.x;      // 0..127
    const int l   = threadIdx.x;
    const int nt  = bid >> 3, kt = bid & 7;
    const int col = nt * 16 + (l & 15);
    float v[8];
    #pragma unroll
    for (int e = 0; e < 8; ++e) {
        const int k = kt * 32 + ((l >> 4) << 3) + e;
        v[e] = Wd[(size_t)k * 256 + col];
    }
    uint4 H, L;
    split8(v, H, L);
    u16* tp = wp + (size_t)(680 + bid) * 1024;
    *(uint4*)&tp[(size_t)l * 8]       = H;
    *(uint4*)&tp[512 + (size_t)l * 8] = L;
}

// ---------------------------------------------------------------------------
// Persistent MFMA encoder == R4's frame EXACTLY (best measured, 1484 us)
// plus ONLY the two LDS-local fixes (AFX swizzle, padded gate_s).
// Grid 256 x 1024 (1 block/CU). Block (g 0..63, p 0..3): rows g*32..+32,
// hidden units p*64..+64. Wave w owns N-tile nt = (w>>2)*16 + p*4 + (w&3);
// its B-hi plane (40 VGPR) is register-resident; B-lo + Wa stream from L2.
// h exchanged between the 4 partner blocks of a group through fp32 hbuf
// (sc0/sc1 LLC stores/loads) + per-group monotonic atomic counter; each
// staging thread polls then loads (poll latency and LLC load latency
// overlap per-wave -- R4-proven). Bounded spin: no hang possible.
// ---------------------------------------------------------------------------
__global__ __launch_bounds__(1024) void enc_mfma4(
    const float* __restrict__ x,
    const float* __restrict__ ba, const float* __restrict__ be,
    const u16* __restrict__ wp,
    float* __restrict__ enc_out,
    float* __restrict__ hbuf,          // [2][BB][256] fp32 (aliases hd|c_d)
    u32* __restrict__ flags)           // [64*32] counters, 128B apart (memset 0)
{
    __shared__ u16   aFrag[20480];         // 40 KB A-fragments (bf16 hi/lo)
    __shared__ float x_s[32 * 68];         // 8.5 KB x fp32
    __shared__ float e_s[32 * 68];         // 8.5 KB attention energies
    __shared__ float gate_s[4][32][66];    // 33 KB gates, padded stride 66

    const int bid = blockIdx.x;
    const int g   = (bid & 7) | ((bid >> 5) << 3);   // group 0..63
    const int p   = (bid >> 3) & 3;                  // unit-quarter
    const int row0 = g * 32;
    const int tid = threadIdx.x;
    const int l   = tid & 63;
    const int w   = tid >> 6;                        // wave 0..15

    // zero aFrag (h region must be 0 at t=0)
    for (int v = tid; v < 20480 / 2; v += 1024) ((u32*)aFrag)[v] = 0u;

    // per-wave N-tile; B-hi plane register-resident (40 VGPR)
    const int ntW = (w >> 2) * 16 + p * 4 + (w & 3);
    uint4 BhR[10];
    #pragma unroll
    for (int kt = 0; kt < 10; ++kt)
        BhR[kt] = *(const uint4*)&wp[(size_t)(ntW * 10 + kt) * 1024 + (size_t)l * 8];

    const float be_r = be[(size_t)ntW * 16 + (l & 15)];
    const float ba_r = (w < 8) ? ba[(w & 3) * 16 + (l & 15)] : 0.f;

    float c_state[2] = {0.f, 0.f};

    __syncthreads();

    for (int t = 0; t < LL; ++t) {
        // ---- P0: x staging (tid<256) | partner-h poll+load (tid>=256) ----
        if (tid < 256) {
            const int kt2 = tid >> 7;          // 0..1
            const int mt  = (tid >> 6) & 1;    // 0..1
            const int l2  = tid & 63;
            const int row2 = mt * 16 + (l2 & 15);
            const int f0   = kt2 * 32 + ((l2 >> 4) << 3);
            const float* xp = x + (size_t)(row0 + row2) * (LL * FF) + (size_t)t * FF + f0;
            float4 xa = *(const float4*)xp;
            float4 xb = *(const float4*)(xp + 4);
            float v[8] = {xa.x, xa.y, xa.z, xa.w, xb.x, xb.y, xb.z, xb.w};
            uint4 H, L;
            split8(v, H, L);
            *(uint4*)&aFrag[AFX(mt, kt2, 0, l2)] = H;
            *(uint4*)&aFrag[AFX(mt, kt2, 1, l2)] = L;
            *(float4*)&x_s[row2 * 68 + f0]     = xa;
            *(float4*)&x_s[row2 * 68 + f0 + 4] = xb;
        } else if (t > 0) {
            // per-thread poll-then-load: spin and LLC latency overlap per wave
            const u32 target = 4u * (u32)t;
            int guard = 0;
            while (__hip_atomic_load(&flags[g * 32], __ATOMIC_RELAXED,
                                     __HIP_MEMORY_SCOPE_AGENT) < target) {
                __builtin_amdgcn_s_sleep(1);
                if (++guard > 2000000) break;   // bounded: no GPU hang
            }
            const int v   = tid - 256;         // 0..767
            const int prl = v >> 8;            // 0..2 (relative partner)
            const int vv  = v & 255;
            const int row = vv >> 3;           // 0..31
            const int i8  = vv & 7;            // 8-unit chunk
            const int ugp = (p + 1 + prl) & 3;
            const int u8  = ugp * 64 + i8 * 8; // global unit base (mult of 8)
            const float* hp_g = hbuf + ((size_t)((t - 1) & 1) * BB + row0 + row) * 256 + u8;
            f32x4 a4, b4;
            asm volatile("global_load_dwordx4 %0, %2, off sc0 sc1\n\t"
                         "global_load_dwordx4 %1, %3, off sc0 sc1\n\t"
                         "s_waitcnt vmcnt(0)"
                         : "=v"(a4), "=v"(b4)
                         : "v"(hp_g), "v"(hp_g + 4) : "memory");
            float v8[8] = {a4[0], a4[1], a4[2], a4[3], b4[0], b4[1], b4[2], b4[3]};
            uint4 H, L;
            split8(v8, H, L);
            const int mt = row >> 4, rowT = row & 15;
            const int kt_h = 2 + (u8 >> 5);
            const int g2   = (u8 & 31) >> 3;
            const int ln   = rowT + (g2 << 4);
            *(uint4*)&aFrag[AFX(mt, kt_h, 0, ln)] = H;
            *(uint4*)&aFrag[AFX(mt, kt_h, 1, ln)] = L;
        }
        __syncthreads();   // A: x/h fragments visible

        // ---- P1: attention energies (waves 0..7: mt = w>>2, nta = w&3) ----
        if (w < 8) {
            const int mt  = w >> 2;
            const int nta = w & 3;
            f32x4 ea = splat4(ba_r);
            #pragma unroll
            for (int kt = 0; kt < 10; ++kt) {
                bf16x8 Ah = *(const bf16x8*)&aFrag[AFX(mt, kt, 0, l)];
                bf16x8 Al = *(const bf16x8*)&aFrag[AFX(mt, kt, 1, l)];
                const size_t o = (size_t)(640 + nta * 10 + kt) * 1024 + (size_t)l * 8;
                bf16x8 Bh = *(const bf16x8*)&wp[o];
                bf16x8 Bl = *(const bf16x8*)&wp[o + 512];
                ea = MFMA_(Ah, Bh, ea);
                ea = MFMA_(Al, Bh, ea);
                ea = MFMA_(Ah, Bl, ea);
            }
            const int colA = nta * 16 + (l & 15);
            #pragma unroll
            for (int r = 0; r < 4; ++r) {
                const int rowT = ((l >> 4) << 2) + r;
                e_s[(mt * 16 + rowT) * 68 + colA] = tanhf_(ea[r]);
            }
        }
        __syncthreads();   // B: energies staged

        // ---- P2: softmax over 64 cols + ein fragments (tid<512) ----
        if (tid < 512) {
            const int row2 = tid >> 4;           // 0..31
            const int c4   = (tid & 15) * 4;     // 0..60
            float4 ev = *(const float4*)&e_s[row2 * 68 + c4];
            float m = fmaxf(fmaxf(ev.x, ev.y), fmaxf(ev.z, ev.w));
            #pragma unroll
            for (int msk = 8; msk >= 1; msk >>= 1) m = fmaxf(m, __shfl_xor(m, msk, 64));
            float4 ex;
            ex.x = expf(ev.x - m); ex.y = expf(ev.y - m);
            ex.z = expf(ev.z - m); ex.w = expf(ev.w - m);
            float s = ex.x + ex.y + ex.z + ex.w;
            #pragma unroll
            for (int msk = 8; msk >= 1; msk >>= 1) s += __shfl_xor(s, msk, 64);
            const float inv = 1.f / s;
            float4 xv = *(const float4*)&x_s[row2 * 68 + c4];
            float ein[4] = { ex.x * inv * xv.x, ex.y * inv * xv.y,
                             ex.z * inv * xv.z, ex.w * inv * xv.w };
            const int mt   = row2 >> 4;
            const int rowT = row2 & 15;
            const int kt   = c4 >> 5;
            const int g2   = (c4 & 31) >> 3;
            const int e0   = c4 & 7;             // 0 or 4
            const int ln   = rowT + (g2 << 4);
            ushort4 h4, l4;
            #pragma unroll
            for (int e = 0; e < 4; ++e) {
                u16 hh = f2b_(ein[e]);
                u16 ll = f2b_(ein[e] - b2f_(hh));
                if (e == 0) { h4.x = hh; l4.x = ll; } else if (e == 1) { h4.y = hh; l4.y = ll; }
                else if (e == 2) { h4.z = hh; l4.z = ll; } else { h4.w = hh; l4.w = ll; }
            }
            *(ushort4*)&aFrag[AFX(mt, kt, 0, ln) + e0] = h4;
            *(ushort4*)&aFrag[AFX(mt, kt, 1, ln) + e0] = l4;
        }
        __syncthreads();   // C: ein fragments staged

        // ---- P3: gate GEMM, B-hi from registers, B-lo streamed (L2) ----
        f32x4 acc0 = splat4(be_r), acc1 = splat4(be_r);
        #pragma unroll
        for (int kt = 0; kt < 10; ++kt) {
            bf16x8 Ah0 = *(const bf16x8*)&aFrag[AFX(0, kt, 0, l)];
            bf16x8 Al0 = *(const bf16x8*)&aFrag[AFX(0, kt, 1, l)];
            bf16x8 Ah1 = *(const bf16x8*)&aFrag[AFX(1, kt, 0, l)];
            bf16x8 Al1 = *(const bf16x8*)&aFrag[AFX(1, kt, 1, l)];
            bf16x8 Bl  = *(const bf16x8*)&wp[(size_t)(ntW * 10 + kt) * 1024 + 512 + (size_t)l * 8];
            bf16x8 Bh  = __builtin_bit_cast(bf16x8, BhR[kt]);
            acc0 = MFMA_(Ah0, Bh, acc0);
            acc1 = MFMA_(Ah1, Bh, acc1);
            acc0 = MFMA_(Al0, Bh, acc0);
            acc1 = MFMA_(Al1, Bh, acc1);
            acc0 = MFMA_(Ah0, Bl, acc0);
            acc1 = MFMA_(Ah1, Bl, acc1);
        }
        // stage gates: gate = w>>2, unit_local = (w&3)*16 + (l&15)
        {
            const int gate = w >> 2;
            const int ulb  = (w & 3) * 16 + (l & 15);
            #pragma unroll
            for (int r = 0; r < 4; ++r) {
                const int rT = ((l >> 4) << 2) + r;
                gate_s[gate][rT][ulb]      = acc0[r];
                gate_s[gate][16 + rT][ulb] = acc1[r];
            }
        }
        __syncthreads();   // D: gates staged; aFrag reads done

        // ---- epilogue: 1024 threads x 2 cells; h out + own h-frags ----
        {
            const int row = tid >> 5;            // 0..31
            const int q2  = (tid & 31) * 2;      // unit_local 0..62 even
            float gi0 = gate_s[0][row][q2], gi1 = gate_s[0][row][q2 + 1];
            float gf0 = gate_s[1][row][q2], gf1 = gate_s[1][row][q2 + 1];
            float gg0 = gate_s[2][row][q2], gg1 = gate_s[2][row][q2 + 1];
            float go0 = gate_s[3][row][q2], go1 = gate_s[3][row][q2 + 1];
            float cv0 = sigmoidf_(gf0) * c_state[0] + sigmoidf_(gi0) * tanhf_(gg0);
            float cv1 = sigmoidf_(gf1) * c_state[1] + sigmoidf_(gi1) * tanhf_(gg1);
            c_state[0] = cv0; c_state[1] = cv1;
            float hv0 = sigmoidf_(go0) * tanhf_(cv0);
            float hv1 = sigmoidf_(go1) * tanhf_(cv1);
            const int u_g = p * 64 + q2;
            // enc_out (plain store)
            *(float2*)&enc_out[((size_t)t * BB + row0 + row) * 256 + u_g]
                = make_float2(hv0, hv1);
            // hbuf write-through (coherence point) for partner blocks
            float* hp_g = hbuf + ((size_t)(t & 1) * BB + row0 + row) * 256 + u_g;
            f32x2 hv2; hv2[0] = hv0; hv2[1] = hv1;
            asm volatile("global_store_dwordx2 %0, %1, off sc0 sc1"
                         :: "v"(hp_g), "v"(hv2) : "memory");
            // own h-fragments for t+1
            const int mt = row >> 4, rowT = row & 15;
            const int kt_h = 2 + (u_g >> 5);
            const int g2   = (u_g & 31) >> 3;
            const int ln   = rowT + (g2 << 4);
            const int e    = u_g & 7;            // even
            ((u32*)aFrag)[(AFX(mt, kt_h, 0, ln) + e) >> 1] = pack2_(hv0, hv1);
            u16 h0 = f2b_(hv0), h1 = f2b_(hv1);
            ((u32*)aFrag)[(AFX(mt, kt_h, 1, ln) + e) >> 1] =
                (u32)f2b_(hv0 - b2f_(h0)) | ((u32)f2b_(hv1 - b2f_(h1)) << 16);
        }
        asm volatile("s_waitcnt vmcnt(0)" ::: "memory");   // h stores complete
        __syncthreads();   // E: all waves' stores acked
        if (tid == 0)
            __hip_atomic_fetch_add(&flags[g * 32], 1u, __ATOMIC_RELEASE,
                                   __HIP_MEMORY_SCOPE_AGENT);
    }
}

// ---------------------------------------------------------------------------
// ep = enc_out @ Wd_top via split-bf16 MFMA (tier 1 hoisted GEMM).
// Grid M/32 x 256 threads (4 waves). Wave w owns nt = w*4..w*4+3.
// ---------------------------------------------------------------------------
__global__ __launch_bounds__(256) void gemm_ep_mfma(
    const float* __restrict__ A, const u16* __restrict__ wp,
    float* __restrict__ C)
{
    __shared__ u16   aF[2 * 8 * 2 * 64 * 8];   // 32 KB A-fragments
    __shared__ float c_s[32 * 260];            // 32.5 KB C staging (padded)
    const int m0  = blockIdx.x * 32;
    const int tid = threadIdx.x;
    const int l   = tid & 63;
    const int w   = tid >> 6;                  // 0..3

    for (int s = tid; s < 1024; s += 256) {
        const int mt = s >> 9, kt = (s >> 6) & 7, l2 = s & 63;
        const int row2 = mt * 16 + (l2 & 15);
        const int k0   = kt * 32 + ((l2 >> 4) << 3);
        const float* ap = A + (size_t)(m0 + row2) * 256 + k0;
        float4 xa = *(const float4*)ap;
        float4 xb = *(const float4*)(ap + 4);
        float v[8] = {xa.x, xa.y, xa.z, xa.w, xb.x, xb.y, xb.z, xb.w};
        uint4 H, L;
        split8(v, H, L);
        *(uint4*)&aF[AF2(mt, kt, 0, l2)] = H;
        *(uint4*)&aF[AF2(mt, kt, 1, l2)] = L;
    }
    __syncthreads();

    f32x4 acc[2][4];
    #pragma unroll
    for (int mt = 0; mt < 2; ++mt)
        #pragma unroll
        for (int j = 0; j < 4; ++j) acc[mt][j] = splat4(0.f);

    #pragma unroll
    for (int kt = 0; kt < 8; ++kt) {
        bf16x8 Ah0 = *(const bf16x8*)&aF[AF2(0, kt, 0, l)];
        bf16x8 Al0 = *(const bf16x8*)&aF[AF2(0, kt, 1, l)];
        bf16x8 Ah1 = *(const bf16x8*)&aF[AF2(1, kt, 0, l)];
        bf16x8 Al1 = *(const bf16x8*)&aF[AF2(1, kt, 1, l)];
        #pragma unroll
        for (int j = 0; j < 4; ++j) {
            const int nt = w * 4 + j;
            const u16* bt = wp + (size_t)(680 + nt * 8 + kt) * 1024 + (size_t)l * 8;
            bf16x8 Bh = *(const bf16x8*)bt;
            bf16x8 Bl = *(const bf16x8*)(bt + 512);
            acc[0][j] = MFMA_(Ah0, Bh, acc[0][j]);
            acc[1][j] = MFMA_(Ah1, Bh, acc[1][j]);
            acc[0][j] = MFMA_(Al0, Bh, acc[0][j]);
            acc[1][j] = MFMA_(Al1, Bh, acc[1][j]);
            acc[0][j] = MFMA_(Ah0, Bl, acc[0][j]);
            acc[1][j] = MFMA_(Ah1, Bl, acc[1][j]);
        }
    }

    #pragma unroll
    for (int mt = 0; mt < 2; ++mt)
        #pragma unroll
        for (int j = 0; j < 4; ++j) {
            const int col = (w * 4 + j) * 16 + (l & 15);
            #pragma unroll
            for (int r = 0; r < 4; ++r) {
                const int row = mt * 16 + ((l >> 4) << 2) + r;
                c_s[row * 260 + col] = acc[mt][j][r];
            }
        }
    __syncthreads();
    for (int v = tid; v < 32 * 64; v += 256) {
        const int row = v >> 6, c4 = (v & 63) << 2;
        *(float4*)&C[(size_t)(m0 + row) * 256 + c4] = *(const float4*)&c_s[row * 260 + c4];
    }
}

// ---------------------------------------------------------------------------
// Generic fp32 GEMM C(M,256) = A(M,256) @ W(256,256) [+ bias].
// Block = 32 rows, 256 threads. skip_gemm: C = bias (decoder step 0, hd==0).
// Used for: hp = hd @ Wd_bot + bd.
// ---------------------------------------------------------------------------
__global__ __launch_bounds__(256) void gemm_nk256(
    const float* __restrict__ A, const float* __restrict__ W,
    const float* __restrict__ bias, float* __restrict__ C, int skip_gemm)
{
    __shared__ float a_s[32 * 256];   // 32 KB
    const int m0   = blockIdx.x * 32;
    const int tid  = threadIdx.x;
    const int lane = tid & 63;
    const int rg   = tid >> 6;        // 0..3 -> rows rg*8..rg*8+7
    const int n0   = lane * 4;

    float4 bias4 = make_float4(0.f, 0.f, 0.f, 0.f);
    if (bias) bias4 = *(const float4*)&bias[n0];

    if (skip_gemm) {
        #pragma unroll
        for (int r = 0; r < 8; ++r)
            *(float4*)&C[(size_t)(m0 + rg * 8 + r) * 256 + n0] = bias4;
        return;
    }

    for (int v = tid; v < 32 * 64; v += 256)
        ((float4*)a_s)[v] = ((const float4*)(A + (size_t)m0 * 256))[v];
    __syncthreads();

    float4 acc[8];
    #pragma unroll
    for (int r = 0; r < 8; ++r) acc[r] = bias4;

    #pragma unroll 2
    for (int k = 0; k < 256; k += 4) {
        float4 wv[4];
        #pragma unroll
        for (int kk = 0; kk < 4; ++kk)
            wv[kk] = *(const float4*)&W[(size_t)(k + kk) * 256 + n0];
        float4 av[8];
        #pragma unroll
        for (int r = 0; r < 8; ++r)
            av[r] = *(const float4*)&a_s[(rg * 8 + r) * 256 + k];
        #pragma unroll
        for (int kk = 0; kk < 4; ++kk) {
            #pragma unroll
            for (int r = 0; r < 8; ++r) {
                float e = COMP(av[r], kk);
                acc[r].x += e * wv[kk].x; acc[r].y += e * wv[kk].y;
                acc[r].z += e * wv[kk].z; acc[r].w += e * wv[kk].w;
            }
        }
    }
    #pragma unroll
    for (int r = 0; r < 8; ++r)
        *(float4*)&C[(size_t)(m0 + rg * 8 + r) * 256 + n0] = acc[r];
}

// ---------------------------------------------------------------------------
// ep = enc_out @ Wd_top, emitted as bf16 (tiers 2/3 fallback).
// ---------------------------------------------------------------------------
__global__ __launch_bounds__(256) void pack_ep(
    float* A, const float* __restrict__ W, u16* epOut, int packed)
{
    __shared__ float a_s[32 * 256];   // 32 KB
    const int m0   = blockIdx.x * 32;
    const int tid  = threadIdx.x;
    const int lane = tid & 63;
    const int rg   = tid >> 6;
    const int n0   = lane * 4;

    for (int v = tid; v < 32 * 64; v += 256)
        ((float4*)a_s)[v] = ((const float4*)(A + (size_t)m0 * 256))[v];
    __syncthreads();

    float4 acc[8];
    #pragma unroll
    for (int r = 0; r < 8; ++r) acc[r] = make_float4(0.f, 0.f, 0.f, 0.f);

    #pragma unroll 2
    for (int k = 0; k < 256; k += 4) {
        float4 wv[4];
        #pragma unroll
        for (int kk = 0; kk < 4; ++kk)
            wv[kk] = *(const float4*)&W[(size_t)(k + kk) * 256 + n0];
        float4 av[8];
        #pragma unroll
        for (int r = 0; r < 8; ++r)
            av[r] = *(const float4*)&a_s[(rg * 8 + r) * 256 + k];
        #pragma unroll
        for (int kk = 0; kk < 4; ++kk) {
            #pragma unroll
            for (int r = 0; r < 8; ++r) {
                float e = COMP(av[r], kk);
                acc[r].x += e * wv[kk].x; acc[r].y += e * wv[kk].y;
                acc[r].z += e * wv[kk].z; acc[r].w += e * wv[kk].w;
            }
        }
    }

    u16* epu = packed ? (u16*)A : epOut;
    #pragma unroll
    for (int r = 0; r < 8; ++r) {
        const size_t row = (size_t)(m0 + rg * 8 + r);
        ushort4 o;
        o.x = f2b_(acc[r].x); o.y = f2b_(acc[r].y);
        o.z = f2b_(acc[r].z); o.w = f2b_(acc[r].w);
        u16* dst = packed ? (epu + row * 512 + 256 + n0)
                          : (epu + row * 256 + n0);
        *(ushort4*)dst = o;
    }

    if (packed) {
        u32* ab = (u32*)A;
        for (int v = tid; v < 32 * 128; v += 256) {
            const int row = v >> 7, j = v & 127;
            float2 f = *(const float2*)&a_s[(row << 8) + (j << 1)];
            ab[((size_t)(m0 + row)) * 256 + j] = pack2_(f.x, f.y);
        }
    }
}

// ---------------------------------------------------------------------------
// Per-step decoder scores from precomputed fp32 ep (tier 1):
//   score[l,b] = Wl . tanh(ep[l,b,:] + hp[b,:])   (bl cancels in softmax)
// ---------------------------------------------------------------------------
__global__ __launch_bounds__(256) void scores_ep_f32(
    const float* __restrict__ ep, const float* __restrict__ hp,
    const float* __restrict__ Wl, float* __restrict__ scores)
{
    __shared__ float hp_s[8 * 256];
    const int b0  = blockIdx.x * 8;
    const int l0  = blockIdx.y * 20;
    const int tid = threadIdx.x;
    const int r   = tid >> 5;
    const int g   = tid & 31;

    for (int v = tid; v < 512; v += 256)
        ((float4*)hp_s)[v] = ((const float4*)(hp + (size_t)b0 * 256))[v];
    __syncthreads();

    const float4 wl0 = *(const float4*)&Wl[g * 4];
    const float4 wl1 = *(const float4*)&Wl[128 + g * 4];
    const float4 h0  = *(const float4*)&hp_s[r * 256 + g * 4];
    const float4 h1  = *(const float4*)&hp_s[r * 256 + 128 + g * 4];
    const float* eb  = ep + (size_t)l0 * (BB * 256) + (size_t)(b0 + r) * 256;

    #pragma unroll 2
    for (int li = 0; li < 20; ++li) {
        float4 e0 = *(const float4*)&eb[(size_t)li * (BB * 256) + g * 4];
        float4 e1 = *(const float4*)&eb[(size_t)li * (BB * 256) + 128 + g * 4];
        float p = tanhf_(e0.x + h0.x) * wl0.x + tanhf_(e0.y + h0.y) * wl0.y
                + tanhf_(e0.z + h0.z) * wl0.z + tanhf_(e0.w + h0.w) * wl0.w
                + tanhf_(e1.x + h1.x) * wl1.x + tanhf_(e1.y + h1.y) * wl1.y
                + tanhf_(e1.z + h1.z) * wl1.z + tanhf_(e1.w + h1.w) * wl1.w;
        #pragma unroll
        for (int msk = 16; msk >= 1; msk >>= 1) p += __shfl_xor(p, msk, 64);
        if (g == 0) scores[(size_t)(l0 + li) * BB + b0 + r] = p;
    }
}

// ---------------------------------------------------------------------------
// Same, from bf16 ep rows (tiers 2/3). sstr/soff in u16 units.
// ---------------------------------------------------------------------------
__global__ __launch_bounds__(256) void scores_ep_b16(
    const u16* __restrict__ ep, const float* __restrict__ hp,
    const float* __restrict__ Wl, float* __restrict__ scores,
    int sstr, int soff)
{
    __shared__ float hp_s[8 * 256];
    const int b0  = blockIdx.x * 8;
    const int l0  = blockIdx.y * 20;
    const int tid = threadIdx.x;
    const int r   = tid >> 5;
    const int g   = tid & 31;

    for (int v = tid; v < 512; v += 256)
        ((float4*)hp_s)[v] = ((const float4*)(hp + (size_t)b0 * 256))[v];
    __syncthreads();

    const float4 wl0 = *(const float4*)&Wl[g * 4];
    const float4 wl1 = *(const float4*)&Wl[128 + g * 4];
    const float4 h0  = *(const float4*)&hp_s[r * 256 + g * 4];
    const float4 h1  = *(const float4*)&hp_s[r * 256 + 128 + g * 4];

    #pragma unroll 2
    for (int li = 0; li < 20; ++li) {
        const u16* er = ep + ((size_t)(l0 + li) * BB + b0 + r) * sstr + soff;
        ushort4 u0 = *(const ushort4*)&er[g * 4];
        ushort4 u1 = *(const ushort4*)&er[128 + g * 4];
        float p = tanhf_(b2f_(u0.x) + h0.x) * wl0.x + tanhf_(b2f_(u0.y) + h0.y) * wl0.y
                + tanhf_(b2f_(u0.z) + h0.z) * wl0.z + tanhf_(b2f_(u0.w) + h0.w) * wl0.w
                + tanhf_(b2f_(u1.x) + h1.x) * wl1.x + tanhf_(b2f_(u1.y) + h1.y) * wl1.y
                + tanhf_(b2f_(u1.z) + h1.z) * wl1.z + tanhf_(b2f_(u1.w) + h1.w) * wl1.w;
        #pragma unroll
        for (int msk = 16; msk >= 1; msk >>= 1) p += __shfl_xor(p, msk, 64);
        if (g == 0) scores[(size_t)(l0 + li) * BB + b0 + r] = p;
    }
}

// ---------------------------------------------------------------------------
// softmax over L + ctx. fp32 enc variant (tiers 1/2). Block = 8 rows.
// ---------------------------------------------------------------------------
__global__ __launch_bounds__(256) void softmax_ctx(
    const float* __restrict__ scores, const float* __restrict__ enc_out,
    float* __restrict__ ctx)
{
    __shared__ float al_s[8 * 100];
    const int b0  = blockIdx.x * 8;
    const int tid = threadIdx.x;
    for (int v = tid; v < 800; v += 256) {
        int r = v / 100, l = v - r * 100;
        al_s[r * 100 + l] = scores[(size_t)l * BB + b0 + r];
    }
    __syncthreads();
    if (tid < 8) {
        float m = -1e30f;
        for (int l = 0; l < LL; ++l) m = fmaxf(m, al_s[tid * 100 + l]);
        float s = 0.f;
        for (int l = 0; l < LL; ++l) { float e = expf(al_s[tid * 100 + l] - m); al_s[tid * 100 + l] = e; s += e; }
        float inv = 1.f / s;
        for (int l = 0; l < LL; ++l) al_s[tid * 100 + l] *= inv;
    }
    __syncthreads();
    float acc[8] = {};
    for (int l = 0; l < LL; ++l) {
        const float* er = enc_out + (size_t)l * (BB * 256) + (size_t)b0 * 256 + tid;
        #pragma unroll
        for (int r = 0; r < 8; ++r) acc[r] += al_s[r * 100 + l] * er[r * 256];
    }
    for (int r = 0; r < 8; ++r) ctx[(size_t)(b0 + r) * 256 + tid] = acc[r];
}

// ---------------------------------------------------------------------------
// softmax over L + ctx, bf16 packed enc (tier 3).
// ---------------------------------------------------------------------------
__global__ __launch_bounds__(256) void softmax_ctx_b16(
    const float* __restrict__ scores, const u16* __restrict__ encp,
    float* __restrict__ ctx)
{
    __shared__ float al_s[8 * 100];
    const int b0  = blockIdx.x * 8;
    const int tid = threadIdx.x;
    for (int v = tid; v < 800; v += 256) {
        int r = v / 100, l = v - r * 100;
        al_s[r * 100 + l] = scores[(size_t)l * BB + b0 + r];
    }
    __syncthreads();
    if (tid < 8) {
        float m = -1e30f;
        for (int l = 0; l < LL; ++l) m = fmaxf(m, al_s[tid * 100 + l]);
        float s = 0.f;
        for (int l = 0; l < LL; ++l) { float e = expf(al_s[tid * 100 + l] - m); al_s[tid * 100 + l] = e; s += e; }
        float inv = 1.f / s;
        for (int l = 0; l < LL; ++l) al_s[tid * 100 + l] *= inv;
    }
    __syncthreads();
    float acc[8] = {};
    for (int l = 0; l < LL; ++l) {
        const u16* er = encp + ((size_t)l * BB + b0) * 512 + tid;
        #pragma unroll
        for (int r = 0; r < 8; ++r) acc[r] += al_s[r * 100 + l] * b2f_(er[r * 512]);
    }
    for (int r = 0; r < 8; ++r) ctx[(size_t)(b0 + r) * 256 + tid] = acc[r];
}

// ---------------------------------------------------------------------------
// Decoder LSTM cell: grid 256 x 512, block = 8 rows, half0 = ctx@Wdi,
// half1 = hd@Wdh, coalesced float4 weights. hd updated in place.
// ---------------------------------------------------------------------------
__global__ __launch_bounds__(512) void dec_step(
    const float* __restrict__ ctxp,
    const float* __restrict__ Wdi, const float* __restrict__ Wdh,
    const float* __restrict__ bdec,
    float* __restrict__ hd, float* __restrict__ c_st, int first)
{
    __shared__ float ct_s[8 * 256];        // 8 KB
    __shared__ float hd_s[8 * 256];        // 8 KB
    __shared__ float gate_s[2][8 * 1024];  // 64 KB
    const int row0 = blockIdx.x * 8;
    const int tid  = threadIdx.x;
    const int lane = tid & 63, w = tid >> 6;
    const int half = tid >> 8;
    const int ct   = tid & 255;
    const int c0   = ct * 4;

    ((float4*)ct_s)[tid] = ((const float4*)(ctxp + (size_t)row0 * 256))[tid];
    if (!first)
        ((float4*)hd_s)[tid] = ((const float4*)(hd + (size_t)row0 * 256))[tid];
    __syncthreads();

    float4 acc[8];
    {
        float4 b4 = *(const float4*)&bdec[c0];
        float4 bias4 = (half == 0) ? b4 : make_float4(0.f, 0.f, 0.f, 0.f);
        #pragma unroll
        for (int r = 0; r < 8; ++r) acc[r] = bias4;
    }
    if (half == 0) {
        const float* wP = Wdi + c0;
        #pragma unroll 2
        for (int ch = 0; ch < 64; ++ch) {
            const int k0 = ch * 4;
            float4 w0 = *(const float4*)&wP[(size_t)(k0 + 0) * 1024];
            float4 w1 = *(const float4*)&wP[(size_t)(k0 + 1) * 1024];
            float4 w2 = *(const float4*)&wP[(size_t)(k0 + 2) * 1024];
            float4 w3 = *(const float4*)&wP[(size_t)(k0 + 3) * 1024];
            #pragma unroll
            for (int r = 0; r < 8; ++r) {
                float4 av = *(const float4*)&ct_s[r * 256 + k0];
                acc[r].x += av.x * w0.x; acc[r].y += av.x * w0.y;
                acc[r].z += av.x * w0.z; acc[r].w += av.x * w0.w;
                acc[r].x += av.y * w1.x; acc[r].y += av.y * w1.y;
                acc[r].z += av.y * w1.z; acc[r].w += av.y * w1.w;
                acc[r].x += av.z * w2.x; acc[r].y += av.z * w2.y;
                acc[r].z += av.z * w2.z; acc[r].w += av.z * w2.w;
                acc[r].x += av.w * w3.x; acc[r].y += av.w * w3.y;
                acc[r].z += av.w * w3.z; acc[r].w += av.w * w3.w;
            }
        }
    } else if (!first) {
        const float* wP = Wdh + c0;
        #pragma unroll 2
        for (int ch = 0; ch < 64; ++ch) {
            const int k0 = ch * 4;
            float4 w0 = *(const float4*)&wP[(size_t)(k0 + 0) * 1024];
            float4 w1 = *(const float4*)&wP[(size_t)(k0 + 1) * 1024];
            float4 w2 = *(const float4*)&wP[(size_t)(k0 + 2) * 1024];
            float4 w3 = *(const float4*)&wP[(size_t)(k0 + 3) * 1024];
            #pragma unroll
            for (int r = 0; r < 8; ++r) {
                float4 av = *(const float4*)&hd_s[r * 256 + k0];
                acc[r].x += av.x * w0.x; acc[r].y += av.x * w0.y;
                acc[r].z += av.x * w0.z; acc[r].w += av.x * w0.w;
                acc[r].x += av.y * w1.x; acc[r].y += av.y * w1.y;
                acc[r].z += av.y * w1.z; acc[r].w += av.y * w1.w;
                acc[r].x += av.z * w2.x; acc[r].y += av.z * w2.y;
                acc[r].z += av.z * w2.z; acc[r].w += av.z * w2.w;
                acc[r].x += av.w * w3.x; acc[r].y += av.w * w3.y;
                acc[r].z += av.w * w3.z; acc[r].w += av.w * w3.w;
            }
        }
    }
    #pragma unroll
    for (int r = 0; r < 8; ++r)
        *(float4*)&gate_s[half][r * 1024 + c0] = acc[r];
    __syncthreads();

    {
        const float* g0 = &gate_s[0][w * 1024 + lane * 4];
        const float* g1 = &gate_s[1][w * 1024 + lane * 4];
        float4 giA = *(const float4*)&g0[0],   giB = *(const float4*)&g1[0];
        float4 gfA = *(const float4*)&g0[256], gfB = *(const float4*)&g1[256];
        float4 ggA = *(const float4*)&g0[512], ggB = *(const float4*)&g1[512];
        float4 goA = *(const float4*)&g0[768], goB = *(const float4*)&g1[768];
        size_t ci = (size_t)(row0 + w) * 256 + lane * 4;
        float4 c4 = first ? make_float4(0.f, 0.f, 0.f, 0.f)
                          : *(const float4*)&c_st[ci];
        float cc[4] = { c4.x, c4.y, c4.z, c4.w };
        float gi[4] = { giA.x + giB.x, giA.y + giB.y, giA.z + giB.z, giA.w + giB.w };
        float gf[4] = { gfA.x + gfB.x, gfA.y + gfB.y, gfA.z + gfB.z, gfA.w + gfB.w };
        float gg[4] = { ggA.x + ggB.x, ggA.y + ggB.y, ggA.z + ggB.z, ggA.w + ggB.w };
        float go[4] = { goA.x + goB.x, goA.y + goB.y, goA.z + goB.z, goA.w + goB.w };
        float4 cn, hn;
        #pragma unroll
        for (int uu = 0; uu < 4; ++uu) {
            float cv = sigmoidf_(gf[uu]) * cc[uu] + sigmoidf_(gi[uu]) * tanhf_(gg[uu]);
            float hv = sigmoidf_(go[uu]) * tanhf_(cv);
            if (uu == 0) { cn.x = cv; hn.x = hv; } else if (uu == 1) { cn.y = cv; hn.y = hv; }
            else if (uu == 2) { cn.z = cv; hn.z = hv; } else { cn.w = cv; hn.w = hv; }
        }
        *(float4*)&c_st[ci] = cn;
        *(float4*)&hd[ci]   = hn;
    }
}

// ---------------------------------------------------------------------------
// Head: fc = tanh(h_d@Wf+bf); out[:,step] = tanh(fc@Wo+bo). Block = 16 rows.
// ---------------------------------------------------------------------------
__global__ __launch_bounds__(256) void head_k(
    const float* __restrict__ hd, const float* __restrict__ Wf,
    const float* __restrict__ bf, const float* __restrict__ Wo,
    const float* __restrict__ bo, float* __restrict__ out, int step)
{
    __shared__ float hd_s[16 * 256];
    __shared__ float fc_s[16 * 128];
    const int b0  = blockIdx.x * 16;
    const int tid = threadIdx.x;
    {
        const float4* hg = (const float4*)(hd + (size_t)b0 * 256);
        for (int i = tid; i < 1024; i += 256) ((float4*)hd_s)[i] = hg[i];
    }
    __syncthreads();
    {
        const int f = tid & 127, rg = tid >> 7;
        float acc[8];
        float bfv = bf[f];
        #pragma unroll
        for (int rr = 0; rr < 8; ++rr) acc[rr] = bfv;
        const float* wp = Wf + f;
        #pragma unroll 2
        for (int k = 0; k < 256; ++k) {
            float wv = wp[k * 128];
            #pragma unroll
            for (int rr = 0; rr < 8; ++rr) acc[rr] += hd_s[(rg * 8 + rr) * 256 + k] * wv;
        }
        for (int rr = 0; rr < 8; ++rr) fc_s[(rg * 8 + rr) * 128 + f] = tanhf_(acc[rr]);
    }
    __syncthreads();
    {
        const int lane = tid & 63, w = tid >> 6;
        const float bov = bo[0];
        #pragma unroll
        for (int rr = 0; rr < 4; ++rr) {
            int r = w * 4 + rr;
            float p = fc_s[r * 128 + lane] * Wo[lane] + fc_s[r * 128 + 64 + lane] * Wo[64 + lane];
            #pragma unroll
            for (int msk = 32; msk >= 1; msk >>= 1) p += __shfl_xor(p, msk, 64);
            if (lane == 0) out[(size_t)(b0 + r) * NOUT + step] = tanhf_(p + bov);
        }
    }
}

extern "C" void kernel_launch(void* const* d_in, const int* in_sizes, int n_in,
                              void* d_out, int out_size, void* d_ws, size_t ws_size,
                              hipStream_t stream)
{
    const float* x    = (const float*)d_in[0];
    const float* Wa   = (const float*)d_in[1];
    const float* ba   = (const float*)d_in[2];
    const float* Wi   = (const float*)d_in[3];
    const float* Wh   = (const float*)d_in[4];
    const float* be   = (const float*)d_in[5];
    const float* Wd   = (const float*)d_in[6];
    const float* bd   = (const float*)d_in[7];
    const float* Wl   = (const float*)d_in[8];
    const float* bl   = (const float*)d_in[9];
    const float* Wdi  = (const float*)d_in[10];
    const float* Wdh  = (const float*)d_in[11];
    const float* bdec = (const float*)d_in[12];
    const float* Wf   = (const float*)d_in[13];
    const float* bf   = (const float*)d_in[14];
    const float* Wo   = (const float*)d_in[15];
    const float* bo   = (const float*)d_in[16];
    float* out = (float*)d_out;

    // ws layout (floats): enc_out | hd | c_d | ctx(=hp=wprep alias) | scores | [ep]
    const size_t f_enc    = (size_t)LL * BB * EE;     // 52,428,800
    const size_t f_state  = (size_t)BB * EE;          // 524,288
    const size_t f_scores = (size_t)LL * BB;          // 204,800
    const size_t need3 = (f_enc + 3 * f_state + f_scores) * sizeof(float);
    const size_t need2 = need3 + f_enc * sizeof(u16);
    const size_t need1 = need3 + f_enc * sizeof(float);

    float* ws      = (float*)d_ws;
    float* enc_out = ws;
    float* hd      = enc_out + f_enc;
    float* c_d     = hd + f_state;
    float* ctx     = c_d + f_state;      // also hp AND the weight-prep buffer
    float* scores  = ctx + f_state;      //   (disjoint lifetimes)
    float* ep32    = scores + f_scores;  // tier 1 only
    u16*   ep16    = (u16*)(scores + f_scores);  // tier 2 only
    float* hp      = ctx;
    u16*   wprep   = (u16*)ctx;          // 808 tiles x 2 KB = 1.616 MB <= 2 MB
    // encoder h-exchange buffer aliases hd|c_d (4 MB combined, dead during
    // encoder); flags alias scores (dead during encoder), 128 B/group.
    float* hbuf    = hd;
    u32*   flags   = (u32*)scores;

    if (ws_size < need3) return;   // diagnostic clean-fail (known satisfied)
    const int tier = (ws_size >= need1) ? 1 : (ws_size >= need2) ? 2 : 3;

    // zero the group sync counters (replayed as a graph node each launch)
    hipMemsetAsync(flags, 0, 64 * 32 * sizeof(u32), stream);
    // weights -> bf16 hi/lo MFMA fragments (ctx region is dead here)
    w_prep<<<680, 64, 0, stream>>>(Wi, Wh, Wa, wprep);
    w_prep2<<<128, 64, 0, stream>>>(Wd, wprep);
    // persistent MFMA encoder: 256 blocks x 1024 threads (1/CU, co-resident)
    enc_mfma4<<<256, 1024, 0, stream>>>(x, ba, be, wprep, enc_out, hbuf, flags);

    // hoist the step-invariant enc_out @ Wd_top out of the decode loop
    if (tier == 1)
        gemm_ep_mfma<<<(LL * BB) / 32, 256, 0, stream>>>(enc_out, wprep, ep32);
    else
        pack_ep<<<(LL * BB) / 32, 256, 0, stream>>>(
            enc_out, Wd, ep16, tier == 3 ? 1 : 0);

    for (int s = 0; s < NOUT; ++s) {
        // hp = hd @ Wd_bot + bd  (step 0: hd == 0 -> hp = bd)
        gemm_nk256<<<BB / 32, 256, 0, stream>>>(
            hd, Wd + 256 * 256, bd, hp, s == 0);
        if (tier == 1)
            scores_ep_f32<<<dim3(BB / 8, 5), 256, 0, stream>>>(ep32, hp, Wl, scores);
        else if (tier == 2)
            scores_ep_b16<<<dim3(BB / 8, 5), 256, 0, stream>>>(ep16, hp, Wl, scores, 256, 0);
        else
            scores_ep_b16<<<dim3(BB / 8, 5), 256, 0, stream>>>(
                (const u16*)enc_out, hp, Wl, scores, 512, 256);
        if (tier == 3)
            softmax_ctx_b16<<<BB / 8, 256, 0, stream>>>(scores, (const u16*)enc_out, ctx);
        else
            softmax_ctx<<<BB / 8, 256, 0, stream>>>(scores, enc_out, ctx);
        dec_step<<<BB / 8, 512, 0, stream>>>(ctx, Wdi, Wdh, bdec, hd, c_d, s == 0);
        head_k<<<BB / 16, 256, 0, stream>>>(hd, Wf, bf, Wo, bo, out, s);
    }
}

// Round 10
// 2292.077 us; speedup vs baseline: 1.1593x; 1.1351x over previous
//
#include <hip/hip_runtime.h>
#include <math.h>

// Problem constants
#define BB 2048
#define LL 100
#define FF 64
#define EE 256
#define DD 256
#define NOUT 3

#define COMP(v, i) ((i) == 0 ? (v).x : (i) == 1 ? (v).y : (i) == 2 ? (v).z : (v).w)

typedef unsigned short u16;
typedef unsigned int u32;
typedef __attribute__((ext_vector_type(8))) __bf16 bf16x8;
typedef __attribute__((ext_vector_type(4))) float f32x4;
typedef __attribute__((ext_vector_type(2))) float f32x2;

#define MFMA_(A, B, C) __builtin_amdgcn_mfma_f32_16x16x32_bf16((A), (B), (C), 0, 0, 0)

__device__ __forceinline__ float sigmoidf_(float x) {
    return 1.0f / (1.0f + expf(-x));
}
// tanh via identity 1 - 2/(1+e^{2x}); ~2e-7 abs fp32 error, saturates correctly.
__device__ __forceinline__ float tanhf_(float x) {
    return 1.0f - 2.0f / (1.0f + expf(2.0f * x));
}
// fp32 -> bf16 round-to-nearest-even
__device__ __forceinline__ u16 f2b_(float f) {
    u32 u = __float_as_uint(f);
    u = (u + 0x7FFFu + ((u >> 16) & 1u)) >> 16;
    return (u16)u;
}
__device__ __forceinline__ float b2f_(u16 b) {
    return __uint_as_float(((u32)b) << 16);
}
__device__ __forceinline__ u32 pack2_(float a, float b) {
    return (u32)f2b_(a) | ((u32)f2b_(b) << 16);
}
__device__ __forceinline__ f32x4 splat4(float b) {
    f32x4 v; v[0] = b; v[1] = b; v[2] = b; v[3] = b; return v;
}
// split 8 fp32 into bf16 hi/lo planes packed as uint4 (little-endian pairs)
__device__ __forceinline__ void split8(const float* v, uint4& H, uint4& L) {
    u16 h[8], lo[8];
    #pragma unroll
    for (int e = 0; e < 8; ++e) {
        h[e]  = f2b_(v[e]);
        lo[e] = f2b_(v[e] - b2f_(h[e]));
    }
    H = make_uint4((u32)h[0]  | ((u32)h[1]  << 16), (u32)h[2]  | ((u32)h[3]  << 16),
                   (u32)h[4]  | ((u32)h[5]  << 16), (u32)h[6]  | ((u32)h[7]  << 16));
    L = make_uint4((u32)lo[0] | ((u32)lo[1] << 16), (u32)lo[2] | ((u32)lo[3] << 16),
                   (u32)lo[4] | ((u32)lo[5] << 16), (u32)lo[6] | ((u32)lo[7] << 16));
}

// Encoder A-fragment LDS index: [mt][kt(10)][plane][lane][8] u16.
// AFX bank swizzle (R7-verified): stored lane = ln ^ ((ln>>4)&3). Pure storage
// permutation; readers use the same macro with ln = hardware lane, so reads
// stay full-tile conflict-free while scatter writes spread across banks
// (SQ_LDS_BANK_CONFLICT 6.5e7 -> 1.6e7 measured).
#define AF(mt, kt, p, ln) (((((mt) * 10 + (kt)) * 2 + (p)) * 64 + (ln)) * 8)
#define AFX(mt, kt, p, ln) AF(mt, kt, p, (ln) ^ (((ln) >> 4) & 3))
// ep-GEMM A-fragment LDS index: [mt][kt(8)][plane][lane][8] u16
#define AF2(mt, kt, p, ln) (((((mt) * 8 + (kt)) * 2 + (p)) * 64 + (ln)) * 8)

// ---------------------------------------------------------------------------
// Weight prep (once per launch, into the dead ctx region):
// bf16 hi/lo split of [Wi;Wh] (tiles 0..639) and Wa (tiles 640..679) in MFMA
// B-fragment order. Tile (nt,kt) = 1024 u16: plane-hi [64 lanes][8 e], then lo.
// Element (lane l, e) = W[k = kt*32 + (l>>4)*8 + e][col = nt*16 + (l&15)].
// ---------------------------------------------------------------------------
__global__ __launch_bounds__(64) void w_prep(
    const float* __restrict__ Wi, const float* __restrict__ Wh,
    const float* __restrict__ Wa, u16* __restrict__ wp)
{
    const int bid = blockIdx.x;      // 0..679
    const int l   = threadIdx.x;     // 0..63
    const int isA = (bid >= 640);
    const int b2  = isA ? bid - 640 : bid;
    const int nt  = b2 / 10, kt = b2 - nt * 10;
    const int col = nt * 16 + (l & 15);

    float v[8];
    #pragma unroll
    for (int e = 0; e < 8; ++e) {
        const int k = kt * 32 + ((l >> 4) << 3) + e;
        v[e] = isA ? Wa[(size_t)k * 64 + col]
                   : (k < 64 ? Wi[(size_t)k * 1024 + col]
                             : Wh[(size_t)(k - 64) * 1024 + col]);
    }
    uint4 H, L;
    split8(v, H, L);
    *(uint4*)&wp[(size_t)bid * 1024 + (size_t)l * 8]       = H;
    *(uint4*)&wp[(size_t)bid * 1024 + 512 + (size_t)l * 8] = L;
}

// ---------------------------------------------------------------------------
// Wd_top (256x256) -> hi/lo MFMA tiles 680..807 (nt 0..15, kt 0..7).
// ---------------------------------------------------------------------------
__global__ __launch_bounds__(64) void w_prep2(
    const float* __restrict__ Wd, u16* __restrict__ wp)
{
    const int bid = blockIdx.x;      // 0..127
    const int l   = threadIdx.x;
    const int nt  = bid >> 3, kt = bid & 7;
    const int col = nt * 16 + (l & 15);
    float v[8];
    #pragma unroll
    for (int e = 0; e < 8; ++e) {
        const int k = kt * 32 + ((l >> 4) << 3) + e;
        v[e] = Wd[(size_t)k * 256 + col];
    }
    uint4 H, L;
    split8(v, H, L);
    u16* tp = wp + (size_t)(680 + bid) * 1024;
    *(uint4*)&tp[(size_t)l * 8]       = H;
    *(uint4*)&tp[512 + (size_t)l * 8] = L;
}

// ---------------------------------------------------------------------------
// Persistent MFMA encoder. Sync protocol is BYTE-FOR-BYTE the measured-1484us
// R4 structure: S1 = tid==0 poll of flags[g] (4B stride) + barrier, THEN all
// staging threads load. (R7-R9 evidence: distributed polling from 12 waves
// costs 150-280us -- the spin's LLC traffic collides with partner epilogue
// write-throughs.) On top of R4: AFX swizzle + padded gate_s (LDS-local,
// PMC-verified: conflicts 6.5e7 -> 1.6e7).
// Grid 256 x 1024 (1 block/CU). Block (g 0..63, p 0..3): rows g*32..+32,
// hidden units p*64..+64. Wave w owns N-tile nt = (w>>2)*16 + p*4 + (w&3);
// its B-hi plane (40 VGPR) is register-resident; B-lo + Wa stream from L2.
// Bounded spin: no hang possible.
// ---------------------------------------------------------------------------
__global__ __launch_bounds__(1024) void enc_mfma4(
    const float* __restrict__ x,
    const float* __restrict__ ba, const float* __restrict__ be,
    const u16* __restrict__ wp,
    float* __restrict__ enc_out,
    float* __restrict__ hbuf,          // [2][BB][256] fp32 (aliases hd|c_d)
    u32* __restrict__ flags)           // [64] monotonic counters (memset 0)
{
    __shared__ u16   aFrag[20480];         // 40 KB A-fragments (bf16 hi/lo)
    __shared__ float x_s[32 * 68];         // 8.5 KB x fp32
    __shared__ float e_s[32 * 68];         // 8.5 KB attention energies
    __shared__ float gate_s[4][32][66];    // 33 KB gates, padded stride 66

    const int bid = blockIdx.x;
    const int g   = (bid & 7) | ((bid >> 5) << 3);   // group 0..63
    const int p   = (bid >> 3) & 3;                  // unit-quarter
    const int row0 = g * 32;
    const int tid = threadIdx.x;
    const int l   = tid & 63;
    const int w   = tid >> 6;                        // wave 0..15

    // zero aFrag (h region must be 0 at t=0)
    for (int v = tid; v < 20480 / 2; v += 1024) ((u32*)aFrag)[v] = 0u;

    // per-wave N-tile; B-hi plane register-resident (40 VGPR)
    const int ntW = (w >> 2) * 16 + p * 4 + (w & 3);
    uint4 BhR[10];
    #pragma unroll
    for (int kt = 0; kt < 10; ++kt)
        BhR[kt] = *(const uint4*)&wp[(size_t)(ntW * 10 + kt) * 1024 + (size_t)l * 8];

    const float be_r = be[(size_t)ntW * 16 + (l & 15)];
    const float ba_r = (w < 8) ? ba[(w & 3) * 16 + (l & 15)] : 0.f;

    float c_state[2] = {0.f, 0.f};

    __syncthreads();

    for (int t = 0; t < LL; ++t) {
        // ---- S1: wait for all 4 partner blocks to finish t-1 (R4 exact) ----
        if (t > 0) {
            if (tid == 0) {
                const u32 target = 4u * (u32)t;
                int guard = 0;
                while (__hip_atomic_load(&flags[g], __ATOMIC_RELAXED,
                                         __HIP_MEMORY_SCOPE_AGENT) < target) {
                    __builtin_amdgcn_s_sleep(1);
                    if (++guard > 2000000) break;   // bounded: no GPU hang
                }
            }
            __syncthreads();
        }

        // ---- P0: stage x_t frags (tid<256) | partner-h frags (tid>=256) ----
        if (tid < 256) {
            const int kt2 = tid >> 7;          // 0..1
            const int mt  = (tid >> 6) & 1;    // 0..1
            const int l2  = tid & 63;
            const int row2 = mt * 16 + (l2 & 15);
            const int f0   = kt2 * 32 + ((l2 >> 4) << 3);
            const float* xp = x + (size_t)(row0 + row2) * (LL * FF) + (size_t)t * FF + f0;
            float4 xa = *(const float4*)xp;
            float4 xb = *(const float4*)(xp + 4);
            float v[8] = {xa.x, xa.y, xa.z, xa.w, xb.x, xb.y, xb.z, xb.w};
            uint4 H, L;
            split8(v, H, L);
            *(uint4*)&aFrag[AFX(mt, kt2, 0, l2)] = H;
            *(uint4*)&aFrag[AFX(mt, kt2, 1, l2)] = L;
            *(float4*)&x_s[row2 * 68 + f0]     = xa;
            *(float4*)&x_s[row2 * 68 + f0 + 4] = xb;
        } else if (t > 0) {
            const int v   = tid - 256;         // 0..767
            const int prl = v >> 8;            // 0..2 (relative partner)
            const int vv  = v & 255;
            const int row = vv >> 3;           // 0..31
            const int i8  = vv & 7;            // 8-unit chunk
            const int ugp = (p + 1 + prl) & 3;
            const int u8  = ugp * 64 + i8 * 8; // global unit base (mult of 8)
            const float* hp_g = hbuf + ((size_t)((t - 1) & 1) * BB + row0 + row) * 256 + u8;
            f32x4 a4, b4;
            asm volatile("global_load_dwordx4 %0, %2, off sc0 sc1\n\t"
                         "global_load_dwordx4 %1, %3, off sc0 sc1\n\t"
                         "s_waitcnt vmcnt(0)"
                         : "=v"(a4), "=v"(b4)
                         : "v"(hp_g), "v"(hp_g + 4) : "memory");
            float v8[8] = {a4[0], a4[1], a4[2], a4[3], b4[0], b4[1], b4[2], b4[3]};
            uint4 H, L;
            split8(v8, H, L);
            const int mt = row >> 4, rowT = row & 15;
            const int kt_h = 2 + (u8 >> 5);
            const int g2   = (u8 & 31) >> 3;
            const int ln   = rowT + (g2 << 4);
            *(uint4*)&aFrag[AFX(mt, kt_h, 0, ln)] = H;
            *(uint4*)&aFrag[AFX(mt, kt_h, 1, ln)] = L;
        }
        __syncthreads();   // A: x/h fragments visible

        // ---- P1: attention energies (waves 0..7: mt = w>>2, nta = w&3) ----
        if (w < 8) {
            const int mt  = w >> 2;
            const int nta = w & 3;
            f32x4 ea = splat4(ba_r);
            #pragma unroll
            for (int kt = 0; kt < 10; ++kt) {
                bf16x8 Ah = *(const bf16x8*)&aFrag[AFX(mt, kt, 0, l)];
                bf16x8 Al = *(const bf16x8*)&aFrag[AFX(mt, kt, 1, l)];
                const size_t o = (size_t)(640 + nta * 10 + kt) * 1024 + (size_t)l * 8;
                bf16x8 Bh = *(const bf16x8*)&wp[o];
                bf16x8 Bl = *(const bf16x8*)&wp[o + 512];
                ea = MFMA_(Ah, Bh, ea);
                ea = MFMA_(Al, Bh, ea);
                ea = MFMA_(Ah, Bl, ea);
            }
            const int colA = nta * 16 + (l & 15);
            #pragma unroll
            for (int r = 0; r < 4; ++r) {
                const int rowT = ((l >> 4) << 2) + r;
                e_s[(mt * 16 + rowT) * 68 + colA] = tanhf_(ea[r]);
            }
        }
        __syncthreads();   // B: energies staged

        // ---- P2: softmax over 64 cols + ein fragments (tid<512) ----
        if (tid < 512) {
            const int row2 = tid >> 4;           // 0..31
            const int c4   = (tid & 15) * 4;     // 0..60
            float4 ev = *(const float4*)&e_s[row2 * 68 + c4];
            float m = fmaxf(fmaxf(ev.x, ev.y), fmaxf(ev.z, ev.w));
            #pragma unroll
            for (int msk = 8; msk >= 1; msk >>= 1) m = fmaxf(m, __shfl_xor(m, msk, 64));
            float4 ex;
            ex.x = expf(ev.x - m); ex.y = expf(ev.y - m);
            ex.z = expf(ev.z - m); ex.w = expf(ev.w - m);
            float s = ex.x + ex.y + ex.z + ex.w;
            #pragma unroll
            for (int msk = 8; msk >= 1; msk >>= 1) s += __shfl_xor(s, msk, 64);
            const float inv = 1.f / s;
            float4 xv = *(const float4*)&x_s[row2 * 68 + c4];
            float ein[4] = { ex.x * inv * xv.x, ex.y * inv * xv.y,
                             ex.z * inv * xv.z, ex.w * inv * xv.w };
            const int mt   = row2 >> 4;
            const int rowT = row2 & 15;
            const int kt   = c4 >> 5;
            const int g2   = (c4 & 31) >> 3;
            const int e0   = c4 & 7;             // 0 or 4
            const int ln   = rowT + (g2 << 4);
            ushort4 h4, l4;
            #pragma unroll
            for (int e = 0; e < 4; ++e) {
                u16 hh = f2b_(ein[e]);
                u16 ll = f2b_(ein[e] - b2f_(hh));
                if (e == 0) { h4.x = hh; l4.x = ll; } else if (e == 1) { h4.y = hh; l4.y = ll; }
                else if (e == 2) { h4.z = hh; l4.z = ll; } else { h4.w = hh; l4.w = ll; }
            }
            *(ushort4*)&aFrag[AFX(mt, kt, 0, ln) + e0] = h4;
            *(ushort4*)&aFrag[AFX(mt, kt, 1, ln) + e0] = l4;
        }
        __syncthreads();   // C: ein fragments staged

        // ---- P3: gate GEMM, B-hi from registers, B-lo streamed (L2) ----
        f32x4 acc0 = splat4(be_r), acc1 = splat4(be_r);
        #pragma unroll
        for (int kt = 0; kt < 10; ++kt) {
            bf16x8 Ah0 = *(const bf16x8*)&aFrag[AFX(0, kt, 0, l)];
            bf16x8 Al0 = *(const bf16x8*)&aFrag[AFX(0, kt, 1, l)];
            bf16x8 Ah1 = *(const bf16x8*)&aFrag[AFX(1, kt, 0, l)];
            bf16x8 Al1 = *(const bf16x8*)&aFrag[AFX(1, kt, 1, l)];
            bf16x8 Bl  = *(const bf16x8*)&wp[(size_t)(ntW * 10 + kt) * 1024 + 512 + (size_t)l * 8];
            bf16x8 Bh  = __builtin_bit_cast(bf16x8, BhR[kt]);
            acc0 = MFMA_(Ah0, Bh, acc0);
            acc1 = MFMA_(Ah1, Bh, acc1);
            acc0 = MFMA_(Al0, Bh, acc0);
            acc1 = MFMA_(Al1, Bh, acc1);
            acc0 = MFMA_(Ah0, Bl, acc0);
            acc1 = MFMA_(Ah1, Bl, acc1);
        }
        // stage gates: gate = w>>2, unit_local = (w&3)*16 + (l&15)
        {
            const int gate = w >> 2;
            const int ulb  = (w & 3) * 16 + (l & 15);
            #pragma unroll
            for (int r = 0; r < 4; ++r) {
                const int rT = ((l >> 4) << 2) + r;
                gate_s[gate][rT][ulb]      = acc0[r];
                gate_s[gate][16 + rT][ulb] = acc1[r];
            }
        }
        __syncthreads();   // D: gates staged; aFrag reads done

        // ---- epilogue: 1024 threads x 2 cells; h out + own h-frags ----
        {
            const int row = tid >> 5;            // 0..31
            const int q2  = (tid & 31) * 2;      // unit_local 0..62 even
            float gi0 = gate_s[0][row][q2], gi1 = gate_s[0][row][q2 + 1];
            float gf0 = gate_s[1][row][q2], gf1 = gate_s[1][row][q2 + 1];
            float gg0 = gate_s[2][row][q2], gg1 = gate_s[2][row][q2 + 1];
            float go0 = gate_s[3][row][q2], go1 = gate_s[3][row][q2 + 1];
            float cv0 = sigmoidf_(gf0) * c_state[0] + sigmoidf_(gi0) * tanhf_(gg0);
            float cv1 = sigmoidf_(gf1) * c_state[1] + sigmoidf_(gi1) * tanhf_(gg1);
            c_state[0] = cv0; c_state[1] = cv1;
            float hv0 = sigmoidf_(go0) * tanhf_(cv0);
            float hv1 = sigmoidf_(go1) * tanhf_(cv1);
            const int u_g = p * 64 + q2;
            // enc_out (plain store)
            *(float2*)&enc_out[((size_t)t * BB + row0 + row) * 256 + u_g]
                = make_float2(hv0, hv1);
            // hbuf write-through (coherence point) for partner blocks
            float* hp_g = hbuf + ((size_t)(t & 1) * BB + row0 + row) * 256 + u_g;
            f32x2 hv2; hv2[0] = hv0; hv2[1] = hv1;
            asm volatile("global_store_dwordx2 %0, %1, off sc0 sc1"
                         :: "v"(hp_g), "v"(hv2) : "memory");
            // own h-fragments for t+1
            const int mt = row >> 4, rowT = row & 15;
            const int kt_h = 2 + (u_g >> 5);
            const int g2   = (u_g & 31) >> 3;
            const int ln   = rowT + (g2 << 4);
            const int e    = u_g & 7;            // even
            ((u32*)aFrag)[(AFX(mt, kt_h, 0, ln) + e) >> 1] = pack2_(hv0, hv1);
            u16 h0 = f2b_(hv0), h1 = f2b_(hv1);
            ((u32*)aFrag)[(AFX(mt, kt_h, 1, ln) + e) >> 1] =
                (u32)f2b_(hv0 - b2f_(h0)) | ((u32)f2b_(hv1 - b2f_(h1)) << 16);
        }
        asm volatile("s_waitcnt vmcnt(0)" ::: "memory");   // h stores complete
        __syncthreads();   // E: all waves' stores acked
        if (tid == 0)
            __hip_atomic_fetch_add(&flags[g], 1u, __ATOMIC_RELEASE,
                                   __HIP_MEMORY_SCOPE_AGENT);
    }
}

// ---------------------------------------------------------------------------
// ep = enc_out @ Wd_top via split-bf16 MFMA (tier 1 hoisted GEMM).
// Grid M/32 x 256 threads (4 waves). Wave w owns nt = w*4..w*4+3.
// ---------------------------------------------------------------------------
__global__ __launch_bounds__(256) void gemm_ep_mfma(
    const float* __restrict__ A, const u16* __restrict__ wp,
    float* __restrict__ C)
{
    __shared__ u16   aF[2 * 8 * 2 * 64 * 8];   // 32 KB A-fragments
    __shared__ float c_s[32 * 260];            // 32.5 KB C staging (padded)
    const int m0  = blockIdx.x * 32;
    const int tid = threadIdx.x;
    const int l   = tid & 63;
    const int w   = tid >> 6;                  // 0..3

    for (int s = tid; s < 1024; s += 256) {
        const int mt = s >> 9, kt = (s >> 6) & 7, l2 = s & 63;
        const int row2 = mt * 16 + (l2 & 15);
        const int k0   = kt * 32 + ((l2 >> 4) << 3);
        const float* ap = A + (size_t)(m0 + row2) * 256 + k0;
        float4 xa = *(const float4*)ap;
        float4 xb = *(const float4*)(ap + 4);
        float v[8] = {xa.x, xa.y, xa.z, xa.w, xb.x, xb.y, xb.z, xb.w};
        uint4 H, L;
        split8(v, H, L);
        *(uint4*)&aF[AF2(mt, kt, 0, l2)] = H;
        *(uint4*)&aF[AF2(mt, kt, 1, l2)] = L;
    }
    __syncthreads();

    f32x4 acc[2][4];
    #pragma unroll
    for (int mt = 0; mt < 2; ++mt)
        #pragma unroll
        for (int j = 0; j < 4; ++j) acc[mt][j] = splat4(0.f);

    #pragma unroll
    for (int kt = 0; kt < 8; ++kt) {
        bf16x8 Ah0 = *(const bf16x8*)&aF[AF2(0, kt, 0, l)];
        bf16x8 Al0 = *(const bf16x8*)&aF[AF2(0, kt, 1, l)];
        bf16x8 Ah1 = *(const bf16x8*)&aF[AF2(1, kt, 0, l)];
        bf16x8 Al1 = *(const bf16x8*)&aF[AF2(1, kt, 1, l)];
        #pragma unroll
        for (int j = 0; j < 4; ++j) {
            const int nt = w * 4 + j;
            const u16* bt = wp + (size_t)(680 + nt * 8 + kt) * 1024 + (size_t)l * 8;
            bf16x8 Bh = *(const bf16x8*)bt;
            bf16x8 Bl = *(const bf16x8*)(bt + 512);
            acc[0][j] = MFMA_(Ah0, Bh, acc[0][j]);
            acc[1][j] = MFMA_(Ah1, Bh, acc[1][j]);
            acc[0][j] = MFMA_(Al0, Bh, acc[0][j]);
            acc[1][j] = MFMA_(Al1, Bh, acc[1][j]);
            acc[0][j] = MFMA_(Ah0, Bl, acc[0][j]);
            acc[1][j] = MFMA_(Ah1, Bl, acc[1][j]);
        }
    }

    #pragma unroll
    for (int mt = 0; mt < 2; ++mt)
        #pragma unroll
        for (int j = 0; j < 4; ++j) {
            const int col = (w * 4 + j) * 16 + (l & 15);
            #pragma unroll
            for (int r = 0; r < 4; ++r) {
                const int row = mt * 16 + ((l >> 4) << 2) + r;
                c_s[row * 260 + col] = acc[mt][j][r];
            }
        }
    __syncthreads();
    for (int v = tid; v < 32 * 64; v += 256) {
        const int row = v >> 6, c4 = (v & 63) << 2;
        *(float4*)&C[(size_t)(m0 + row) * 256 + c4] = *(const float4*)&c_s[row * 260 + c4];
    }
}

// ---------------------------------------------------------------------------
// Generic fp32 GEMM C(M,256) = A(M,256) @ W(256,256) [+ bias].
// Block = 32 rows, 256 threads. skip_gemm: C = bias (decoder step 0, hd==0).
// Used for: hp = hd @ Wd_bot + bd.
// ---------------------------------------------------------------------------
__global__ __launch_bounds__(256) void gemm_nk256(
    const float* __restrict__ A, const float* __restrict__ W,
    const float* __restrict__ bias, float* __restrict__ C, int skip_gemm)
{
    __shared__ float a_s[32 * 256];   // 32 KB
    const int m0   = blockIdx.x * 32;
    const int tid  = threadIdx.x;
    const int lane = tid & 63;
    const int rg   = tid >> 6;        // 0..3 -> rows rg*8..rg*8+7
    const int n0   = lane * 4;

    float4 bias4 = make_float4(0.f, 0.f, 0.f, 0.f);
    if (bias) bias4 = *(const float4*)&bias[n0];

    if (skip_gemm) {
        #pragma unroll
        for (int r = 0; r < 8; ++r)
            *(float4*)&C[(size_t)(m0 + rg * 8 + r) * 256 + n0] = bias4;
        return;
    }

    for (int v = tid; v < 32 * 64; v += 256)
        ((float4*)a_s)[v] = ((const float4*)(A + (size_t)m0 * 256))[v];
    __syncthreads();

    float4 acc[8];
    #pragma unroll
    for (int r = 0; r < 8; ++r) acc[r] = bias4;

    #pragma unroll 2
    for (int k = 0; k < 256; k += 4) {
        float4 wv[4];
        #pragma unroll
        for (int kk = 0; kk < 4; ++kk)
            wv[kk] = *(const float4*)&W[(size_t)(k + kk) * 256 + n0];
        float4 av[8];
        #pragma unroll
        for (int r = 0; r < 8; ++r)
            av[r] = *(const float4*)&a_s[(rg * 8 + r) * 256 + k];
        #pragma unroll
        for (int kk = 0; kk < 4; ++kk) {
            #pragma unroll
            for (int r = 0; r < 8; ++r) {
                float e = COMP(av[r], kk);
                acc[r].x += e * wv[kk].x; acc[r].y += e * wv[kk].y;
                acc[r].z += e * wv[kk].z; acc[r].w += e * wv[kk].w;
            }
        }
    }
    #pragma unroll
    for (int r = 0; r < 8; ++r)
        *(float4*)&C[(size_t)(m0 + rg * 8 + r) * 256 + n0] = acc[r];
}

// ---------------------------------------------------------------------------
// ep = enc_out @ Wd_top, emitted as bf16 (tiers 2/3 fallback).
// ---------------------------------------------------------------------------
__global__ __launch_bounds__(256) void pack_ep(
    float* A, const float* __restrict__ W, u16* epOut, int packed)
{
    __shared__ float a_s[32 * 256];   // 32 KB
    const int m0   = blockIdx.x * 32;
    const int tid  = threadIdx.x;
    const int lane = tid & 63;
    const int rg   = tid >> 6;
    const int n0   = lane * 4;

    for (int v = tid; v < 32 * 64; v += 256)
        ((float4*)a_s)[v] = ((const float4*)(A + (size_t)m0 * 256))[v];
    __syncthreads();

    float4 acc[8];
    #pragma unroll
    for (int r = 0; r < 8; ++r) acc[r] = make_float4(0.f, 0.f, 0.f, 0.f);

    #pragma unroll 2
    for (int k = 0; k < 256; k += 4) {
        float4 wv[4];
        #pragma unroll
        for (int kk = 0; kk < 4; ++kk)
            wv[kk] = *(const float4*)&W[(size_t)(k + kk) * 256 + n0];
        float4 av[8];
        #pragma unroll
        for (int r = 0; r < 8; ++r)
            av[r] = *(const float4*)&a_s[(rg * 8 + r) * 256 + k];
        #pragma unroll
        for (int kk = 0; kk < 4; ++kk) {
            #pragma unroll
            for (int r = 0; r < 8; ++r) {
                float e = COMP(av[r], kk);
                acc[r].x += e * wv[kk].x; acc[r].y += e * wv[kk].y;
                acc[r].z += e * wv[kk].z; acc[r].w += e * wv[kk].w;
            }
        }
    }

    u16* epu = packed ? (u16*)A : epOut;
    #pragma unroll
    for (int r = 0; r < 8; ++r) {
        const size_t row = (size_t)(m0 + rg * 8 + r);
        ushort4 o;
        o.x = f2b_(acc[r].x); o.y = f2b_(acc[r].y);
        o.z = f2b_(acc[r].z); o.w = f2b_(acc[r].w);
        u16* dst = packed ? (epu + row * 512 + 256 + n0)
                          : (epu + row * 256 + n0);
        *(ushort4*)dst = o;
    }

    if (packed) {
        u32* ab = (u32*)A;
        for (int v = tid; v < 32 * 128; v += 256) {
            const int row = v >> 7, j = v & 127;
            float2 f = *(const float2*)&a_s[(row << 8) + (j << 1)];
            ab[((size_t)(m0 + row)) * 256 + j] = pack2_(f.x, f.y);
        }
    }
}

// ---------------------------------------------------------------------------
// Per-step decoder scores from precomputed fp32 ep (tier 1):
//   score[l,b] = Wl . tanh(ep[l,b,:] + hp[b,:])   (bl cancels in softmax)
// ---------------------------------------------------------------------------
__global__ __launch_bounds__(256) void scores_ep_f32(
    const float* __restrict__ ep, const float* __restrict__ hp,
    const float* __restrict__ Wl, float* __restrict__ scores)
{
    __shared__ float hp_s[8 * 256];
    const int b0  = blockIdx.x * 8;
    const int l0  = blockIdx.y * 20;
    const int tid = threadIdx.x;
    const int r   = tid >> 5;
    const int g   = tid & 31;

    for (int v = tid; v < 512; v += 256)
        ((float4*)hp_s)[v] = ((const float4*)(hp + (size_t)b0 * 256))[v];
    __syncthreads();

    const float4 wl0 = *(const float4*)&Wl[g * 4];
    const float4 wl1 = *(const float4*)&Wl[128 + g * 4];
    const float4 h0  = *(const float4*)&hp_s[r * 256 + g * 4];
    const float4 h1  = *(const float4*)&hp_s[r * 256 + 128 + g * 4];
    const float* eb  = ep + (size_t)l0 * (BB * 256) + (size_t)(b0 + r) * 256;

    #pragma unroll 2
    for (int li = 0; li < 20; ++li) {
        float4 e0 = *(const float4*)&eb[(size_t)li * (BB * 256) + g * 4];
        float4 e1 = *(const float4*)&eb[(size_t)li * (BB * 256) + 128 + g * 4];
        float p = tanhf_(e0.x + h0.x) * wl0.x + tanhf_(e0.y + h0.y) * wl0.y
                + tanhf_(e0.z + h0.z) * wl0.z + tanhf_(e0.w + h0.w) * wl0.w
                + tanhf_(e1.x + h1.x) * wl1.x + tanhf_(e1.y + h1.y) * wl1.y
                + tanhf_(e1.z + h1.z) * wl1.z + tanhf_(e1.w + h1.w) * wl1.w;
        #pragma unroll
        for (int msk = 16; msk >= 1; msk >>= 1) p += __shfl_xor(p, msk, 64);
        if (g == 0) scores[(size_t)(l0 + li) * BB + b0 + r] = p;
    }
}

// ---------------------------------------------------------------------------
// Same, from bf16 ep rows (tiers 2/3). sstr/soff in u16 units.
// ---------------------------------------------------------------------------
__global__ __launch_bounds__(256) void scores_ep_b16(
    const u16* __restrict__ ep, const float* __restrict__ hp,
    const float* __restrict__ Wl, float* __restrict__ scores,
    int sstr, int soff)
{
    __shared__ float hp_s[8 * 256];
    const int b0  = blockIdx.x * 8;
    const int l0  = blockIdx.y * 20;
    const int tid = threadIdx.x;
    const int r   = tid >> 5;
    const int g   = tid & 31;

    for (int v = tid; v < 512; v += 256)
        ((float4*)hp_s)[v] = ((const float4*)(hp + (size_t)b0 * 256))[v];
    __syncthreads();

    const float4 wl0 = *(const float4*)&Wl[g * 4];
    const float4 wl1 = *(const float4*)&Wl[128 + g * 4];
    const float4 h0  = *(const float4*)&hp_s[r * 256 + g * 4];
    const float4 h1  = *(const float4*)&hp_s[r * 256 + 128 + g * 4];

    #pragma unroll 2
    for (int li = 0; li < 20; ++li) {
        const u16* er = ep + ((size_t)(l0 + li) * BB + b0 + r) * sstr + soff;
        ushort4 u0 = *(const ushort4*)&er[g * 4];
        ushort4 u1 = *(const ushort4*)&er[128 + g * 4];
        float p = tanhf_(b2f_(u0.x) + h0.x) * wl0.x + tanhf_(b2f_(u0.y) + h0.y) * wl0.y
                + tanhf_(b2f_(u0.z) + h0.z) * wl0.z + tanhf_(b2f_(u0.w) + h0.w) * wl0.w
                + tanhf_(b2f_(u1.x) + h1.x) * wl1.x + tanhf_(b2f_(u1.y) + h1.y) * wl1.y
                + tanhf_(b2f_(u1.z) + h1.z) * wl1.z + tanhf_(b2f_(u1.w) + h1.w) * wl1.w;
        #pragma unroll
        for (int msk = 16; msk >= 1; msk >>= 1) p += __shfl_xor(p, msk, 64);
        if (g == 0) scores[(size_t)(l0 + li) * BB + b0 + r] = p;
    }
}

// ---------------------------------------------------------------------------
// softmax over L + ctx. fp32 enc variant (tiers 1/2). Block = 8 rows.
// ---------------------------------------------------------------------------
__global__ __launch_bounds__(256) void softmax_ctx(
    const float* __restrict__ scores, const float* __restrict__ enc_out,
    float* __restrict__ ctx)
{
    __shared__ float al_s[8 * 100];
    const int b0  = blockIdx.x * 8;
    const int tid = threadIdx.x;
    for (int v = tid; v < 800; v += 256) {
        int r = v / 100, l = v - r * 100;
        al_s[r * 100 + l] = scores[(size_t)l * BB + b0 + r];
    }
    __syncthreads();
    if (tid < 8) {
        float m = -1e30f;
        for (int l = 0; l < LL; ++l) m = fmaxf(m, al_s[tid * 100 + l]);
        float s = 0.f;
        for (int l = 0; l < LL; ++l) { float e = expf(al_s[tid * 100 + l] - m); al_s[tid * 100 + l] = e; s += e; }
        float inv = 1.f / s;
        for (int l = 0; l < LL; ++l) al_s[tid * 100 + l] *= inv;
    }
    __syncthreads();
    float acc[8] = {};
    for (int l = 0; l < LL; ++l) {
        const float* er = enc_out + (size_t)l * (BB * 256) + (size_t)b0 * 256 + tid;
        #pragma unroll
        for (int r = 0; r < 8; ++r) acc[r] += al_s[r * 100 + l] * er[r * 256];
    }
    for (int r = 0; r < 8; ++r) ctx[(size_t)(b0 + r) * 256 + tid] = acc[r];
}

// ---------------------------------------------------------------------------
// softmax over L + ctx, bf16 packed enc (tier 3).
// ---------------------------------------------------------------------------
__global__ __launch_bounds__(256) void softmax_ctx_b16(
    const float* __restrict__ scores, const u16* __restrict__ encp,
    float* __restrict__ ctx)
{
    __shared__ float al_s[8 * 100];
    const int b0  = blockIdx.x * 8;
    const int tid = threadIdx.x;
    for (int v = tid; v < 800; v += 256) {
        int r = v / 100, l = v - r * 100;
        al_s[r * 100 + l] = scores[(size_t)l * BB + b0 + r];
    }
    __syncthreads();
    if (tid < 8) {
        float m = -1e30f;
        for (int l = 0; l < LL; ++l) m = fmaxf(m, al_s[tid * 100 + l]);
        float s = 0.f;
        for (int l = 0; l < LL; ++l) { float e = expf(al_s[tid * 100 + l] - m); al_s[tid * 100 + l] = e; s += e; }
        float inv = 1.f / s;
        for (int l = 0; l < LL; ++l) al_s[tid * 100 + l] *= inv;
    }
    __syncthreads();
    float acc[8] = {};
    for (int l = 0; l < LL; ++l) {
        const u16* er = encp + ((size_t)l * BB + b0) * 512 + tid;
        #pragma unroll
        for (int r = 0; r < 8; ++r) acc[r] += al_s[r * 100 + l] * b2f_(er[r * 512]);
    }
    for (int r = 0; r < 8; ++r) ctx[(size_t)(b0 + r) * 256 + tid] = acc[r];
}

// ---------------------------------------------------------------------------
// Decoder LSTM cell: grid 256 x 512, block = 8 rows, half0 = ctx@Wdi,
// half1 = hd@Wdh, coalesced float4 weights. hd updated in place.
// ---------------------------------------------------------------------------
__global__ __launch_bounds__(512) void dec_step(
    const float* __restrict__ ctxp,
    const float* __restrict__ Wdi, const float* __restrict__ Wdh,
    const float* __restrict__ bdec,
    float* __restrict__ hd, float* __restrict__ c_st, int first)
{
    __shared__ float ct_s[8 * 256];        // 8 KB
    __shared__ float hd_s[8 * 256];        // 8 KB
    __shared__ float gate_s[2][8 * 1024];  // 64 KB
    const int row0 = blockIdx.x * 8;
    const int tid  = threadIdx.x;
    const int lane = tid & 63, w = tid >> 6;
    const int half = tid >> 8;
    const int ct   = tid & 255;
    const int c0   = ct * 4;

    ((float4*)ct_s)[tid] = ((const float4*)(ctxp + (size_t)row0 * 256))[tid];
    if (!first)
        ((float4*)hd_s)[tid] = ((const float4*)(hd + (size_t)row0 * 256))[tid];
    __syncthreads();

    float4 acc[8];
    {
        float4 b4 = *(const float4*)&bdec[c0];
        float4 bias4 = (half == 0) ? b4 : make_float4(0.f, 0.f, 0.f, 0.f);
        #pragma unroll
        for (int r = 0; r < 8; ++r) acc[r] = bias4;
    }
    if (half == 0) {
        const float* wP = Wdi + c0;
        #pragma unroll 2
        for (int ch = 0; ch < 64; ++ch) {
            const int k0 = ch * 4;
            float4 w0 = *(const float4*)&wP[(size_t)(k0 + 0) * 1024];
            float4 w1 = *(const float4*)&wP[(size_t)(k0 + 1) * 1024];
            float4 w2 = *(const float4*)&wP[(size_t)(k0 + 2) * 1024];
            float4 w3 = *(const float4*)&wP[(size_t)(k0 + 3) * 1024];
            #pragma unroll
            for (int r = 0; r < 8; ++r) {
                float4 av = *(const float4*)&ct_s[r * 256 + k0];
                acc[r].x += av.x * w0.x; acc[r].y += av.x * w0.y;
                acc[r].z += av.x * w0.z; acc[r].w += av.x * w0.w;
                acc[r].x += av.y * w1.x; acc[r].y += av.y * w1.y;
                acc[r].z += av.y * w1.z; acc[r].w += av.y * w1.w;
                acc[r].x += av.z * w2.x; acc[r].y += av.z * w2.y;
                acc[r].z += av.z * w2.z; acc[r].w += av.z * w2.w;
                acc[r].x += av.w * w3.x; acc[r].y += av.w * w3.y;
                acc[r].z += av.w * w3.z; acc[r].w += av.w * w3.w;
            }
        }
    } else if (!first) {
        const float* wP = Wdh + c0;
        #pragma unroll 2
        for (int ch = 0; ch < 64; ++ch) {
            const int k0 = ch * 4;
            float4 w0 = *(const float4*)&wP[(size_t)(k0 + 0) * 1024];
            float4 w1 = *(const float4*)&wP[(size_t)(k0 + 1) * 1024];
            float4 w2 = *(const float4*)&wP[(size_t)(k0 + 2) * 1024];
            float4 w3 = *(const float4*)&wP[(size_t)(k0 + 3) * 1024];
            #pragma unroll
            for (int r = 0; r < 8; ++r) {
                float4 av = *(const float4*)&hd_s[r * 256 + k0];
                acc[r].x += av.x * w0.x; acc[r].y += av.x * w0.y;
                acc[r].z += av.x * w0.z; acc[r].w += av.x * w0.w;
                acc[r].x += av.y * w1.x; acc[r].y += av.y * w1.y;
                acc[r].z += av.y * w1.z; acc[r].w += av.y * w1.w;
                acc[r].x += av.z * w2.x; acc[r].y += av.z * w2.y;
                acc[r].z += av.z * w2.z; acc[r].w += av.z * w2.w;
                acc[r].x += av.w * w3.x; acc[r].y += av.w * w3.y;
                acc[r].z += av.w * w3.z; acc[r].w += av.w * w3.w;
            }
        }
    }
    #pragma unroll
    for (int r = 0; r < 8; ++r)
        *(float4*)&gate_s[half][r * 1024 + c0] = acc[r];
    __syncthreads();

    {
        const float* g0 = &gate_s[0][w * 1024 + lane * 4];
        const float* g1 = &gate_s[1][w * 1024 + lane * 4];
        float4 giA = *(const float4*)&g0[0],   giB = *(const float4*)&g1[0];
        float4 gfA = *(const float4*)&g0[256], gfB = *(const float4*)&g1[256];
        float4 ggA = *(const float4*)&g0[512], ggB = *(const float4*)&g1[512];
        float4 goA = *(const float4*)&g0[768], goB = *(const float4*)&g1[768];
        size_t ci = (size_t)(row0 + w) * 256 + lane * 4;
        float4 c4 = first ? make_float4(0.f, 0.f, 0.f, 0.f)
                          : *(const float4*)&c_st[ci];
        float cc[4] = { c4.x, c4.y, c4.z, c4.w };
        float gi[4] = { giA.x + giB.x, giA.y + giB.y, giA.z + giB.z, giA.w + giB.w };
        float gf[4] = { gfA.x + gfB.x, gfA.y + gfB.y, gfA.z + gfB.z, gfA.w + gfB.w };
        float gg[4] = { ggA.x + ggB.x, ggA.y + ggB.y, ggA.z + ggB.z, ggA.w + ggB.w };
        float go[4] = { goA.x + goB.x, goA.y + goB.y, goA.z + goB.z, goA.w + goB.w };
        float4 cn, hn;
        #pragma unroll
        for (int uu = 0; uu < 4; ++uu) {
            float cv = sigmoidf_(gf[uu]) * cc[uu] + sigmoidf_(gi[uu]) * tanhf_(gg[uu]);
            float hv = sigmoidf_(go[uu]) * tanhf_(cv);
            if (uu == 0) { cn.x = cv; hn.x = hv; } else if (uu == 1) { cn.y = cv; hn.y = hv; }
            else if (uu == 2) { cn.z = cv; hn.z = hv; } else { cn.w = cv; hn.w = hv; }
        }
        *(float4*)&c_st[ci] = cn;
        *(float4*)&hd[ci]   = hn;
    }
}

// ---------------------------------------------------------------------------
// Head: fc = tanh(h_d@Wf+bf); out[:,step] = tanh(fc@Wo+bo). Block = 16 rows.
// ---------------------------------------------------------------------------
__global__ __launch_bounds__(256) void head_k(
    const float* __restrict__ hd, const float* __restrict__ Wf,
    const float* __restrict__ bf, const float* __restrict__ Wo,
    const float* __restrict__ bo, float* __restrict__ out, int step)
{
    __shared__ float hd_s[16 * 256];
    __shared__ float fc_s[16 * 128];
    const int b0  = blockIdx.x * 16;
    const int tid = threadIdx.x;
    {
        const float4* hg = (const float4*)(hd + (size_t)b0 * 256);
        for (int i = tid; i < 1024; i += 256) ((float4*)hd_s)[i] = hg[i];
    }
    __syncthreads();
    {
        const int f = tid & 127, rg = tid >> 7;
        float acc[8];
        float bfv = bf[f];
        #pragma unroll
        for (int rr = 0; rr < 8; ++rr) acc[rr] = bfv;
        const float* wp = Wf + f;
        #pragma unroll 2
        for (int k = 0; k < 256; ++k) {
            float wv = wp[k * 128];
            #pragma unroll
            for (int rr = 0; rr < 8; ++rr) acc[rr] += hd_s[(rg * 8 + rr) * 256 + k] * wv;
        }
        for (int rr = 0; rr < 8; ++rr) fc_s[(rg * 8 + rr) * 128 + f] = tanhf_(acc[rr]);
    }
    __syncthreads();
    {
        const int lane = tid & 63, w = tid >> 6;
        const float bov = bo[0];
        #pragma unroll
        for (int rr = 0; rr < 4; ++rr) {
            int r = w * 4 + rr;
            float p = fc_s[r * 128 + lane] * Wo[lane] + fc_s[r * 128 + 64 + lane] * Wo[64 + lane];
            #pragma unroll
            for (int msk = 32; msk >= 1; msk >>= 1) p += __shfl_xor(p, msk, 64);
            if (lane == 0) out[(size_t)(b0 + r) * NOUT + step] = tanhf_(p + bov);
        }
    }
}

extern "C" void kernel_launch(void* const* d_in, const int* in_sizes, int n_in,
                              void* d_out, int out_size, void* d_ws, size_t ws_size,
                              hipStream_t stream)
{
    const float* x    = (const float*)d_in[0];
    const float* Wa   = (const float*)d_in[1];
    const float* ba   = (const float*)d_in[2];
    const float* Wi   = (const float*)d_in[3];
    const float* Wh   = (const float*)d_in[4];
    const float* be   = (const float*)d_in[5];
    const float* Wd   = (const float*)d_in[6];
    const float* bd   = (const float*)d_in[7];
    const float* Wl   = (const float*)d_in[8];
    const float* bl   = (const float*)d_in[9];
    const float* Wdi  = (const float*)d_in[10];
    const float* Wdh  = (const float*)d_in[11];
    const float* bdec = (const float*)d_in[12];
    const float* Wf   = (const float*)d_in[13];
    const float* bf   = (const float*)d_in[14];
    const float* Wo   = (const float*)d_in[15];
    const float* bo   = (const float*)d_in[16];
    float* out = (float*)d_out;

    // ws layout (floats): enc_out | hd | c_d | ctx(=hp=wprep alias) | scores | [ep]
    const size_t f_enc    = (size_t)LL * BB * EE;     // 52,428,800
    const size_t f_state  = (size_t)BB * EE;          // 524,288
    const size_t f_scores = (size_t)LL * BB;          // 204,800
    const size_t need3 = (f_enc + 3 * f_state + f_scores) * sizeof(float);
    const size_t need2 = need3 + f_enc * sizeof(u16);
    const size_t need1 = need3 + f_enc * sizeof(float);

    float* ws      = (float*)d_ws;
    float* enc_out = ws;
    float* hd      = enc_out + f_enc;
    float* c_d     = hd + f_state;
    float* ctx     = c_d + f_state;      // also hp AND the weight-prep buffer
    float* scores  = ctx + f_state;      //   (disjoint lifetimes)
    float* ep32    = scores + f_scores;  // tier 1 only
    u16*   ep16    = (u16*)(scores + f_scores);  // tier 2 only
    float* hp      = ctx;
    u16*   wprep   = (u16*)ctx;          // 808 tiles x 2 KB = 1.616 MB <= 2 MB
    // encoder h-exchange buffer aliases hd|c_d (4 MB combined, dead during
    // encoder); flags alias scores (dead during encoder).
    float* hbuf    = hd;
    u32*   flags   = (u32*)scores;

    if (ws_size < need3) return;   // diagnostic clean-fail (known satisfied)
    const int tier = (ws_size >= need1) ? 1 : (ws_size >= need2) ? 2 : 3;

    // zero the group sync counters (replayed as a graph node each launch)
    hipMemsetAsync(flags, 0, 256, stream);
    // weights -> bf16 hi/lo MFMA fragments (ctx region is dead here)
    w_prep<<<680, 64, 0, stream>>>(Wi, Wh, Wa, wprep);
    w_prep2<<<128, 64, 0, stream>>>(Wd, wprep);
    // persistent MFMA encoder: 256 blocks x 1024 threads (1/CU, co-resident)
    enc_mfma4<<<256, 1024, 0, stream>>>(x, ba, be, wprep, enc_out, hbuf, flags);

    // hoist the step-invariant enc_out @ Wd_top out of the decode loop
    if (tier == 1)
        gemm_ep_mfma<<<(LL * BB) / 32, 256, 0, stream>>>(enc_out, wprep, ep32);
    else
        pack_ep<<<(LL * BB) / 32, 256, 0, stream>>>(
            enc_out, Wd, ep16, tier == 3 ? 1 : 0);

    for (int s = 0; s < NOUT; ++s) {
        // hp = hd @ Wd_bot + bd  (step 0: hd == 0 -> hp = bd)
        gemm_nk256<<<BB / 32, 256, 0, stream>>>(
            hd, Wd + 256 * 256, bd, hp, s == 0);
        if (tier == 1)
            scores_ep_f32<<<dim3(BB / 8, 5), 256, 0, stream>>>(ep32, hp, Wl, scores);
        else if (tier == 2)
            scores_ep_b16<<<dim3(BB / 8, 5), 256, 0, stream>>>(ep16, hp, Wl, scores, 256, 0);
        else
            scores_ep_b16<<<dim3(BB / 8, 5), 256, 0, stream>>>(
                (const u16*)enc_out, hp, Wl, scores, 512, 256);
        if (tier == 3)
            softmax_ctx_b16<<<BB / 8, 256, 0, stream>>>(scores, (const u16*)enc_out, ctx);
        else
            softmax_ctx<<<BB / 8, 256, 0, stream>>>(scores, enc_out, ctx);
        dec_step<<<BB / 8, 512, 0, stream>>>(ctx, Wdi, Wdh, bdec, hd, c_d, s == 0);
        head_k<<<BB / 16, 256, 0, stream>>>(hd, Wf, bf, Wo, bo, out, s);
    }
}

// Round 11
// 2251.194 us; speedup vs baseline: 1.1804x; 1.0182x over previous
//
#include <hip/hip_runtime.h>
#include <math.h>

// Problem constants
#define BB 2048
#define LL 100
#define FF 64
#define EE 256
#define DD 256
#define NOUT 3

#define COMP(v, i) ((i) == 0 ? (v).x : (i) == 1 ? (v).y : (i) == 2 ? (v).z : (v).w)

typedef unsigned short u16;
typedef unsigned int u32;
typedef __attribute__((ext_vector_type(8))) __bf16 bf16x8;
typedef __attribute__((ext_vector_type(4))) float f32x4;
typedef __attribute__((ext_vector_type(2))) float f32x2;

#define MFMA_(A, B, C) __builtin_amdgcn_mfma_f32_16x16x32_bf16((A), (B), (C), 0, 0, 0)

__device__ __forceinline__ float sigmoidf_(float x) {
    return 1.0f / (1.0f + expf(-x));
}
// tanh via identity 1 - 2/(1+e^{2x}); ~2e-7 abs fp32 error, saturates correctly.
__device__ __forceinline__ float tanhf_(float x) {
    return 1.0f - 2.0f / (1.0f + expf(2.0f * x));
}
// fp32 -> bf16 round-to-nearest-even
__device__ __forceinline__ u16 f2b_(float f) {
    u32 u = __float_as_uint(f);
    u = (u + 0x7FFFu + ((u >> 16) & 1u)) >> 16;
    return (u16)u;
}
__device__ __forceinline__ float b2f_(u16 b) {
    return __uint_as_float(((u32)b) << 16);
}
__device__ __forceinline__ u32 pack2_(float a, float b) {
    return (u32)f2b_(a) | ((u32)f2b_(b) << 16);
}
__device__ __forceinline__ f32x4 splat4(float b) {
    f32x4 v; v[0] = b; v[1] = b; v[2] = b; v[3] = b; return v;
}
// split 8 fp32 into bf16 hi/lo planes packed as uint4 (little-endian pairs)
__device__ __forceinline__ void split8(const float* v, uint4& H, uint4& L) {
    u16 h[8], lo[8];
    #pragma unroll
    for (int e = 0; e < 8; ++e) {
        h[e]  = f2b_(v[e]);
        lo[e] = f2b_(v[e] - b2f_(h[e]));
    }
    H = make_uint4((u32)h[0]  | ((u32)h[1]  << 16), (u32)h[2]  | ((u32)h[3]  << 16),
                   (u32)h[4]  | ((u32)h[5]  << 16), (u32)h[6]  | ((u32)h[7]  << 16));
    L = make_uint4((u32)lo[0] | ((u32)lo[1] << 16), (u32)lo[2] | ((u32)lo[3] << 16),
                   (u32)lo[4] | ((u32)lo[5] << 16), (u32)lo[6] | ((u32)lo[7] << 16));
}

// Encoder A-fragment LDS index: [mt][kt(10)][plane][lane][8] u16.
// AFX bank swizzle (R7/R10-verified): stored lane = ln ^ ((ln>>4)&3). Pure
// storage permutation; readers use the same macro with ln = hardware lane, so
// reads stay full-tile conflict-free while scatter writes spread across banks
// (SQ_LDS_BANK_CONFLICT 6.5e7 -> 1.6e7; enc 1484 -> 1424 us on R4 frame).
#define AF(mt, kt, p, ln) (((((mt) * 10 + (kt)) * 2 + (p)) * 64 + (ln)) * 8)
#define AFX(mt, kt, p, ln) AF(mt, kt, p, (ln) ^ (((ln) >> 4) & 3))
// ep-GEMM A-fragment LDS index: [mt][kt(8)][plane][lane][8] u16
#define AF2(mt, kt, p, ln) (((((mt) * 8 + (kt)) * 2 + (p)) * 64 + (ln)) * 8)

// ---------------------------------------------------------------------------
// Weight prep (once per launch, into the dead ctx region), single launch:
// blocks 0..679:   bf16 hi/lo split of [Wi;Wh] (tiles 0..639) + Wa (640..679)
// blocks 680..807: Wd_top (256x256) -> tiles 680..807 (nt 0..15, kt 0..7)
// Tile (nt,kt) = 1024 u16: plane-hi [64 lanes][8 e], then plane-lo.
// Element (lane l, e) = W[k = kt*32 + (l>>4)*8 + e][col = nt*16 + (l&15)].
// ---------------------------------------------------------------------------
__global__ __launch_bounds__(64) void w_prep_all(
    const float* __restrict__ Wi, const float* __restrict__ Wh,
    const float* __restrict__ Wa, const float* __restrict__ Wd,
    u16* __restrict__ wp)
{
    const int bid = blockIdx.x;      // 0..807
    const int l   = threadIdx.x;     // 0..63

    float v[8];
    if (bid < 640) {
        const int nt = bid / 10, kt = bid - nt * 10;
        const int col = nt * 16 + (l & 15);
        #pragma unroll
        for (int e = 0; e < 8; ++e) {
            const int k = kt * 32 + ((l >> 4) << 3) + e;
            v[e] = (k < 64) ? Wi[(size_t)k * 1024 + col]
                            : Wh[(size_t)(k - 64) * 1024 + col];
        }
    } else if (bid < 680) {
        const int b2 = bid - 640;
        const int nt = b2 / 10, kt = b2 - nt * 10;
        const int col = nt * 16 + (l & 15);
        #pragma unroll
        for (int e = 0; e < 8; ++e) {
            const int k = kt * 32 + ((l >> 4) << 3) + e;
            v[e] = Wa[(size_t)k * 64 + col];
        }
    } else {
        const int b2 = bid - 680;
        const int nt = b2 >> 3, kt = b2 & 7;
        const int col = nt * 16 + (l & 15);
        #pragma unroll
        for (int e = 0; e < 8; ++e) {
            const int k = kt * 32 + ((l >> 4) << 3) + e;
            v[e] = Wd[(size_t)k * 256 + col];
        }
    }
    uint4 H, L;
    split8(v, H, L);
    *(uint4*)&wp[(size_t)bid * 1024 + (size_t)l * 8]       = H;
    *(uint4*)&wp[(size_t)bid * 1024 + 512 + (size_t)l * 8] = L;
}

// ---------------------------------------------------------------------------
// Persistent MFMA encoder == R10 (best measured: 1424 us) with ONE change:
// flags padded to 128 B per group (flags[g*32]) so each group's counter owns
// its own LLC line. R10 had 64 counters in two 128-B lines shared by all 256
// pollers + 256 releasers -> line-ownership serialization in S1.
// Sync protocol otherwise byte-identical: S1 = tid==0 poll + barrier, then
// staging loads (R7-R9: distributed polling costs 150-280 us).
// Grid 256 x 1024 (1 block/CU). Block (g 0..63, p 0..3): rows g*32..+32,
// hidden units p*64..+64. Wave w owns N-tile nt = (w>>2)*16 + p*4 + (w&3);
// its B-hi plane (40 VGPR) is register-resident; B-lo + Wa stream from L2.
// Bounded spin: no hang possible.
// ---------------------------------------------------------------------------
__global__ __launch_bounds__(1024) void enc_mfma4(
    const float* __restrict__ x,
    const float* __restrict__ ba, const float* __restrict__ be,
    const u16* __restrict__ wp,
    float* __restrict__ enc_out,
    float* __restrict__ hbuf,          // [2][BB][256] fp32 (aliases hd|c_d)
    u32* __restrict__ flags)           // [64*32] counters, 128B apart (memset 0)
{
    __shared__ u16   aFrag[20480];         // 40 KB A-fragments (bf16 hi/lo)
    __shared__ float x_s[32 * 68];         // 8.5 KB x fp32
    __shared__ float e_s[32 * 68];         // 8.5 KB attention energies
    __shared__ float gate_s[4][32][66];    // 33 KB gates, padded stride 66

    const int bid = blockIdx.x;
    const int g   = (bid & 7) | ((bid >> 5) << 3);   // group 0..63
    const int p   = (bid >> 3) & 3;                  // unit-quarter
    const int row0 = g * 32;
    const int tid = threadIdx.x;
    const int l   = tid & 63;
    const int w   = tid >> 6;                        // wave 0..15

    // zero aFrag (h region must be 0 at t=0)
    for (int v = tid; v < 20480 / 2; v += 1024) ((u32*)aFrag)[v] = 0u;

    // per-wave N-tile; B-hi plane register-resident (40 VGPR)
    const int ntW = (w >> 2) * 16 + p * 4 + (w & 3);
    uint4 BhR[10];
    #pragma unroll
    for (int kt = 0; kt < 10; ++kt)
        BhR[kt] = *(const uint4*)&wp[(size_t)(ntW * 10 + kt) * 1024 + (size_t)l * 8];

    const float be_r = be[(size_t)ntW * 16 + (l & 15)];
    const float ba_r = (w < 8) ? ba[(w & 3) * 16 + (l & 15)] : 0.f;

    float c_state[2] = {0.f, 0.f};

    __syncthreads();

    for (int t = 0; t < LL; ++t) {
        // ---- S1: wait for all 4 partner blocks to finish t-1 ----
        if (t > 0) {
            if (tid == 0) {
                const u32 target = 4u * (u32)t;
                int guard = 0;
                while (__hip_atomic_load(&flags[g * 32], __ATOMIC_RELAXED,
                                         __HIP_MEMORY_SCOPE_AGENT) < target) {
                    __builtin_amdgcn_s_sleep(1);
                    if (++guard > 2000000) break;   // bounded: no GPU hang
                }
            }
            __syncthreads();
        }

        // ---- P0: stage x_t frags (tid<256) | partner-h frags (tid>=256) ----
        if (tid < 256) {
            const int kt2 = tid >> 7;          // 0..1
            const int mt  = (tid >> 6) & 1;    // 0..1
            const int l2  = tid & 63;
            const int row2 = mt * 16 + (l2 & 15);
            const int f0   = kt2 * 32 + ((l2 >> 4) << 3);
            const float* xp = x + (size_t)(row0 + row2) * (LL * FF) + (size_t)t * FF + f0;
            float4 xa = *(const float4*)xp;
            float4 xb = *(const float4*)(xp + 4);
            float v[8] = {xa.x, xa.y, xa.z, xa.w, xb.x, xb.y, xb.z, xb.w};
            uint4 H, L;
            split8(v, H, L);
            *(uint4*)&aFrag[AFX(mt, kt2, 0, l2)] = H;
            *(uint4*)&aFrag[AFX(mt, kt2, 1, l2)] = L;
            *(float4*)&x_s[row2 * 68 + f0]     = xa;
            *(float4*)&x_s[row2 * 68 + f0 + 4] = xb;
        } else if (t > 0) {
            const int v   = tid - 256;         // 0..767
            const int prl = v >> 8;            // 0..2 (relative partner)
            const int vv  = v & 255;
            const int row = vv >> 3;           // 0..31
            const int i8  = vv & 7;            // 8-unit chunk
            const int ugp = (p + 1 + prl) & 3;
            const int u8  = ugp * 64 + i8 * 8; // global unit base (mult of 8)
            const float* hp_g = hbuf + ((size_t)((t - 1) & 1) * BB + row0 + row) * 256 + u8;
            f32x4 a4, b4;
            asm volatile("global_load_dwordx4 %0, %2, off sc0 sc1\n\t"
                         "global_load_dwordx4 %1, %3, off sc0 sc1\n\t"
                         "s_waitcnt vmcnt(0)"
                         : "=v"(a4), "=v"(b4)
                         : "v"(hp_g), "v"(hp_g + 4) : "memory");
            float v8[8] = {a4[0], a4[1], a4[2], a4[3], b4[0], b4[1], b4[2], b4[3]};
            uint4 H, L;
            split8(v8, H, L);
            const int mt = row >> 4, rowT = row & 15;
            const int kt_h = 2 + (u8 >> 5);
            const int g2   = (u8 & 31) >> 3;
            const int ln   = rowT + (g2 << 4);
            *(uint4*)&aFrag[AFX(mt, kt_h, 0, ln)] = H;
            *(uint4*)&aFrag[AFX(mt, kt_h, 1, ln)] = L;
        }
        __syncthreads();   // A: x/h fragments visible

        // ---- P1: attention energies (waves 0..7: mt = w>>2, nta = w&3) ----
        if (w < 8) {
            const int mt  = w >> 2;
            const int nta = w & 3;
            f32x4 ea = splat4(ba_r);
            #pragma unroll
            for (int kt = 0; kt < 10; ++kt) {
                bf16x8 Ah = *(const bf16x8*)&aFrag[AFX(mt, kt, 0, l)];
                bf16x8 Al = *(const bf16x8*)&aFrag[AFX(mt, kt, 1, l)];
                const size_t o = (size_t)(640 + nta * 10 + kt) * 1024 + (size_t)l * 8;
                bf16x8 Bh = *(const bf16x8*)&wp[o];
                bf16x8 Bl = *(const bf16x8*)&wp[o + 512];
                ea = MFMA_(Ah, Bh, ea);
                ea = MFMA_(Al, Bh, ea);
                ea = MFMA_(Ah, Bl, ea);
            }
            const int colA = nta * 16 + (l & 15);
            #pragma unroll
            for (int r = 0; r < 4; ++r) {
                const int rowT = ((l >> 4) << 2) + r;
                e_s[(mt * 16 + rowT) * 68 + colA] = tanhf_(ea[r]);
            }
        }
        __syncthreads();   // B: energies staged

        // ---- P2: softmax over 64 cols + ein fragments (tid<512) ----
        if (tid < 512) {
            const int row2 = tid >> 4;           // 0..31
            const int c4   = (tid & 15) * 4;     // 0..60
            float4 ev = *(const float4*)&e_s[row2 * 68 + c4];
            float m = fmaxf(fmaxf(ev.x, ev.y), fmaxf(ev.z, ev.w));
            #pragma unroll
            for (int msk = 8; msk >= 1; msk >>= 1) m = fmaxf(m, __shfl_xor(m, msk, 64));
            float4 ex;
            ex.x = expf(ev.x - m); ex.y = expf(ev.y - m);
            ex.z = expf(ev.z - m); ex.w = expf(ev.w - m);
            float s = ex.x + ex.y + ex.z + ex.w;
            #pragma unroll
            for (int msk = 8; msk >= 1; msk >>= 1) s += __shfl_xor(s, msk, 64);
            const float inv = 1.f / s;
            float4 xv = *(const float4*)&x_s[row2 * 68 + c4];
            float ein[4] = { ex.x * inv * xv.x, ex.y * inv * xv.y,
                             ex.z * inv * xv.z, ex.w * inv * xv.w };
            const int mt   = row2 >> 4;
            const int rowT = row2 & 15;
            const int kt   = c4 >> 5;
            const int g2   = (c4 & 31) >> 3;
            const int e0   = c4 & 7;             // 0 or 4
            const int ln   = rowT + (g2 << 4);
            ushort4 h4, l4;
            #pragma unroll
            for (int e = 0; e < 4; ++e) {
                u16 hh = f2b_(ein[e]);
                u16 ll = f2b_(ein[e] - b2f_(hh));
                if (e == 0) { h4.x = hh; l4.x = ll; } else if (e == 1) { h4.y = hh; l4.y = ll; }
                else if (e == 2) { h4.z = hh; l4.z = ll; } else { h4.w = hh; l4.w = ll; }
            }
            *(ushort4*)&aFrag[AFX(mt, kt, 0, ln) + e0] = h4;
            *(ushort4*)&aFrag[AFX(mt, kt, 1, ln) + e0] = l4;
        }
        __syncthreads();   // C: ein fragments staged

        // ---- P3: gate GEMM, B-hi from registers, B-lo streamed (L2) ----
        f32x4 acc0 = splat4(be_r), acc1 = splat4(be_r);
        #pragma unroll
        for (int kt = 0; kt < 10; ++kt) {
            bf16x8 Ah0 = *(const bf16x8*)&aFrag[AFX(0, kt, 0, l)];
            bf16x8 Al0 = *(const bf16x8*)&aFrag[AFX(0, kt, 1, l)];
            bf16x8 Ah1 = *(const bf16x8*)&aFrag[AFX(1, kt, 0, l)];
            bf16x8 Al1 = *(const bf16x8*)&aFrag[AFX(1, kt, 1, l)];
            bf16x8 Bl  = *(const bf16x8*)&wp[(size_t)(ntW * 10 + kt) * 1024 + 512 + (size_t)l * 8];
            bf16x8 Bh  = __builtin_bit_cast(bf16x8, BhR[kt]);
            acc0 = MFMA_(Ah0, Bh, acc0);
            acc1 = MFMA_(Ah1, Bh, acc1);
            acc0 = MFMA_(Al0, Bh, acc0);
            acc1 = MFMA_(Al1, Bh, acc1);
            acc0 = MFMA_(Ah0, Bl, acc0);
            acc1 = MFMA_(Ah1, Bl, acc1);
        }
        // stage gates: gate = w>>2, unit_local = (w&3)*16 + (l&15)
        {
            const int gate = w >> 2;
            const int ulb  = (w & 3) * 16 + (l & 15);
            #pragma unroll
            for (int r = 0; r < 4; ++r) {
                const int rT = ((l >> 4) << 2) + r;
                gate_s[gate][rT][ulb]      = acc0[r];
                gate_s[gate][16 + rT][ulb] = acc1[r];
            }
        }
        __syncthreads();   // D: gates staged; aFrag reads done

        // ---- epilogue: 1024 threads x 2 cells; h out + own h-frags ----
        {
            const int row = tid >> 5;            // 0..31
            const int q2  = (tid & 31) * 2;      // unit_local 0..62 even
            float gi0 = gate_s[0][row][q2], gi1 = gate_s[0][row][q2 + 1];
            float gf0 = gate_s[1][row][q2], gf1 = gate_s[1][row][q2 + 1];
            float gg0 = gate_s[2][row][q2], gg1 = gate_s[2][row][q2 + 1];
            float go0 = gate_s[3][row][q2], go1 = gate_s[3][row][q2 + 1];
            float cv0 = sigmoidf_(gf0) * c_state[0] + sigmoidf_(gi0) * tanhf_(gg0);
            float cv1 = sigmoidf_(gf1) * c_state[1] + sigmoidf_(gi1) * tanhf_(gg1);
            c_state[0] = cv0; c_state[1] = cv1;
            float hv0 = sigmoidf_(go0) * tanhf_(cv0);
            float hv1 = sigmoidf_(go1) * tanhf_(cv1);
            const int u_g = p * 64 + q2;
            // enc_out (plain store)
            *(float2*)&enc_out[((size_t)t * BB + row0 + row) * 256 + u_g]
                = make_float2(hv0, hv1);
            // hbuf write-through (coherence point) for partner blocks
            float* hp_g = hbuf + ((size_t)(t & 1) * BB + row0 + row) * 256 + u_g;
            f32x2 hv2; hv2[0] = hv0; hv2[1] = hv1;
            asm volatile("global_store_dwordx2 %0, %1, off sc0 sc1"
                         :: "v"(hp_g), "v"(hv2) : "memory");
            // own h-fragments for t+1
            const int mt = row >> 4, rowT = row & 15;
            const int kt_h = 2 + (u_g >> 5);
            const int g2   = (u_g & 31) >> 3;
            const int ln   = rowT + (g2 << 4);
            const int e    = u_g & 7;            // even
            ((u32*)aFrag)[(AFX(mt, kt_h, 0, ln) + e) >> 1] = pack2_(hv0, hv1);
            u16 h0 = f2b_(hv0), h1 = f2b_(hv1);
            ((u32*)aFrag)[(AFX(mt, kt_h, 1, ln) + e) >> 1] =
                (u32)f2b_(hv0 - b2f_(h0)) | ((u32)f2b_(hv1 - b2f_(h1)) << 16);
        }
        asm volatile("s_waitcnt vmcnt(0)" ::: "memory");   // h stores complete
        __syncthreads();   // E: all waves' stores acked
        if (tid == 0)
            __hip_atomic_fetch_add(&flags[g * 32], 1u, __ATOMIC_RELEASE,
                                   __HIP_MEMORY_SCOPE_AGENT);
    }
}

// ---------------------------------------------------------------------------
// ep = enc_out @ Wd_top via split-bf16 MFMA (tier 1 hoisted GEMM).
// Grid M/32 x 256 threads (4 waves). Wave w owns nt = w*4..w*4+3.
// ---------------------------------------------------------------------------
__global__ __launch_bounds__(256) void gemm_ep_mfma(
    const float* __restrict__ A, const u16* __restrict__ wp,
    float* __restrict__ C)
{
    __shared__ u16   aF[2 * 8 * 2 * 64 * 8];   // 32 KB A-fragments
    __shared__ float c_s[32 * 260];            // 32.5 KB C staging (padded)
    const int m0  = blockIdx.x * 32;
    const int tid = threadIdx.x;
    const int l   = tid & 63;
    const int w   = tid >> 6;                  // 0..3

    for (int s = tid; s < 1024; s += 256) {
        const int mt = s >> 9, kt = (s >> 6) & 7, l2 = s & 63;
        const int row2 = mt * 16 + (l2 & 15);
        const int k0   = kt * 32 + ((l2 >> 4) << 3);
        const float* ap = A + (size_t)(m0 + row2) * 256 + k0;
        float4 xa = *(const float4*)ap;
        float4 xb = *(const float4*)(ap + 4);
        float v[8] = {xa.x, xa.y, xa.z, xa.w, xb.x, xb.y, xb.z, xb.w};
        uint4 H, L;
        split8(v, H, L);
        *(uint4*)&aF[AF2(mt, kt, 0, l2)] = H;
        *(uint4*)&aF[AF2(mt, kt, 1, l2)] = L;
    }
    __syncthreads();

    f32x4 acc[2][4];
    #pragma unroll
    for (int mt = 0; mt < 2; ++mt)
        #pragma unroll
        for (int j = 0; j < 4; ++j) acc[mt][j] = splat4(0.f);

    #pragma unroll
    for (int kt = 0; kt < 8; ++kt) {
        bf16x8 Ah0 = *(const bf16x8*)&aF[AF2(0, kt, 0, l)];
        bf16x8 Al0 = *(const bf16x8*)&aF[AF2(0, kt, 1, l)];
        bf16x8 Ah1 = *(const bf16x8*)&aF[AF2(1, kt, 0, l)];
        bf16x8 Al1 = *(const bf16x8*)&aF[AF2(1, kt, 1, l)];
        #pragma unroll
        for (int j = 0; j < 4; ++j) {
            const int nt = w * 4 + j;
            const u16* bt = wp + (size_t)(680 + nt * 8 + kt) * 1024 + (size_t)l * 8;
            bf16x8 Bh = *(const bf16x8*)bt;
            bf16x8 Bl = *(const bf16x8*)(bt + 512);
            acc[0][j] = MFMA_(Ah0, Bh, acc[0][j]);
            acc[1][j] = MFMA_(Ah1, Bh, acc[1][j]);
            acc[0][j] = MFMA_(Al0, Bh, acc[0][j]);
            acc[1][j] = MFMA_(Al1, Bh, acc[1][j]);
            acc[0][j] = MFMA_(Ah0, Bl, acc[0][j]);
            acc[1][j] = MFMA_(Ah1, Bl, acc[1][j]);
        }
    }

    #pragma unroll
    for (int mt = 0; mt < 2; ++mt)
        #pragma unroll
        for (int j = 0; j < 4; ++j) {
            const int col = (w * 4 + j) * 16 + (l & 15);
            #pragma unroll
            for (int r = 0; r < 4; ++r) {
                const int row = mt * 16 + ((l >> 4) << 2) + r;
                c_s[row * 260 + col] = acc[mt][j][r];
            }
        }
    __syncthreads();
    for (int v = tid; v < 32 * 64; v += 256) {
        const int row = v >> 6, c4 = (v & 63) << 2;
        *(float4*)&C[(size_t)(m0 + row) * 256 + c4] = *(const float4*)&c_s[row * 260 + c4];
    }
}

// ---------------------------------------------------------------------------
// Generic fp32 GEMM C(M,256) = A(M,256) @ W(256,256) [+ bias].
// Block = 32 rows, 256 threads. skip_gemm: C = bias (decoder step 0, hd==0).
// Used for: hp = hd @ Wd_bot + bd.
// ---------------------------------------------------------------------------
__global__ __launch_bounds__(256) void gemm_nk256(
    const float* __restrict__ A, const float* __restrict__ W,
    const float* __restrict__ bias, float* __restrict__ C, int skip_gemm)
{
    __shared__ float a_s[32 * 256];   // 32 KB
    const int m0   = blockIdx.x * 32;
    const int tid  = threadIdx.x;
    const int lane = tid & 63;
    const int rg   = tid >> 6;        // 0..3 -> rows rg*8..rg*8+7
    const int n0   = lane * 4;

    float4 bias4 = make_float4(0.f, 0.f, 0.f, 0.f);
    if (bias) bias4 = *(const float4*)&bias[n0];

    if (skip_gemm) {
        #pragma unroll
        for (int r = 0; r < 8; ++r)
            *(float4*)&C[(size_t)(m0 + rg * 8 + r) * 256 + n0] = bias4;
        return;
    }

    for (int v = tid; v < 32 * 64; v += 256)
        ((float4*)a_s)[v] = ((const float4*)(A + (size_t)m0 * 256))[v];
    __syncthreads();

    float4 acc[8];
    #pragma unroll
    for (int r = 0; r < 8; ++r) acc[r] = bias4;

    #pragma unroll 2
    for (int k = 0; k < 256; k += 4) {
        float4 wv[4];
        #pragma unroll
        for (int kk = 0; kk < 4; ++kk)
            wv[kk] = *(const float4*)&W[(size_t)(k + kk) * 256 + n0];
        float4 av[8];
        #pragma unroll
        for (int r = 0; r < 8; ++r)
            av[r] = *(const float4*)&a_s[(rg * 8 + r) * 256 + k];
        #pragma unroll
        for (int kk = 0; kk < 4; ++kk) {
            #pragma unroll
            for (int r = 0; r < 8; ++r) {
                float e = COMP(av[r], kk);
                acc[r].x += e * wv[kk].x; acc[r].y += e * wv[kk].y;
                acc[r].z += e * wv[kk].z; acc[r].w += e * wv[kk].w;
            }
        }
    }
    #pragma unroll
    for (int r = 0; r < 8; ++r)
        *(float4*)&C[(size_t)(m0 + rg * 8 + r) * 256 + n0] = acc[r];
}

// ---------------------------------------------------------------------------
// ep = enc_out @ Wd_top, emitted as bf16 (tiers 2/3 fallback).
// ---------------------------------------------------------------------------
__global__ __launch_bounds__(256) void pack_ep(
    float* A, const float* __restrict__ W, u16* epOut, int packed)
{
    __shared__ float a_s[32 * 256];   // 32 KB
    const int m0   = blockIdx.x * 32;
    const int tid  = threadIdx.x;
    const int lane = tid & 63;
    const int rg   = tid >> 6;
    const int n0   = lane * 4;

    for (int v = tid; v < 32 * 64; v += 256)
        ((float4*)a_s)[v] = ((const float4*)(A + (size_t)m0 * 256))[v];
    __syncthreads();

    float4 acc[8];
    #pragma unroll
    for (int r = 0; r < 8; ++r) acc[r] = make_float4(0.f, 0.f, 0.f, 0.f);

    #pragma unroll 2
    for (int k = 0; k < 256; k += 4) {
        float4 wv[4];
        #pragma unroll
        for (int kk = 0; kk < 4; ++kk)
            wv[kk] = *(const float4*)&W[(size_t)(k + kk) * 256 + n0];
        float4 av[8];
        #pragma unroll
        for (int r = 0; r < 8; ++r)
            av[r] = *(const float4*)&a_s[(rg * 8 + r) * 256 + k];
        #pragma unroll
        for (int kk = 0; kk < 4; ++kk) {
            #pragma unroll
            for (int r = 0; r < 8; ++r) {
                float e = COMP(av[r], kk);
                acc[r].x += e * wv[kk].x; acc[r].y += e * wv[kk].y;
                acc[r].z += e * wv[kk].z; acc[r].w += e * wv[kk].w;
            }
        }
    }

    u16* epu = packed ? (u16*)A : epOut;
    #pragma unroll
    for (int r = 0; r < 8; ++r) {
        const size_t row = (size_t)(m0 + rg * 8 + r);
        ushort4 o;
        o.x = f2b_(acc[r].x); o.y = f2b_(acc[r].y);
        o.z = f2b_(acc[r].z); o.w = f2b_(acc[r].w);
        u16* dst = packed ? (epu + row * 512 + 256 + n0)
                          : (epu + row * 256 + n0);
        *(ushort4*)dst = o;
    }

    if (packed) {
        u32* ab = (u32*)A;
        for (int v = tid; v < 32 * 128; v += 256) {
            const int row = v >> 7, j = v & 127;
            float2 f = *(const float2*)&a_s[(row << 8) + (j << 1)];
            ab[((size_t)(m0 + row)) * 256 + j] = pack2_(f.x, f.y);
        }
    }
}

// ---------------------------------------------------------------------------
// Per-step decoder scores from precomputed fp32 ep (tier 1):
//   score[l,b] = Wl . tanh(ep[l,b,:] + hp[b,:])   (bl cancels in softmax)
// ---------------------------------------------------------------------------
__global__ __launch_bounds__(256) void scores_ep_f32(
    const float* __restrict__ ep, const float* __restrict__ hp,
    const float* __restrict__ Wl, float* __restrict__ scores)
{
    __shared__ float hp_s[8 * 256];
    const int b0  = blockIdx.x * 8;
    const int l0  = blockIdx.y * 20;
    const int tid = threadIdx.x;
    const int r   = tid >> 5;
    const int g   = tid & 31;

    for (int v = tid; v < 512; v += 256)
        ((float4*)hp_s)[v] = ((const float4*)(hp + (size_t)b0 * 256))[v];
    __syncthreads();

    const float4 wl0 = *(const float4*)&Wl[g * 4];
    const float4 wl1 = *(const float4*)&Wl[128 + g * 4];
    const float4 h0  = *(const float4*)&hp_s[r * 256 + g * 4];
    const float4 h1  = *(const float4*)&hp_s[r * 256 + 128 + g * 4];
    const float* eb  = ep + (size_t)l0 * (BB * 256) + (size_t)(b0 + r) * 256;

    #pragma unroll 2
    for (int li = 0; li < 20; ++li) {
        float4 e0 = *(const float4*)&eb[(size_t)li * (BB * 256) + g * 4];
        float4 e1 = *(const float4*)&eb[(size_t)li * (BB * 256) + 128 + g * 4];
        float p = tanhf_(e0.x + h0.x) * wl0.x + tanhf_(e0.y + h0.y) * wl0.y
                + tanhf_(e0.z + h0.z) * wl0.z + tanhf_(e0.w + h0.w) * wl0.w
                + tanhf_(e1.x + h1.x) * wl1.x + tanhf_(e1.y + h1.y) * wl1.y
                + tanhf_(e1.z + h1.z) * wl1.z + tanhf_(e1.w + h1.w) * wl1.w;
        #pragma unroll
        for (int msk = 16; msk >= 1; msk >>= 1) p += __shfl_xor(p, msk, 64);
        if (g == 0) scores[(size_t)(l0 + li) * BB + b0 + r] = p;
    }
}

// ---------------------------------------------------------------------------
// Same, from bf16 ep rows (tiers 2/3). sstr/soff in u16 units.
// ---------------------------------------------------------------------------
__global__ __launch_bounds__(256) void scores_ep_b16(
    const u16* __restrict__ ep, const float* __restrict__ hp,
    const float* __restrict__ Wl, float* __restrict__ scores,
    int sstr, int soff)
{
    __shared__ float hp_s[8 * 256];
    const int b0  = blockIdx.x * 8;
    const int l0  = blockIdx.y * 20;
    const int tid = threadIdx.x;
    const int r   = tid >> 5;
    const int g   = tid & 31;

    for (int v = tid; v < 512; v += 256)
        ((float4*)hp_s)[v] = ((const float4*)(hp + (size_t)b0 * 256))[v];
    __syncthreads();

    const float4 wl0 = *(const float4*)&Wl[g * 4];
    const float4 wl1 = *(const float4*)&Wl[128 + g * 4];
    const float4 h0  = *(const float4*)&hp_s[r * 256 + g * 4];
    const float4 h1  = *(const float4*)&hp_s[r * 256 + 128 + g * 4];

    #pragma unroll 2
    for (int li = 0; li < 20; ++li) {
        const u16* er = ep + ((size_t)(l0 + li) * BB + b0 + r) * sstr + soff;
        ushort4 u0 = *(const ushort4*)&er[g * 4];
        ushort4 u1 = *(const ushort4*)&er[128 + g * 4];
        float p = tanhf_(b2f_(u0.x) + h0.x) * wl0.x + tanhf_(b2f_(u0.y) + h0.y) * wl0.y
                + tanhf_(b2f_(u0.z) + h0.z) * wl0.z + tanhf_(b2f_(u0.w) + h0.w) * wl0.w
                + tanhf_(b2f_(u1.x) + h1.x) * wl1.x + tanhf_(b2f_(u1.y) + h1.y) * wl1.y
                + tanhf_(b2f_(u1.z) + h1.z) * wl1.z + tanhf_(b2f_(u1.w) + h1.w) * wl1.w;
        #pragma unroll
        for (int msk = 16; msk >= 1; msk >>= 1) p += __shfl_xor(p, msk, 64);
        if (g == 0) scores[(size_t)(l0 + li) * BB + b0 + r] = p;
    }
}

// ---------------------------------------------------------------------------
// softmax over L + ctx. fp32 enc variant (tiers 1/2). Block = 8 rows.
// ---------------------------------------------------------------------------
__global__ __launch_bounds__(256) void softmax_ctx(
    const float* __restrict__ scores, const float* __restrict__ enc_out,
    float* __restrict__ ctx)
{
    __shared__ float al_s[8 * 100];
    const int b0  = blockIdx.x * 8;
    const int tid = threadIdx.x;
    for (int v = tid; v < 800; v += 256) {
        int r = v / 100, l = v - r * 100;
        al_s[r * 100 + l] = scores[(size_t)l * BB + b0 + r];
    }
    __syncthreads();
    if (tid < 8) {
        float m = -1e30f;
        for (int l = 0; l < LL; ++l) m = fmaxf(m, al_s[tid * 100 + l]);
        float s = 0.f;
        for (int l = 0; l < LL; ++l) { float e = expf(al_s[tid * 100 + l] - m); al_s[tid * 100 + l] = e; s += e; }
        float inv = 1.f / s;
        for (int l = 0; l < LL; ++l) al_s[tid * 100 + l] *= inv;
    }
    __syncthreads();
    float acc[8] = {};
    for (int l = 0; l < LL; ++l) {
        const float* er = enc_out + (size_t)l * (BB * 256) + (size_t)b0 * 256 + tid;
        #pragma unroll
        for (int r = 0; r < 8; ++r) acc[r] += al_s[r * 100 + l] * er[r * 256];
    }
    for (int r = 0; r < 8; ++r) ctx[(size_t)(b0 + r) * 256 + tid] = acc[r];
}

// ---------------------------------------------------------------------------
// softmax over L + ctx, bf16 packed enc (tier 3).
// ---------------------------------------------------------------------------
__global__ __launch_bounds__(256) void softmax_ctx_b16(
    const float* __restrict__ scores, const u16* __restrict__ encp,
    float* __restrict__ ctx)
{
    __shared__ float al_s[8 * 100];
    const int b0  = blockIdx.x * 8;
    const int tid = threadIdx.x;
    for (int v = tid; v < 800; v += 256) {
        int r = v / 100, l = v - r * 100;
        al_s[r * 100 + l] = scores[(size_t)l * BB + b0 + r];
    }
    __syncthreads();
    if (tid < 8) {
        float m = -1e30f;
        for (int l = 0; l < LL; ++l) m = fmaxf(m, al_s[tid * 100 + l]);
        float s = 0.f;
        for (int l = 0; l < LL; ++l) { float e = expf(al_s[tid * 100 + l] - m); al_s[tid * 100 + l] = e; s += e; }
        float inv = 1.f / s;
        for (int l = 0; l < LL; ++l) al_s[tid * 100 + l] *= inv;
    }
    __syncthreads();
    float acc[8] = {};
    for (int l = 0; l < LL; ++l) {
        const u16* er = encp + ((size_t)l * BB + b0) * 512 + tid;
        #pragma unroll
        for (int r = 0; r < 8; ++r) acc[r] += al_s[r * 100 + l] * b2f_(er[r * 512]);
    }
    for (int r = 0; r < 8; ++r) ctx[(size_t)(b0 + r) * 256 + tid] = acc[r];
}

// ---------------------------------------------------------------------------
// Decoder LSTM cell: grid 256 x 512, block = 8 rows, half0 = ctx@Wdi,
// half1 = hd@Wdh, coalesced float4 weights. hd updated in place.
// ---------------------------------------------------------------------------
__global__ __launch_bounds__(512) void dec_step(
    const float* __restrict__ ctxp,
    const float* __restrict__ Wdi, const float* __restrict__ Wdh,
    const float* __restrict__ bdec,
    float* __restrict__ hd, float* __restrict__ c_st, int first)
{
    __shared__ float ct_s[8 * 256];        // 8 KB
    __shared__ float hd_s[8 * 256];        // 8 KB
    __shared__ float gate_s[2][8 * 1024];  // 64 KB
    const int row0 = blockIdx.x * 8;
    const int tid  = threadIdx.x;
    const int lane = tid & 63, w = tid >> 6;
    const int half = tid >> 8;
    const int ct   = tid & 255;
    const int c0   = ct * 4;

    ((float4*)ct_s)[tid] = ((const float4*)(ctxp + (size_t)row0 * 256))[tid];
    if (!first)
        ((float4*)hd_s)[tid] = ((const float4*)(hd + (size_t)row0 * 256))[tid];
    __syncthreads();

    float4 acc[8];
    {
        float4 b4 = *(const float4*)&bdec[c0];
        float4 bias4 = (half == 0) ? b4 : make_float4(0.f, 0.f, 0.f, 0.f);
        #pragma unroll
        for (int r = 0; r < 8; ++r) acc[r] = bias4;
    }
    if (half == 0) {
        const float* wP = Wdi + c0;
        #pragma unroll 2
        for (int ch = 0; ch < 64; ++ch) {
            const int k0 = ch * 4;
            float4 w0 = *(const float4*)&wP[(size_t)(k0 + 0) * 1024];
            float4 w1 = *(const float4*)&wP[(size_t)(k0 + 1) * 1024];
            float4 w2 = *(const float4*)&wP[(size_t)(k0 + 2) * 1024];
            float4 w3 = *(const float4*)&wP[(size_t)(k0 + 3) * 1024];
            #pragma unroll
            for (int r = 0; r < 8; ++r) {
                float4 av = *(const float4*)&ct_s[r * 256 + k0];
                acc[r].x += av.x * w0.x; acc[r].y += av.x * w0.y;
                acc[r].z += av.x * w0.z; acc[r].w += av.x * w0.w;
                acc[r].x += av.y * w1.x; acc[r].y += av.y * w1.y;
                acc[r].z += av.y * w1.z; acc[r].w += av.y * w1.w;
                acc[r].x += av.z * w2.x; acc[r].y += av.z * w2.y;
                acc[r].z += av.z * w2.z; acc[r].w += av.z * w2.w;
                acc[r].x += av.w * w3.x; acc[r].y += av.w * w3.y;
                acc[r].z += av.w * w3.z; acc[r].w += av.w * w3.w;
            }
        }
    } else if (!first) {
        const float* wP = Wdh + c0;
        #pragma unroll 2
        for (int ch = 0; ch < 64; ++ch) {
            const int k0 = ch * 4;
            float4 w0 = *(const float4*)&wP[(size_t)(k0 + 0) * 1024];
            float4 w1 = *(const float4*)&wP[(size_t)(k0 + 1) * 1024];
            float4 w2 = *(const float4*)&wP[(size_t)(k0 + 2) * 1024];
            float4 w3 = *(const float4*)&wP[(size_t)(k0 + 3) * 1024];
            #pragma unroll
            for (int r = 0; r < 8; ++r) {
                float4 av = *(const float4*)&hd_s[r * 256 + k0];
                acc[r].x += av.x * w0.x; acc[r].y += av.x * w0.y;
                acc[r].z += av.x * w0.z; acc[r].w += av.x * w0.w;
                acc[r].x += av.y * w1.x; acc[r].y += av.y * w1.y;
                acc[r].z += av.y * w1.z; acc[r].w += av.y * w1.w;
                acc[r].x += av.z * w2.x; acc[r].y += av.z * w2.y;
                acc[r].z += av.z * w2.z; acc[r].w += av.z * w2.w;
                acc[r].x += av.w * w3.x; acc[r].y += av.w * w3.y;
                acc[r].z += av.w * w3.z; acc[r].w += av.w * w3.w;
            }
        }
    }
    #pragma unroll
    for (int r = 0; r < 8; ++r)
        *(float4*)&gate_s[half][r * 1024 + c0] = acc[r];
    __syncthreads();

    {
        const float* g0 = &gate_s[0][w * 1024 + lane * 4];
        const float* g1 = &gate_s[1][w * 1024 + lane * 4];
        float4 giA = *(const float4*)&g0[0],   giB = *(const float4*)&g1[0];
        float4 gfA = *(const float4*)&g0[256], gfB = *(const float4*)&g1[256];
        float4 ggA = *(const float4*)&g0[512], ggB = *(const float4*)&g1[512];
        float4 goA = *(const float4*)&g0[768], goB = *(const float4*)&g1[768];
        size_t ci = (size_t)(row0 + w) * 256 + lane * 4;
        float4 c4 = first ? make_float4(0.f, 0.f, 0.f, 0.f)
                          : *(const float4*)&c_st[ci];
        float cc[4] = { c4.x, c4.y, c4.z, c4.w };
        float gi[4] = { giA.x + giB.x, giA.y + giB.y, giA.z + giB.z, giA.w + giB.w };
        float gf[4] = { gfA.x + gfB.x, gfA.y + gfB.y, gfA.z + gfB.z, gfA.w + gfB.w };
        float gg[4] = { ggA.x + ggB.x, ggA.y + ggB.y, ggA.z + ggB.z, ggA.w + ggB.w };
        float go[4] = { goA.x + goB.x, goA.y + goB.y, goA.z + goB.z, goA.w + goB.w };
        float4 cn, hn;
        #pragma unroll
        for (int uu = 0; uu < 4; ++uu) {
            float cv = sigmoidf_(gf[uu]) * cc[uu] + sigmoidf_(gi[uu]) * tanhf_(gg[uu]);
            float hv = sigmoidf_(go[uu]) * tanhf_(cv);
            if (uu == 0) { cn.x = cv; hn.x = hv; } else if (uu == 1) { cn.y = cv; hn.y = hv; }
            else if (uu == 2) { cn.z = cv; hn.z = hv; } else { cn.w = cv; hn.w = hv; }
        }
        *(float4*)&c_st[ci] = cn;
        *(float4*)&hd[ci]   = hn;
    }
}

// ---------------------------------------------------------------------------
// Head: fc = tanh(h_d@Wf+bf); out[:,step] = tanh(fc@Wo+bo). Block = 16 rows.
// ---------------------------------------------------------------------------
__global__ __launch_bounds__(256) void head_k(
    const float* __restrict__ hd, const float* __restrict__ Wf,
    const float* __restrict__ bf, const float* __restrict__ Wo,
    const float* __restrict__ bo, float* __restrict__ out, int step)
{
    __shared__ float hd_s[16 * 256];
    __shared__ float fc_s[16 * 128];
    const int b0  = blockIdx.x * 16;
    const int tid = threadIdx.x;
    {
        const float4* hg = (const float4*)(hd + (size_t)b0 * 256);
        for (int i = tid; i < 1024; i += 256) ((float4*)hd_s)[i] = hg[i];
    }
    __syncthreads();
    {
        const int f = tid & 127, rg = tid >> 7;
        float acc[8];
        float bfv = bf[f];
        #pragma unroll
        for (int rr = 0; rr < 8; ++rr) acc[rr] = bfv;
        const float* wp = Wf + f;
        #pragma unroll 2
        for (int k = 0; k < 256; ++k) {
            float wv = wp[k * 128];
            #pragma unroll
            for (int rr = 0; rr < 8; ++rr) acc[rr] += hd_s[(rg * 8 + rr) * 256 + k] * wv;
        }
        for (int rr = 0; rr < 8; ++rr) fc_s[(rg * 8 + rr) * 128 + f] = tanhf_(acc[rr]);
    }
    __syncthreads();
    {
        const int lane = tid & 63, w = tid >> 6;
        const float bov = bo[0];
        #pragma unroll
        for (int rr = 0; rr < 4; ++rr) {
            int r = w * 4 + rr;
            float p = fc_s[r * 128 + lane] * Wo[lane] + fc_s[r * 128 + 64 + lane] * Wo[64 + lane];
            #pragma unroll
            for (int msk = 32; msk >= 1; msk >>= 1) p += __shfl_xor(p, msk, 64);
            if (lane == 0) out[(size_t)(b0 + r) * NOUT + step] = tanhf_(p + bov);
        }
    }
}

extern "C" void kernel_launch(void* const* d_in, const int* in_sizes, int n_in,
                              void* d_out, int out_size, void* d_ws, size_t ws_size,
                              hipStream_t stream)
{
    const float* x    = (const float*)d_in[0];
    const float* Wa   = (const float*)d_in[1];
    const float* ba   = (const float*)d_in[2];
    const float* Wi   = (const float*)d_in[3];
    const float* Wh   = (const float*)d_in[4];
    const float* be   = (const float*)d_in[5];
    const float* Wd   = (const float*)d_in[6];
    const float* bd   = (const float*)d_in[7];
    const float* Wl   = (const float*)d_in[8];
    const float* bl   = (const float*)d_in[9];
    const float* Wdi  = (const float*)d_in[10];
    const float* Wdh  = (const float*)d_in[11];
    const float* bdec = (const float*)d_in[12];
    const float* Wf   = (const float*)d_in[13];
    const float* bf   = (const float*)d_in[14];
    const float* Wo   = (const float*)d_in[15];
    const float* bo   = (const float*)d_in[16];
    float* out = (float*)d_out;

    // ws layout (floats): enc_out | hd | c_d | ctx(=hp=wprep alias) | scores | [ep]
    const size_t f_enc    = (size_t)LL * BB * EE;     // 52,428,800
    const size_t f_state  = (size_t)BB * EE;          // 524,288
    const size_t f_scores = (size_t)LL * BB;          // 204,800
    const size_t need3 = (f_enc + 3 * f_state + f_scores) * sizeof(float);
    const size_t need2 = need3 + f_enc * sizeof(u16);
    const size_t need1 = need3 + f_enc * sizeof(float);

    float* ws      = (float*)d_ws;
    float* enc_out = ws;
    float* hd      = enc_out + f_enc;
    float* c_d     = hd + f_state;
    float* ctx     = c_d + f_state;      // also hp AND the weight-prep buffer
    float* scores  = ctx + f_state;      //   (disjoint lifetimes)
    float* ep32    = scores + f_scores;  // tier 1 only
    u16*   ep16    = (u16*)(scores + f_scores);  // tier 2 only
    float* hp      = ctx;
    u16*   wprep   = (u16*)ctx;          // 808 tiles x 2 KB = 1.616 MB <= 2 MB
    // encoder h-exchange buffer aliases hd|c_d (4 MB combined, dead during
    // encoder); flags alias scores (dead during encoder), 128 B per group.
    float* hbuf    = hd;
    u32*   flags   = (u32*)scores;

    if (ws_size < need3) return;   // diagnostic clean-fail (known satisfied)
    const int tier = (ws_size >= need1) ? 1 : (ws_size >= need2) ? 2 : 3;

    // zero the group sync counters (replayed as a graph node each launch)
    hipMemsetAsync(flags, 0, 64 * 32 * sizeof(u32), stream);
    // weights -> bf16 hi/lo MFMA fragments (ctx region is dead here)
    w_prep_all<<<808, 64, 0, stream>>>(Wi, Wh, Wa, Wd, wprep);
    // persistent MFMA encoder: 256 blocks x 1024 threads (1/CU, co-resident)
    enc_mfma4<<<256, 1024, 0, stream>>>(x, ba, be, wprep, enc_out, hbuf, flags);

    // hoist the step-invariant enc_out @ Wd_top out of the decode loop
    if (tier == 1)
        gemm_ep_mfma<<<(LL * BB) / 32, 256, 0, stream>>>(enc_out, wprep, ep32);
    else
        pack_ep<<<(LL * BB) / 32, 256, 0, stream>>>(
            enc_out, Wd, ep16, tier == 3 ? 1 : 0);

    for (int s = 0; s < NOUT; ++s) {
        // hp = hd @ Wd_bot + bd  (step 0: hd == 0 -> hp = bd)
        gemm_nk256<<<BB / 32, 256, 0, stream>>>(
            hd, Wd + 256 * 256, bd, hp, s == 0);
        if (tier == 1)
            scores_ep_f32<<<dim3(BB / 8, 5), 256, 0, stream>>>(ep32, hp, Wl, scores);
        else if (tier == 2)
            scores_ep_b16<<<dim3(BB / 8, 5), 256, 0, stream>>>(ep16, hp, Wl, scores, 256, 0);
        else
            scores_ep_b16<<<dim3(BB / 8, 5), 256, 0, stream>>>(
                (const u16*)enc_out, hp, Wl, scores, 512, 256);
        if (tier == 3)
            softmax_ctx_b16<<<BB / 8, 256, 0, stream>>>(scores, (const u16*)enc_out, ctx);
        else
            softmax_ctx<<<BB / 8, 256, 0, stream>>>(scores, enc_out, ctx);
        dec_step<<<BB / 8, 512, 0, stream>>>(ctx, Wdi, Wdh, bdec, hd, c_d, s == 0);
        head_k<<<BB / 16, 256, 0, stream>>>(hd, Wf, bf, Wo, bo, out, s);
    }
}

// Round 12
// 2249.168 us; speedup vs baseline: 1.1814x; 1.0009x over previous
//
#include <hip/hip_runtime.h>
#include <math.h>

// Problem constants
#define BB 2048
#define LL 100
#define FF 64
#define EE 256
#define DD 256
#define NOUT 3

#define COMP(v, i) ((i) == 0 ? (v).x : (i) == 1 ? (v).y : (i) == 2 ? (v).z : (v).w)

typedef unsigned short u16;
typedef unsigned int u32;
typedef __attribute__((ext_vector_type(8))) __bf16 bf16x8;
typedef __attribute__((ext_vector_type(4))) float f32x4;
typedef __attribute__((ext_vector_type(2))) float f32x2;

#define MFMA_(A, B, C) __builtin_amdgcn_mfma_f32_16x16x32_bf16((A), (B), (C), 0, 0, 0)

__device__ __forceinline__ float sigmoidf_(float x) {
    return 1.0f / (1.0f + expf(-x));
}
// tanh via identity 1 - 2/(1+e^{2x}); ~2e-7 abs fp32 error, saturates correctly.
__device__ __forceinline__ float tanhf_(float x) {
    return 1.0f - 2.0f / (1.0f + expf(2.0f * x));
}
// fp32 -> bf16 round-to-nearest-even
__device__ __forceinline__ u16 f2b_(float f) {
    u32 u = __float_as_uint(f);
    u = (u + 0x7FFFu + ((u >> 16) & 1u)) >> 16;
    return (u16)u;
}
__device__ __forceinline__ float b2f_(u16 b) {
    return __uint_as_float(((u32)b) << 16);
}
__device__ __forceinline__ u32 pack2_(float a, float b) {
    return (u32)f2b_(a) | ((u32)f2b_(b) << 16);
}
__device__ __forceinline__ f32x4 splat4(float b) {
    f32x4 v; v[0] = b; v[1] = b; v[2] = b; v[3] = b; return v;
}
// split 8 fp32 into bf16 hi/lo planes packed as uint4 (little-endian pairs)
__device__ __forceinline__ void split8(const float* v, uint4& H, uint4& L) {
    u16 h[8], lo[8];
    #pragma unroll
    for (int e = 0; e < 8; ++e) {
        h[e]  = f2b_(v[e]);
        lo[e] = f2b_(v[e] - b2f_(h[e]));
    }
    H = make_uint4((u32)h[0]  | ((u32)h[1]  << 16), (u32)h[2]  | ((u32)h[3]  << 16),
                   (u32)h[4]  | ((u32)h[5]  << 16), (u32)h[6]  | ((u32)h[7]  << 16));
    L = make_uint4((u32)lo[0] | ((u32)lo[1] << 16), (u32)lo[2] | ((u32)lo[3] << 16),
                   (u32)lo[4] | ((u32)lo[5] << 16), (u32)lo[6] | ((u32)lo[7] << 16));
}

// Encoder A-fragment LDS index: [mt][kt(10)][plane][lane][8] u16.
// AFX bank swizzle (R7/R10-verified): stored lane = ln ^ ((ln>>4)&3).
#define AF(mt, kt, p, ln) (((((mt) * 10 + (kt)) * 2 + (p)) * 64 + (ln)) * 8)
#define AFX(mt, kt, p, ln) AF(mt, kt, p, (ln) ^ (((ln) >> 4) & 3))
// ep-GEMM A-fragment LDS index: [mt][kt(8)][plane][lane][8] u16
#define AF2(mt, kt, p, ln) (((((mt) * 8 + (kt)) * 2 + (p)) * 64 + (ln)) * 8)

// ---------------------------------------------------------------------------
// Weight prep (once per launch, into the dead ctx region), single launch:
// blocks 0..679:   bf16 hi/lo split of [Wi;Wh] (tiles 0..639) + Wa (640..679)
// blocks 680..807: Wd_top (256x256) -> tiles 680..807 (nt 0..15, kt 0..7)
// Tile (nt,kt) = 1024 u16: plane-hi [64 lanes][8 e], then plane-lo.
// Element (lane l, e) = W[k = kt*32 + (l>>4)*8 + e][col = nt*16 + (l&15)].
// ---------------------------------------------------------------------------
__global__ __launch_bounds__(64) void w_prep_all(
    const float* __restrict__ Wi, const float* __restrict__ Wh,
    const float* __restrict__ Wa, const float* __restrict__ Wd,
    u16* __restrict__ wp)
{
    const int bid = blockIdx.x;      // 0..807
    const int l   = threadIdx.x;     // 0..63

    float v[8];
    if (bid < 640) {
        const int nt = bid / 10, kt = bid - nt * 10;
        const int col = nt * 16 + (l & 15);
        #pragma unroll
        for (int e = 0; e < 8; ++e) {
            const int k = kt * 32 + ((l >> 4) << 3) + e;
            v[e] = (k < 64) ? Wi[(size_t)k * 1024 + col]
                            : Wh[(size_t)(k - 64) * 1024 + col];
        }
    } else if (bid < 680) {
        const int b2 = bid - 640;
        const int nt = b2 / 10, kt = b2 - nt * 10;
        const int col = nt * 16 + (l & 15);
        #pragma unroll
        for (int e = 0; e < 8; ++e) {
            const int k = kt * 32 + ((l >> 4) << 3) + e;
            v[e] = Wa[(size_t)k * 64 + col];
        }
    } else {
        const int b2 = bid - 680;
        const int nt = b2 >> 3, kt = b2 & 7;
        const int col = nt * 16 + (l & 15);
        #pragma unroll
        for (int e = 0; e < 8; ++e) {
            const int k = kt * 32 + ((l >> 4) << 3) + e;
            v[e] = Wd[(size_t)k * 256 + col];
        }
    }
    uint4 H, L;
    split8(v, H, L);
    *(uint4*)&wp[(size_t)bid * 1024 + (size_t)l * 8]       = H;
    *(uint4*)&wp[(size_t)bid * 1024 + 512 + (size_t)l * 8] = L;
}

// ---------------------------------------------------------------------------
// Persistent MFMA encoder == R11 (best: 1387 us) + wave specialization:
// P3's h-part (kt 2..9, 48/60 MFMAs) only needs fragments ready at barrier A,
// so waves 8-15 run it during P1 (waves 0-7) and waves 0-7 run it during P2
// (now on waves 8-15, tid-512 remap). After barrier C all waves finish the
// ein part (kt 0,1). Disjoint aFrag regions (P2 writes kt0-1; P3h reads
// kt2-9); barrier count unchanged. Accumulation order kt2..9 then kt0,1
// (reassociation-only numerics change).
// Sync protocol: R4/R10-proven tid==0 poll + barrier; flags 128B-padded
// (R11-verified). Grid 256 x 1024 (1 block/CU). Bounded spin: no hang.
// ---------------------------------------------------------------------------
__global__ __launch_bounds__(1024) void enc_mfma4(
    const float* __restrict__ x,
    const float* __restrict__ ba, const float* __restrict__ be,
    const u16* __restrict__ wp,
    float* __restrict__ enc_out,
    float* __restrict__ hbuf,          // [2][BB][256] fp32 (aliases hd|c_d)
    u32* __restrict__ flags)           // [64*32] counters, 128B apart (memset 0)
{
    __shared__ u16   aFrag[20480];         // 40 KB A-fragments (bf16 hi/lo)
    __shared__ float x_s[32 * 68];         // 8.5 KB x fp32
    __shared__ float e_s[32 * 68];         // 8.5 KB attention energies
    __shared__ float gate_s[4][32][66];    // 33 KB gates, padded stride 66

    const int bid = blockIdx.x;
    const int g   = (bid & 7) | ((bid >> 5) << 3);   // group 0..63
    const int p   = (bid >> 3) & 3;                  // unit-quarter
    const int row0 = g * 32;
    const int tid = threadIdx.x;
    const int l   = tid & 63;
    const int w   = tid >> 6;                        // wave 0..15

    // zero aFrag (h region must be 0 at t=0)
    for (int v = tid; v < 20480 / 2; v += 1024) ((u32*)aFrag)[v] = 0u;

    // per-wave N-tile; B-hi plane register-resident (40 VGPR)
    const int ntW = (w >> 2) * 16 + p * 4 + (w & 3);
    uint4 BhR[10];
    #pragma unroll
    for (int kt = 0; kt < 10; ++kt)
        BhR[kt] = *(const uint4*)&wp[(size_t)(ntW * 10 + kt) * 1024 + (size_t)l * 8];

    const float be_r = be[(size_t)ntW * 16 + (l & 15)];
    const float ba_r = (w < 8) ? ba[(w & 3) * 16 + (l & 15)] : 0.f;

    float c_state[2] = {0.f, 0.f};

    __syncthreads();

    for (int t = 0; t < LL; ++t) {
        // ---- S1: wait for all 4 partner blocks to finish t-1 ----
        if (t > 0) {
            if (tid == 0) {
                const u32 target = 4u * (u32)t;
                int guard = 0;
                while (__hip_atomic_load(&flags[g * 32], __ATOMIC_RELAXED,
                                         __HIP_MEMORY_SCOPE_AGENT) < target) {
                    __builtin_amdgcn_s_sleep(1);
                    if (++guard > 2000000) break;   // bounded: no GPU hang
                }
            }
            __syncthreads();
        }

        // ---- P0: stage x_t frags (tid<256) | partner-h frags (tid>=256) ----
        if (tid < 256) {
            const int kt2 = tid >> 7;          // 0..1
            const int mt  = (tid >> 6) & 1;    // 0..1
            const int l2  = tid & 63;
            const int row2 = mt * 16 + (l2 & 15);
            const int f0   = kt2 * 32 + ((l2 >> 4) << 3);
            const float* xp = x + (size_t)(row0 + row2) * (LL * FF) + (size_t)t * FF + f0;
            float4 xa = *(const float4*)xp;
            float4 xb = *(const float4*)(xp + 4);
            float v[8] = {xa.x, xa.y, xa.z, xa.w, xb.x, xb.y, xb.z, xb.w};
            uint4 H, L;
            split8(v, H, L);
            *(uint4*)&aFrag[AFX(mt, kt2, 0, l2)] = H;
            *(uint4*)&aFrag[AFX(mt, kt2, 1, l2)] = L;
            *(float4*)&x_s[row2 * 68 + f0]     = xa;
            *(float4*)&x_s[row2 * 68 + f0 + 4] = xb;
        } else if (t > 0) {
            const int v   = tid - 256;         // 0..767
            const int prl = v >> 8;            // 0..2 (relative partner)
            const int vv  = v & 255;
            const int row = vv >> 3;           // 0..31
            const int i8  = vv & 7;            // 8-unit chunk
            const int ugp = (p + 1 + prl) & 3;
            const int u8  = ugp * 64 + i8 * 8; // global unit base (mult of 8)
            const float* hp_g = hbuf + ((size_t)((t - 1) & 1) * BB + row0 + row) * 256 + u8;
            f32x4 a4, b4;
            asm volatile("global_load_dwordx4 %0, %2, off sc0 sc1\n\t"
                         "global_load_dwordx4 %1, %3, off sc0 sc1\n\t"
                         "s_waitcnt vmcnt(0)"
                         : "=v"(a4), "=v"(b4)
                         : "v"(hp_g), "v"(hp_g + 4) : "memory");
            float v8[8] = {a4[0], a4[1], a4[2], a4[3], b4[0], b4[1], b4[2], b4[3]};
            uint4 H, L;
            split8(v8, H, L);
            const int mt = row >> 4, rowT = row & 15;
            const int kt_h = 2 + (u8 >> 5);
            const int g2   = (u8 & 31) >> 3;
            const int ln   = rowT + (g2 << 4);
            *(uint4*)&aFrag[AFX(mt, kt_h, 0, ln)] = H;
            *(uint4*)&aFrag[AFX(mt, kt_h, 1, ln)] = L;
        }
        __syncthreads();   // A: x/h fragments visible

        f32x4 acc0, acc1;   // gate accumulators, built across phases B1/B2

        // ---- B1: waves 0-7 -> P1 attention | waves 8-15 -> P3h (kt 2..9) ----
        if (w < 8) {
            const int mt  = w >> 2;
            const int nta = w & 3;
            f32x4 ea = splat4(ba_r);
            #pragma unroll
            for (int kt = 0; kt < 10; ++kt) {
                bf16x8 Ah = *(const bf16x8*)&aFrag[AFX(mt, kt, 0, l)];
                bf16x8 Al = *(const bf16x8*)&aFrag[AFX(mt, kt, 1, l)];
                const size_t o = (size_t)(640 + nta * 10 + kt) * 1024 + (size_t)l * 8;
                bf16x8 Bh = *(const bf16x8*)&wp[o];
                bf16x8 Bl = *(const bf16x8*)&wp[o + 512];
                ea = MFMA_(Ah, Bh, ea);
                ea = MFMA_(Al, Bh, ea);
                ea = MFMA_(Ah, Bl, ea);
            }
            const int colA = nta * 16 + (l & 15);
            #pragma unroll
            for (int r = 0; r < 4; ++r) {
                const int rowT = ((l >> 4) << 2) + r;
                e_s[(mt * 16 + rowT) * 68 + colA] = tanhf_(ea[r]);
            }
        } else {
            acc0 = splat4(be_r); acc1 = splat4(be_r);
            #pragma unroll
            for (int kt = 2; kt < 10; ++kt) {
                bf16x8 Ah0 = *(const bf16x8*)&aFrag[AFX(0, kt, 0, l)];
                bf16x8 Al0 = *(const bf16x8*)&aFrag[AFX(0, kt, 1, l)];
                bf16x8 Ah1 = *(const bf16x8*)&aFrag[AFX(1, kt, 0, l)];
                bf16x8 Al1 = *(const bf16x8*)&aFrag[AFX(1, kt, 1, l)];
                bf16x8 Bl  = *(const bf16x8*)&wp[(size_t)(ntW * 10 + kt) * 1024 + 512 + (size_t)l * 8];
                bf16x8 Bh  = __builtin_bit_cast(bf16x8, BhR[kt]);
                acc0 = MFMA_(Ah0, Bh, acc0);
                acc1 = MFMA_(Ah1, Bh, acc1);
                acc0 = MFMA_(Al0, Bh, acc0);
                acc1 = MFMA_(Al1, Bh, acc1);
                acc0 = MFMA_(Ah0, Bl, acc0);
                acc1 = MFMA_(Ah1, Bl, acc1);
            }
        }
        __syncthreads();   // B: energies staged

        // ---- B2: waves 0-7 -> P3h (kt 2..9) | waves 8-15 -> P2 softmax ----
        if (w >= 8) {
            const int v2   = tid - 512;          // 0..511
            const int row2 = v2 >> 4;            // 0..31
            const int c4   = (v2 & 15) * 4;      // 0..60
            float4 ev = *(const float4*)&e_s[row2 * 68 + c4];
            float m = fmaxf(fmaxf(ev.x, ev.y), fmaxf(ev.z, ev.w));
            #pragma unroll
            for (int msk = 8; msk >= 1; msk >>= 1) m = fmaxf(m, __shfl_xor(m, msk, 64));
            float4 ex;
            ex.x = expf(ev.x - m); ex.y = expf(ev.y - m);
            ex.z = expf(ev.z - m); ex.w = expf(ev.w - m);
            float s = ex.x + ex.y + ex.z + ex.w;
            #pragma unroll
            for (int msk = 8; msk >= 1; msk >>= 1) s += __shfl_xor(s, msk, 64);
            const float inv = 1.f / s;
            float4 xv = *(const float4*)&x_s[row2 * 68 + c4];
            float ein[4] = { ex.x * inv * xv.x, ex.y * inv * xv.y,
                             ex.z * inv * xv.z, ex.w * inv * xv.w };
            const int mt   = row2 >> 4;
            const int rowT = row2 & 15;
            const int kt   = c4 >> 5;
            const int g2   = (c4 & 31) >> 3;
            const int e0   = c4 & 7;             // 0 or 4
            const int ln   = rowT + (g2 << 4);
            ushort4 h4, l4;
            #pragma unroll
            for (int e = 0; e < 4; ++e) {
                u16 hh = f2b_(ein[e]);
                u16 ll = f2b_(ein[e] - b2f_(hh));
                if (e == 0) { h4.x = hh; l4.x = ll; } else if (e == 1) { h4.y = hh; l4.y = ll; }
                else if (e == 2) { h4.z = hh; l4.z = ll; } else { h4.w = hh; l4.w = ll; }
            }
            *(ushort4*)&aFrag[AFX(mt, kt, 0, ln) + e0] = h4;
            *(ushort4*)&aFrag[AFX(mt, kt, 1, ln) + e0] = l4;
        } else {
            acc0 = splat4(be_r); acc1 = splat4(be_r);
            #pragma unroll
            for (int kt = 2; kt < 10; ++kt) {
                bf16x8 Ah0 = *(const bf16x8*)&aFrag[AFX(0, kt, 0, l)];
                bf16x8 Al0 = *(const bf16x8*)&aFrag[AFX(0, kt, 1, l)];
                bf16x8 Ah1 = *(const bf16x8*)&aFrag[AFX(1, kt, 0, l)];
                bf16x8 Al1 = *(const bf16x8*)&aFrag[AFX(1, kt, 1, l)];
                bf16x8 Bl  = *(const bf16x8*)&wp[(size_t)(ntW * 10 + kt) * 1024 + 512 + (size_t)l * 8];
                bf16x8 Bh  = __builtin_bit_cast(bf16x8, BhR[kt]);
                acc0 = MFMA_(Ah0, Bh, acc0);
                acc1 = MFMA_(Ah1, Bh, acc1);
                acc0 = MFMA_(Al0, Bh, acc0);
                acc1 = MFMA_(Al1, Bh, acc1);
                acc0 = MFMA_(Ah0, Bl, acc0);
                acc1 = MFMA_(Ah1, Bl, acc1);
            }
        }
        __syncthreads();   // C: ein fragments staged

        // ---- P3e: all waves, ein part (kt 0,1) ----
        #pragma unroll
        for (int kt = 0; kt < 2; ++kt) {
            bf16x8 Ah0 = *(const bf16x8*)&aFrag[AFX(0, kt, 0, l)];
            bf16x8 Al0 = *(const bf16x8*)&aFrag[AFX(0, kt, 1, l)];
            bf16x8 Ah1 = *(const bf16x8*)&aFrag[AFX(1, kt, 0, l)];
            bf16x8 Al1 = *(const bf16x8*)&aFrag[AFX(1, kt, 1, l)];
            bf16x8 Bl  = *(const bf16x8*)&wp[(size_t)(ntW * 10 + kt) * 1024 + 512 + (size_t)l * 8];
            bf16x8 Bh  = __builtin_bit_cast(bf16x8, BhR[kt]);
            acc0 = MFMA_(Ah0, Bh, acc0);
            acc1 = MFMA_(Ah1, Bh, acc1);
            acc0 = MFMA_(Al0, Bh, acc0);
            acc1 = MFMA_(Al1, Bh, acc1);
            acc0 = MFMA_(Ah0, Bl, acc0);
            acc1 = MFMA_(Ah1, Bl, acc1);
        }
        // stage gates: gate = w>>2, unit_local = (w&3)*16 + (l&15)
        {
            const int gate = w >> 2;
            const int ulb  = (w & 3) * 16 + (l & 15);
            #pragma unroll
            for (int r = 0; r < 4; ++r) {
                const int rT = ((l >> 4) << 2) + r;
                gate_s[gate][rT][ulb]      = acc0[r];
                gate_s[gate][16 + rT][ulb] = acc1[r];
            }
        }
        __syncthreads();   // D: gates staged; aFrag reads done

        // ---- epilogue: 1024 threads x 2 cells; h out + own h-frags ----
        {
            const int row = tid >> 5;            // 0..31
            const int q2  = (tid & 31) * 2;      // unit_local 0..62 even
            float gi0 = gate_s[0][row][q2], gi1 = gate_s[0][row][q2 + 1];
            float gf0 = gate_s[1][row][q2], gf1 = gate_s[1][row][q2 + 1];
            float gg0 = gate_s[2][row][q2], gg1 = gate_s[2][row][q2 + 1];
            float go0 = gate_s[3][row][q2], go1 = gate_s[3][row][q2 + 1];
            float cv0 = sigmoidf_(gf0) * c_state[0] + sigmoidf_(gi0) * tanhf_(gg0);
            float cv1 = sigmoidf_(gf1) * c_state[1] + sigmoidf_(gi1) * tanhf_(gg1);
            c_state[0] = cv0; c_state[1] = cv1;
            float hv0 = sigmoidf_(go0) * tanhf_(cv0);
            float hv1 = sigmoidf_(go1) * tanhf_(cv1);
            const int u_g = p * 64 + q2;
            *(float2*)&enc_out[((size_t)t * BB + row0 + row) * 256 + u_g]
                = make_float2(hv0, hv1);
            float* hp_g = hbuf + ((size_t)(t & 1) * BB + row0 + row) * 256 + u_g;
            f32x2 hv2; hv2[0] = hv0; hv2[1] = hv1;
            asm volatile("global_store_dwordx2 %0, %1, off sc0 sc1"
                         :: "v"(hp_g), "v"(hv2) : "memory");
            const int mt = row >> 4, rowT = row & 15;
            const int kt_h = 2 + (u_g >> 5);
            const int g2   = (u_g & 31) >> 3;
            const int ln   = rowT + (g2 << 4);
            const int e    = u_g & 7;            // even
            ((u32*)aFrag)[(AFX(mt, kt_h, 0, ln) + e) >> 1] = pack2_(hv0, hv1);
            u16 h0 = f2b_(hv0), h1 = f2b_(hv1);
            ((u32*)aFrag)[(AFX(mt, kt_h, 1, ln) + e) >> 1] =
                (u32)f2b_(hv0 - b2f_(h0)) | ((u32)f2b_(hv1 - b2f_(h1)) << 16);
        }
        asm volatile("s_waitcnt vmcnt(0)" ::: "memory");   // h stores complete
        __syncthreads();   // E: all waves' stores acked
        if (tid == 0)
            __hip_atomic_fetch_add(&flags[g * 32], 1u, __ATOMIC_RELEASE,
                                   __HIP_MEMORY_SCOPE_AGENT);
    }
}

// ---------------------------------------------------------------------------
// ep = enc_out @ Wd_top via split-bf16 MFMA (tier 1 hoisted GEMM).
// Grid M/32 x 256 threads (4 waves). Wave w owns nt = w*4..w*4+3.
// ---------------------------------------------------------------------------
__global__ __launch_bounds__(256) void gemm_ep_mfma(
    const float* __restrict__ A, const u16* __restrict__ wp,
    float* __restrict__ C)
{
    __shared__ u16   aF[2 * 8 * 2 * 64 * 8];   // 32 KB A-fragments
    __shared__ float c_s[32 * 260];            // 32.5 KB C staging (padded)
    const int m0  = blockIdx.x * 32;
    const int tid = threadIdx.x;
    const int l   = tid & 63;
    const int w   = tid >> 6;                  // 0..3

    for (int s = tid; s < 1024; s += 256) {
        const int mt = s >> 9, kt = (s >> 6) & 7, l2 = s & 63;
        const int row2 = mt * 16 + (l2 & 15);
        const int k0   = kt * 32 + ((l2 >> 4) << 3);
        const float* ap = A + (size_t)(m0 + row2) * 256 + k0;
        float4 xa = *(const float4*)ap;
        float4 xb = *(const float4*)(ap + 4);
        float v[8] = {xa.x, xa.y, xa.z, xa.w, xb.x, xb.y, xb.z, xb.w};
        uint4 H, L;
        split8(v, H, L);
        *(uint4*)&aF[AF2(mt, kt, 0, l2)] = H;
        *(uint4*)&aF[AF2(mt, kt, 1, l2)] = L;
    }
    __syncthreads();

    f32x4 acc[2][4];
    #pragma unroll
    for (int mt = 0; mt < 2; ++mt)
        #pragma unroll
        for (int j = 0; j < 4; ++j) acc[mt][j] = splat4(0.f);

    #pragma unroll
    for (int kt = 0; kt < 8; ++kt) {
        bf16x8 Ah0 = *(const bf16x8*)&aF[AF2(0, kt, 0, l)];
        bf16x8 Al0 = *(const bf16x8*)&aF[AF2(0, kt, 1, l)];
        bf16x8 Ah1 = *(const bf16x8*)&aF[AF2(1, kt, 0, l)];
        bf16x8 Al1 = *(const bf16x8*)&aF[AF2(1, kt, 1, l)];
        #pragma unroll
        for (int j = 0; j < 4; ++j) {
            const int nt = w * 4 + j;
            const u16* bt = wp + (size_t)(680 + nt * 8 + kt) * 1024 + (size_t)l * 8;
            bf16x8 Bh = *(const bf16x8*)bt;
            bf16x8 Bl = *(const bf16x8*)(bt + 512);
            acc[0][j] = MFMA_(Ah0, Bh, acc[0][j]);
            acc[1][j] = MFMA_(Ah1, Bh, acc[1][j]);
            acc[0][j] = MFMA_(Al0, Bh, acc[0][j]);
            acc[1][j] = MFMA_(Al1, Bh, acc[1][j]);
            acc[0][j] = MFMA_(Ah0, Bl, acc[0][j]);
            acc[1][j] = MFMA_(Ah1, Bl, acc[1][j]);
        }
    }

    #pragma unroll
    for (int mt = 0; mt < 2; ++mt)
        #pragma unroll
        for (int j = 0; j < 4; ++j) {
            const int col = (w * 4 + j) * 16 + (l & 15);
            #pragma unroll
            for (int r = 0; r < 4; ++r) {
                const int row = mt * 16 + ((l >> 4) << 2) + r;
                c_s[row * 260 + col] = acc[mt][j][r];
            }
        }
    __syncthreads();
    for (int v = tid; v < 32 * 64; v += 256) {
        const int row = v >> 6, c4 = (v & 63) << 2;
        *(float4*)&C[(size_t)(m0 + row) * 256 + c4] = *(const float4*)&c_s[row * 260 + c4];
    }
}

// ---------------------------------------------------------------------------
// Generic fp32 GEMM C(M,256) = A(M,256) @ W(256,256) [+ bias].
// Block = 32 rows, 256 threads. skip_gemm: C = bias (decoder step 0, hd==0).
// Used for: hp = hd @ Wd_bot + bd.
// ---------------------------------------------------------------------------
__global__ __launch_bounds__(256) void gemm_nk256(
    const float* __restrict__ A, const float* __restrict__ W,
    const float* __restrict__ bias, float* __restrict__ C, int skip_gemm)
{
    __shared__ float a_s[32 * 256];   // 32 KB
    const int m0   = blockIdx.x * 32;
    const int tid  = threadIdx.x;
    const int lane = tid & 63;
    const int rg   = tid >> 6;        // 0..3 -> rows rg*8..rg*8+7
    const int n0   = lane * 4;

    float4 bias4 = make_float4(0.f, 0.f, 0.f, 0.f);
    if (bias) bias4 = *(const float4*)&bias[n0];

    if (skip_gemm) {
        #pragma unroll
        for (int r = 0; r < 8; ++r)
            *(float4*)&C[(size_t)(m0 + rg * 8 + r) * 256 + n0] = bias4;
        return;
    }

    for (int v = tid; v < 32 * 64; v += 256)
        ((float4*)a_s)[v] = ((const float4*)(A + (size_t)m0 * 256))[v];
    __syncthreads();

    float4 acc[8];
    #pragma unroll
    for (int r = 0; r < 8; ++r) acc[r] = bias4;

    #pragma unroll 2
    for (int k = 0; k < 256; k += 4) {
        float4 wv[4];
        #pragma unroll
        for (int kk = 0; kk < 4; ++kk)
            wv[kk] = *(const float4*)&W[(size_t)(k + kk) * 256 + n0];
        float4 av[8];
        #pragma unroll
        for (int r = 0; r < 8; ++r)
            av[r] = *(const float4*)&a_s[(rg * 8 + r) * 256 + k];
        #pragma unroll
        for (int kk = 0; kk < 4; ++kk) {
            #pragma unroll
            for (int r = 0; r < 8; ++r) {
                float e = COMP(av[r], kk);
                acc[r].x += e * wv[kk].x; acc[r].y += e * wv[kk].y;
                acc[r].z += e * wv[kk].z; acc[r].w += e * wv[kk].w;
            }
        }
    }
    #pragma unroll
    for (int r = 0; r < 8; ++r)
        *(float4*)&C[(size_t)(m0 + rg * 8 + r) * 256 + n0] = acc[r];
}

// ---------------------------------------------------------------------------
// ep = enc_out @ Wd_top, emitted as bf16 (tiers 2/3 fallback).
// ---------------------------------------------------------------------------
__global__ __launch_bounds__(256) void pack_ep(
    float* A, const float* __restrict__ W, u16* epOut, int packed)
{
    __shared__ float a_s[32 * 256];   // 32 KB
    const int m0   = blockIdx.x * 32;
    const int tid  = threadIdx.x;
    const int lane = tid & 63;
    const int rg   = tid >> 6;
    const int n0   = lane * 4;

    for (int v = tid; v < 32 * 64; v += 256)
        ((float4*)a_s)[v] = ((const float4*)(A + (size_t)m0 * 256))[v];
    __syncthreads();

    float4 acc[8];
    #pragma unroll
    for (int r = 0; r < 8; ++r) acc[r] = make_float4(0.f, 0.f, 0.f, 0.f);

    #pragma unroll 2
    for (int k = 0; k < 256; k += 4) {
        float4 wv[4];
        #pragma unroll
        for (int kk = 0; kk < 4; ++kk)
            wv[kk] = *(const float4*)&W[(size_t)(k + kk) * 256 + n0];
        float4 av[8];
        #pragma unroll
        for (int r = 0; r < 8; ++r)
            av[r] = *(const float4*)&a_s[(rg * 8 + r) * 256 + k];
        #pragma unroll
        for (int kk = 0; kk < 4; ++kk) {
            #pragma unroll
            for (int r = 0; r < 8; ++r) {
                float e = COMP(av[r], kk);
                acc[r].x += e * wv[kk].x; acc[r].y += e * wv[kk].y;
                acc[r].z += e * wv[kk].z; acc[r].w += e * wv[kk].w;
            }
        }
    }

    u16* epu = packed ? (u16*)A : epOut;
    #pragma unroll
    for (int r = 0; r < 8; ++r) {
        const size_t row = (size_t)(m0 + rg * 8 + r);
        ushort4 o;
        o.x = f2b_(acc[r].x); o.y = f2b_(acc[r].y);
        o.z = f2b_(acc[r].z); o.w = f2b_(acc[r].w);
        u16* dst = packed ? (epu + row * 512 + 256 + n0)
                          : (epu + row * 256 + n0);
        *(ushort4*)dst = o;
    }

    if (packed) {
        u32* ab = (u32*)A;
        for (int v = tid; v < 32 * 128; v += 256) {
            const int row = v >> 7, j = v & 127;
            float2 f = *(const float2*)&a_s[(row << 8) + (j << 1)];
            ab[((size_t)(m0 + row)) * 256 + j] = pack2_(f.x, f.y);
        }
    }
}

// ---------------------------------------------------------------------------
// FUSED per-step decoder attention (tier 1): scores + softmax + ctx in one
// kernel. Grid BB/8 = 256 blocks x 512 threads; block owns 8 batch rows.
//   score[l,b] = Wl . tanh(ep[l,b,:] + hp[b,:])   (bl cancels in softmax)
// Scores: wave r (= tid>>6) owns row r; lane covers 4 elems; full-wave
// shuffle reduce. Softmax: tid<8 serial over L. ctx: 512 threads, thread
// (u = tid&255, rh = tid>>8) accumulates rows rh*4..+3 over all l.
// Replaces scores_ep_f32 + softmax_ctx (one launch + scores round-trip).
// ---------------------------------------------------------------------------
__global__ __launch_bounds__(512) void scores_sm_ctx(
    const float* __restrict__ ep, const float* __restrict__ hp,
    const float* __restrict__ Wl, const float* __restrict__ enc_out,
    float* __restrict__ ctx)
{
    __shared__ float hp_s[8 * 256];   // 8 KB
    __shared__ float al_s[8 * 100];   // 3.2 KB
    const int b0  = blockIdx.x * 8;
    const int tid = threadIdx.x;

    for (int v = tid; v < 512; v += 512)
        ((float4*)hp_s)[v] = ((const float4*)(hp + (size_t)b0 * 256))[v];
    __syncthreads();

    {
        const int r = tid >> 6;          // 0..7 (wave per row)
        const int g = tid & 63;
        const float4 wl4 = *(const float4*)&Wl[g * 4];
        const float4 h4  = *(const float4*)&hp_s[r * 256 + g * 4];
        for (int l = 0; l < LL; ++l) {
            const float* er = ep + ((size_t)l * BB + b0 + r) * 256;
            float4 e4 = *(const float4*)&er[g * 4];
            float p = tanhf_(e4.x + h4.x) * wl4.x + tanhf_(e4.y + h4.y) * wl4.y
                    + tanhf_(e4.z + h4.z) * wl4.z + tanhf_(e4.w + h4.w) * wl4.w;
            #pragma unroll
            for (int msk = 32; msk >= 1; msk >>= 1) p += __shfl_xor(p, msk, 64);
            if (g == 0) al_s[r * 100 + l] = p;
        }
    }
    __syncthreads();
    if (tid < 8) {
        float m = -1e30f;
        for (int l = 0; l < LL; ++l) m = fmaxf(m, al_s[tid * 100 + l]);
        float s = 0.f;
        for (int l = 0; l < LL; ++l) { float e = expf(al_s[tid * 100 + l] - m); al_s[tid * 100 + l] = e; s += e; }
        float inv = 1.f / s;
        for (int l = 0; l < LL; ++l) al_s[tid * 100 + l] *= inv;
    }
    __syncthreads();
    {
        const int u  = tid & 255;
        const int rh = tid >> 8;         // 0..1 -> rows rh*4..rh*4+3
        float acc[4] = {};
        for (int l = 0; l < LL; ++l) {
            const float* er2 = enc_out + (size_t)l * (BB * 256)
                             + (size_t)(b0 + rh * 4) * 256 + u;
            #pragma unroll
            for (int j = 0; j < 4; ++j)
                acc[j] += al_s[(rh * 4 + j) * 100 + l] * er2[j * 256];
        }
        #pragma unroll
        for (int j = 0; j < 4; ++j)
            ctx[(size_t)(b0 + rh * 4 + j) * 256 + u] = acc[j];
    }
}

// ---------------------------------------------------------------------------
// Per-step decoder scores from bf16 ep rows (tiers 2/3). sstr/soff in u16.
// ---------------------------------------------------------------------------
__global__ __launch_bounds__(256) void scores_ep_b16(
    const u16* __restrict__ ep, const float* __restrict__ hp,
    const float* __restrict__ Wl, float* __restrict__ scores,
    int sstr, int soff)
{
    __shared__ float hp_s[8 * 256];
    const int b0  = blockIdx.x * 8;
    const int l0  = blockIdx.y * 20;
    const int tid = threadIdx.x;
    const int r   = tid >> 5;
    const int g   = tid & 31;

    for (int v = tid; v < 512; v += 256)
        ((float4*)hp_s)[v] = ((const float4*)(hp + (size_t)b0 * 256))[v];
    __syncthreads();

    const float4 wl0 = *(const float4*)&Wl[g * 4];
    const float4 wl1 = *(const float4*)&Wl[128 + g * 4];
    const float4 h0  = *(const float4*)&hp_s[r * 256 + g * 4];
    const float4 h1  = *(const float4*)&hp_s[r * 256 + 128 + g * 4];

    #pragma unroll 2
    for (int li = 0; li < 20; ++li) {
        const u16* er = ep + ((size_t)(l0 + li) * BB + b0 + r) * sstr + soff;
        ushort4 u0 = *(const ushort4*)&er[g * 4];
        ushort4 u1 = *(const ushort4*)&er[128 + g * 4];
        float p = tanhf_(b2f_(u0.x) + h0.x) * wl0.x + tanhf_(b2f_(u0.y) + h0.y) * wl0.y
                + tanhf_(b2f_(u0.z) + h0.z) * wl0.z + tanhf_(b2f_(u0.w) + h0.w) * wl0.w
                + tanhf_(b2f_(u1.x) + h1.x) * wl1.x + tanhf_(b2f_(u1.y) + h1.y) * wl1.y
                + tanhf_(b2f_(u1.z) + h1.z) * wl1.z + tanhf_(b2f_(u1.w) + h1.w) * wl1.w;
        #pragma unroll
        for (int msk = 16; msk >= 1; msk >>= 1) p += __shfl_xor(p, msk, 64);
        if (g == 0) scores[(size_t)(l0 + li) * BB + b0 + r] = p;
    }
}

// ---------------------------------------------------------------------------
// softmax over L + ctx, fp32 enc (tier 2 fallback). Block = 8 rows.
// ---------------------------------------------------------------------------
__global__ __launch_bounds__(256) void softmax_ctx(
    const float* __restrict__ scores, const float* __restrict__ enc_out,
    float* __restrict__ ctx)
{
    __shared__ float al_s[8 * 100];
    const int b0  = blockIdx.x * 8;
    const int tid = threadIdx.x;
    for (int v = tid; v < 800; v += 256) {
        int r = v / 100, l = v - r * 100;
        al_s[r * 100 + l] = scores[(size_t)l * BB + b0 + r];
    }
    __syncthreads();
    if (tid < 8) {
        float m = -1e30f;
        for (int l = 0; l < LL; ++l) m = fmaxf(m, al_s[tid * 100 + l]);
        float s = 0.f;
        for (int l = 0; l < LL; ++l) { float e = expf(al_s[tid * 100 + l] - m); al_s[tid * 100 + l] = e; s += e; }
        float inv = 1.f / s;
        for (int l = 0; l < LL; ++l) al_s[tid * 100 + l] *= inv;
    }
    __syncthreads();
    float acc[8] = {};
    for (int l = 0; l < LL; ++l) {
        const float* er = enc_out + (size_t)l * (BB * 256) + (size_t)b0 * 256 + tid;
        #pragma unroll
        for (int r = 0; r < 8; ++r) acc[r] += al_s[r * 100 + l] * er[r * 256];
    }
    for (int r = 0; r < 8; ++r) ctx[(size_t)(b0 + r) * 256 + tid] = acc[r];
}

// ---------------------------------------------------------------------------
// softmax over L + ctx, bf16 packed enc (tier 3).
// ---------------------------------------------------------------------------
__global__ __launch_bounds__(256) void softmax_ctx_b16(
    const float* __restrict__ scores, const u16* __restrict__ encp,
    float* __restrict__ ctx)
{
    __shared__ float al_s[8 * 100];
    const int b0  = blockIdx.x * 8;
    const int tid = threadIdx.x;
    for (int v = tid; v < 800; v += 256) {
        int r = v / 100, l = v - r * 100;
        al_s[r * 100 + l] = scores[(size_t)l * BB + b0 + r];
    }
    __syncthreads();
    if (tid < 8) {
        float m = -1e30f;
        for (int l = 0; l < LL; ++l) m = fmaxf(m, al_s[tid * 100 + l]);
        float s = 0.f;
        for (int l = 0; l < LL; ++l) { float e = expf(al_s[tid * 100 + l] - m); al_s[tid * 100 + l] = e; s += e; }
        float inv = 1.f / s;
        for (int l = 0; l < LL; ++l) al_s[tid * 100 + l] *= inv;
    }
    __syncthreads();
    float acc[8] = {};
    for (int l = 0; l < LL; ++l) {
        const u16* er = encp + ((size_t)l * BB + b0) * 512 + tid;
        #pragma unroll
        for (int r = 0; r < 8; ++r) acc[r] += al_s[r * 100 + l] * b2f_(er[r * 512]);
    }
    for (int r = 0; r < 8; ++r) ctx[(size_t)(b0 + r) * 256 + tid] = acc[r];
}

// ---------------------------------------------------------------------------
// Decoder LSTM cell: grid 256 x 512, block = 8 rows, half0 = ctx@Wdi,
// half1 = hd@Wdh, coalesced float4 weights. hd updated in place.
// ---------------------------------------------------------------------------
__global__ __launch_bounds__(512) void dec_step(
    const float* __restrict__ ctxp,
    const float* __restrict__ Wdi, const float* __restrict__ Wdh,
    const float* __restrict__ bdec,
    float* __restrict__ hd, float* __restrict__ c_st, int first)
{
    __shared__ float ct_s[8 * 256];        // 8 KB
    __shared__ float hd_s[8 * 256];        // 8 KB
    __shared__ float gate_s[2][8 * 1024];  // 64 KB
    const int row0 = blockIdx.x * 8;
    const int tid  = threadIdx.x;
    const int lane = tid & 63, w = tid >> 6;
    const int half = tid >> 8;
    const int ct   = tid & 255;
    const int c0   = ct * 4;

    ((float4*)ct_s)[tid] = ((const float4*)(ctxp + (size_t)row0 * 256))[tid];
    if (!first)
        ((float4*)hd_s)[tid] = ((const float4*)(hd + (size_t)row0 * 256))[tid];
    __syncthreads();

    float4 acc[8];
    {
        float4 b4 = *(const float4*)&bdec[c0];
        float4 bias4 = (half == 0) ? b4 : make_float4(0.f, 0.f, 0.f, 0.f);
        #pragma unroll
        for (int r = 0; r < 8; ++r) acc[r] = bias4;
    }
    if (half == 0) {
        const float* wP = Wdi + c0;
        #pragma unroll 2
        for (int ch = 0; ch < 64; ++ch) {
            const int k0 = ch * 4;
            float4 w0 = *(const float4*)&wP[(size_t)(k0 + 0) * 1024];
            float4 w1 = *(const float4*)&wP[(size_t)(k0 + 1) * 1024];
            float4 w2 = *(const float4*)&wP[(size_t)(k0 + 2) * 1024];
            float4 w3 = *(const float4*)&wP[(size_t)(k0 + 3) * 1024];
            #pragma unroll
            for (int r = 0; r < 8; ++r) {
                float4 av = *(const float4*)&ct_s[r * 256 + k0];
                acc[r].x += av.x * w0.x; acc[r].y += av.x * w0.y;
                acc[r].z += av.x * w0.z; acc[r].w += av.x * w0.w;
                acc[r].x += av.y * w1.x; acc[r].y += av.y * w1.y;
                acc[r].z += av.y * w1.z; acc[r].w += av.y * w1.w;
                acc[r].x += av.z * w2.x; acc[r].y += av.z * w2.y;
                acc[r].z += av.z * w2.z; acc[r].w += av.z * w2.w;
                acc[r].x += av.w * w3.x; acc[r].y += av.w * w3.y;
                acc[r].z += av.w * w3.z; acc[r].w += av.w * w3.w;
            }
        }
    } else if (!first) {
        const float* wP = Wdh + c0;
        #pragma unroll 2
        for (int ch = 0; ch < 64; ++ch) {
            const int k0 = ch * 4;
            float4 w0 = *(const float4*)&wP[(size_t)(k0 + 0) * 1024];
            float4 w1 = *(const float4*)&wP[(size_t)(k0 + 1) * 1024];
            float4 w2 = *(const float4*)&wP[(size_t)(k0 + 2) * 1024];
            float4 w3 = *(const float4*)&wP[(size_t)(k0 + 3) * 1024];
            #pragma unroll
            for (int r = 0; r < 8; ++r) {
                float4 av = *(const float4*)&hd_s[r * 256 + k0];
                acc[r].x += av.x * w0.x; acc[r].y += av.x * w0.y;
                acc[r].z += av.x * w0.z; acc[r].w += av.x * w0.w;
                acc[r].x += av.y * w1.x; acc[r].y += av.y * w1.y;
                acc[r].z += av.y * w1.z; acc[r].w += av.y * w1.w;
                acc[r].x += av.z * w2.x; acc[r].y += av.z * w2.y;
                acc[r].z += av.z * w2.z; acc[r].w += av.z * w2.w;
                acc[r].x += av.w * w3.x; acc[r].y += av.w * w3.y;
                acc[r].z += av.w * w3.z; acc[r].w += av.w * w3.w;
            }
        }
    }
    #pragma unroll
    for (int r = 0; r < 8; ++r)
        *(float4*)&gate_s[half][r * 1024 + c0] = acc[r];
    __syncthreads();

    {
        const float* g0 = &gate_s[0][w * 1024 + lane * 4];
        const float* g1 = &gate_s[1][w * 1024 + lane * 4];
        float4 giA = *(const float4*)&g0[0],   giB = *(const float4*)&g1[0];
        float4 gfA = *(const float4*)&g0[256], gfB = *(const float4*)&g1[256];
        float4 ggA = *(const float4*)&g0[512], ggB = *(const float4*)&g1[512];
        float4 goA = *(const float4*)&g0[768], goB = *(const float4*)&g1[768];
        size_t ci = (size_t)(row0 + w) * 256 + lane * 4;
        float4 c4 = first ? make_float4(0.f, 0.f, 0.f, 0.f)
                          : *(const float4*)&c_st[ci];
        float cc[4] = { c4.x, c4.y, c4.z, c4.w };
        float gi[4] = { giA.x + giB.x, giA.y + giB.y, giA.z + giB.z, giA.w + giB.w };
        float gf[4] = { gfA.x + gfB.x, gfA.y + gfB.y, gfA.z + gfB.z, gfA.w + gfB.w };
        float gg[4] = { ggA.x + ggB.x, ggA.y + ggB.y, ggA.z + ggB.z, ggA.w + ggB.w };
        float go[4] = { goA.x + goB.x, goA.y + goB.y, goA.z + goB.z, goA.w + goB.w };
        float4 cn, hn;
        #pragma unroll
        for (int uu = 0; uu < 4; ++uu) {
            float cv = sigmoidf_(gf[uu]) * cc[uu] + sigmoidf_(gi[uu]) * tanhf_(gg[uu]);
            float hv = sigmoidf_(go[uu]) * tanhf_(cv);
            if (uu == 0) { cn.x = cv; hn.x = hv; } else if (uu == 1) { cn.y = cv; hn.y = hv; }
            else if (uu == 2) { cn.z = cv; hn.z = hv; } else { cn.w = cv; hn.w = hv; }
        }
        *(float4*)&c_st[ci] = cn;
        *(float4*)&hd[ci]   = hn;
    }
}

// ---------------------------------------------------------------------------
// Head: fc = tanh(h_d@Wf+bf); out[:,step] = tanh(fc@Wo+bo). Block = 16 rows.
// ---------------------------------------------------------------------------
__global__ __launch_bounds__(256) void head_k(
    const float* __restrict__ hd, const float* __restrict__ Wf,
    const float* __restrict__ bf, const float* __restrict__ Wo,
    const float* __restrict__ bo, float* __restrict__ out, int step)
{
    __shared__ float hd_s[16 * 256];
    __shared__ float fc_s[16 * 128];
    const int b0  = blockIdx.x * 16;
    const int tid = threadIdx.x;
    {
        const float4* hg = (const float4*)(hd + (size_t)b0 * 256);
        for (int i = tid; i < 1024; i += 256) ((float4*)hd_s)[i] = hg[i];
    }
    __syncthreads();
    {
        const int f = tid & 127, rg = tid >> 7;
        float acc[8];
        float bfv = bf[f];
        #pragma unroll
        for (int rr = 0; rr < 8; ++rr) acc[rr] = bfv;
        const float* wp = Wf + f;
        #pragma unroll 2
        for (int k = 0; k < 256; ++k) {
            float wv = wp[k * 128];
            #pragma unroll
            for (int rr = 0; rr < 8; ++rr) acc[rr] += hd_s[(rg * 8 + rr) * 256 + k] * wv;
        }
        for (int rr = 0; rr < 8; ++rr) fc_s[(rg * 8 + rr) * 128 + f] = tanhf_(acc[rr]);
    }
    __syncthreads();
    {
        const int lane = tid & 63, w = tid >> 6;
        const float bov = bo[0];
        #pragma unroll
        for (int rr = 0; rr < 4; ++rr) {
            int r = w * 4 + rr;
            float p = fc_s[r * 128 + lane] * Wo[lane] + fc_s[r * 128 + 64 + lane] * Wo[64 + lane];
            #pragma unroll
            for (int msk = 32; msk >= 1; msk >>= 1) p += __shfl_xor(p, msk, 64);
            if (lane == 0) out[(size_t)(b0 + r) * NOUT + step] = tanhf_(p + bov);
        }
    }
}

extern "C" void kernel_launch(void* const* d_in, const int* in_sizes, int n_in,
                              void* d_out, int out_size, void* d_ws, size_t ws_size,
                              hipStream_t stream)
{
    const float* x    = (const float*)d_in[0];
    const float* Wa   = (const float*)d_in[1];
    const float* ba   = (const float*)d_in[2];
    const float* Wi   = (const float*)d_in[3];
    const float* Wh   = (const float*)d_in[4];
    const float* be   = (const float*)d_in[5];
    const float* Wd   = (const float*)d_in[6];
    const float* bd   = (const float*)d_in[7];
    const float* Wl   = (const float*)d_in[8];
    const float* bl   = (const float*)d_in[9];
    const float* Wdi  = (const float*)d_in[10];
    const float* Wdh  = (const float*)d_in[11];
    const float* bdec = (const float*)d_in[12];
    const float* Wf   = (const float*)d_in[13];
    const float* bf   = (const float*)d_in[14];
    const float* Wo   = (const float*)d_in[15];
    const float* bo   = (const float*)d_in[16];
    float* out = (float*)d_out;

    // ws layout (floats): enc_out | hd | c_d | ctx(=hp=wprep alias) | scores | [ep]
    const size_t f_enc    = (size_t)LL * BB * EE;     // 52,428,800
    const size_t f_state  = (size_t)BB * EE;          // 524,288
    const size_t f_scores = (size_t)LL * BB;          // 204,800
    const size_t need3 = (f_enc + 3 * f_state + f_scores) * sizeof(float);
    const size_t need2 = need3 + f_enc * sizeof(u16);
    const size_t need1 = need3 + f_enc * sizeof(float);

    float* ws      = (float*)d_ws;
    float* enc_out = ws;
    float* hd      = enc_out + f_enc;
    float* c_d     = hd + f_state;
    float* ctx     = c_d + f_state;      // also hp AND the weight-prep buffer
    float* scores  = ctx + f_state;      //   (disjoint lifetimes)
    float* ep32    = scores + f_scores;  // tier 1 only
    u16*   ep16    = (u16*)(scores + f_scores);  // tier 2 only
    float* hp      = ctx;
    u16*   wprep   = (u16*)ctx;          // 808 tiles x 2 KB = 1.616 MB <= 2 MB
    // encoder h-exchange buffer aliases hd|c_d (4 MB combined, dead during
    // encoder); flags alias scores (dead during encoder), 128 B per group.
    float* hbuf    = hd;
    u32*   flags   = (u32*)scores;

    if (ws_size < need3) return;   // diagnostic clean-fail (known satisfied)
    const int tier = (ws_size >= need1) ? 1 : (ws_size >= need2) ? 2 : 3;

    // zero the group sync counters (replayed as a graph node each launch)
    hipMemsetAsync(flags, 0, 64 * 32 * sizeof(u32), stream);
    // weights -> bf16 hi/lo MFMA fragments (ctx region is dead here)
    w_prep_all<<<808, 64, 0, stream>>>(Wi, Wh, Wa, Wd, wprep);
    // persistent MFMA encoder: 256 blocks x 1024 threads (1/CU, co-resident)
    enc_mfma4<<<256, 1024, 0, stream>>>(x, ba, be, wprep, enc_out, hbuf, flags);

    // hoist the step-invariant enc_out @ Wd_top out of the decode loop
    if (tier == 1)
        gemm_ep_mfma<<<(LL * BB) / 32, 256, 0, stream>>>(enc_out, wprep, ep32);
    else
        pack_ep<<<(LL * BB) / 32, 256, 0, stream>>>(
            enc_out, Wd, ep16, tier == 3 ? 1 : 0);

    for (int s = 0; s < NOUT; ++s) {
        // hp = hd @ Wd_bot + bd  (step 0: hd == 0 -> hp = bd)
        gemm_nk256<<<BB / 32, 256, 0, stream>>>(
            hd, Wd + 256 * 256, bd, hp, s == 0);
        if (tier == 1) {
            scores_sm_ctx<<<BB / 8, 512, 0, stream>>>(ep32, hp, Wl, enc_out, ctx);
        } else if (tier == 2) {
            scores_ep_b16<<<dim3(BB / 8, 5), 256, 0, stream>>>(ep16, hp, Wl, scores, 256, 0);
            softmax_ctx<<<BB / 8, 256, 0, stream>>>(scores, enc_out, ctx);
        } else {
            scores_ep_b16<<<dim3(BB / 8, 5), 256, 0, stream>>>(
                (const u16*)enc_out, hp, Wl, scores, 512, 256);
            softmax_ctx_b16<<<BB / 8, 256, 0, stream>>>(scores, (const u16*)enc_out, ctx);
        }
        dec_step<<<BB / 8, 512, 0, stream>>>(ctx, Wdi, Wdh, bdec, hd, c_d, s == 0);
        head_k<<<BB / 16, 256, 0, stream>>>(hd, Wf, bf, Wo, bo, out, s);
    }
}